// Round 1
// baseline (1955.660 us; speedup 1.0000x reference)
//
#include <hip/hip_runtime.h>
#include <hip/hip_bf16.h>
#include <math.h>

#define Bq 4
#define Sq 512
#define Hq 512
#define NHq 8
#define DHq 64
#define Tq 3
#define DTSq 170
#define BSq 2048
#define ENCSTRIDE 520

__device__ __forceinline__ float gelu_f(float x){
  return 0.5f * x * (1.0f + erff(x * 0.70710678118654752f));
}

__device__ __forceinline__ float waveReduceSum(float v){
  #pragma unroll
  for (int off = 32; off > 0; off >>= 1) v += __shfl_xor(v, off);
  return v;
}
__device__ __forceinline__ float waveReduceMax(float v){
  #pragma unroll
  for (int off = 32; off > 0; off >>= 1) v = fmaxf(v, __shfl_xor(v, off));
  return v;
}

__device__ __forceinline__ float blockReduce(float v, float* red){
  int tid = threadIdx.x;
  __syncthreads();
  red[tid] = v; __syncthreads();
  for (int s = 128; s > 0; s >>= 1){
    if (tid < s) red[tid] += red[tid + s];
    __syncthreads();
  }
  return red[0];
}

// ---------------- encoder prep: centered vectors + covariance scalars -------
__global__ __launch_bounds__(256) void enc_prep(const float* __restrict__ encW,
                                                const float* __restrict__ encB,
                                                float* __restrict__ out){
  int t = blockIdx.x, tid = threadIdx.x;
  __shared__ float red[256];
  const float* W0 = encW + t * 2 * DTSq;
  const float* W1 = W0 + DTSq;
  const float* Bv = encB + t * DTSq;
  float w0 = (tid < DTSq) ? W0[tid] : 0.f;
  float w1 = (tid < DTSq) ? W1[tid] : 0.f;
  float bv = (tid < DTSq) ? Bv[tid] : 0.f;
  const float invD = 1.0f / (float)DTSq;
  float m0 = blockReduce(w0, red) * invD;
  float m1 = blockReduce(w1, red) * invD;
  float mb = blockReduce(bv, red) * invD;
  float c0 = (tid < DTSq) ? (w0 - m0) : 0.f;
  float c1 = (tid < DTSq) ? (w1 - m1) : 0.f;
  float cb = (tid < DTSq) ? (bv - mb) : 0.f;
  float* op = out + t * ENCSTRIDE;
  if (tid < DTSq){
    op[tid] = c0; op[DTSq + tid] = c1; op[2 * DTSq + tid] = cb;
  }
  float pa = blockReduce(c0 * c0, red) * invD;
  float pb = blockReduce(c1 * c1, red) * invD;
  float pc = blockReduce(c0 * c1, red) * invD;
  float pd = blockReduce(c0 * cb, red) * invD;
  float pe = blockReduce(c1 * cb, red) * invD;
  float pf = blockReduce(cb * cb, red) * invD;
  if (tid == 0){
    op[3 * DTSq + 0] = pa; op[3 * DTSq + 1] = pb; op[3 * DTSq + 2] = pc;
    op[3 * DTSq + 3] = pd; op[3 * DTSq + 4] = pe; op[3 * DTSq + 5] = pf;
  }
}

// ---------------- pairwise temporal masks [T][B][S][S] ----------------------
__global__ __launch_bounds__(256) void mask_kernel(const float* __restrict__ ts,
                                                   const float* __restrict__ enc,
                                                   const float* __restrict__ g,
                                                   const float* __restrict__ be,
                                                   float* __restrict__ maskbuf){
  __shared__ float sw0[Tq][DTSq], sw1[Tq][DTSq], sbc[Tq][DTSq];
  __shared__ float sg[Tq][DTSq], sbe[Tq][DTSq];
  __shared__ float sS[Tq][6];
  int tid = threadIdx.x;
  for (int l = tid; l < Tq * DTSq; l += 256){
    int t = l / DTSq, c = l % DTSq;
    const float* ep = enc + t * ENCSTRIDE;
    sw0[t][c] = ep[c];
    sw1[t][c] = ep[DTSq + c];
    sbc[t][c] = ep[2 * DTSq + c];
    sg[t][c]  = g[t * DTSq + c];
    sbe[t][c] = be[t * DTSq + c];
  }
  if (tid < Tq * 6){
    int t = tid / 6, k = tid % 6;
    sS[t][k] = enc[t * ENCSTRIDE + 3 * DTSq + k];
  }
  __syncthreads();
  int bi = blockIdx.x;                // b*S + i
  int b = bi >> 9, i = bi & 511;
  float tsi = ts[bi];
  for (int j0 = 0; j0 < Sq; j0 += 256){
    int j = j0 + tid;
    float dt = tsi - ts[(b << 9) + j];
    float d = (dt > 0.f) ? 1.f : ((dt < 0.f) ? -1.f : 0.f);
    float mag = log1pf(fabsf(dt) * (1.0f / 3600.0f));
    float sc = 1.0f;
    for (int t = 0; t < Tq; ++t){
      float m = mag * sc;
      float A = sS[t][0], Bs = sS[t][1], Cs = sS[t][2];
      float Ds = sS[t][3], Es = sS[t][4], Fs = sS[t][5];
      float var = fabsf(d) * A + m * m * Bs + Fs
                + 2.f * (d * m * Cs + d * Ds + m * Es);
      float rs = rsqrtf(var + 1e-5f);
      float sum = 0.f;
      for (int c = 0; c < DTSq; ++c){
        float e = fmaf(m, sw1[t][c], fmaf(d, sw0[t][c], sbc[t][c]));
        float n = fmaf(e * rs, sg[t][c], sbe[t][c]);
        sum += n * 0.5f * (1.0f + erff(n * 0.70710678118654752f));
      }
      maskbuf[(( (t * Bq + b) * Sq + i ) * Sq) + j] = sum * (1.0f / (float)DTSq);
      sc *= 0.1f;
    }
  }
}

// ---------------- generic fp32 tiled GEMM: C = act(A@W + bias) --------------
// A[M,K] row stride lda; W[K,N] row stride ldw; C row stride ldc.
// grid: x = N/64, y = M/64. act: 0 none, 1 gelu.
__global__ __launch_bounds__(256) void gemm_tiled(const float* __restrict__ A, int lda,
                                                  const float* __restrict__ W, int ldw,
                                                  const float* __restrict__ bias,
                                                  float* __restrict__ C, int ldc,
                                                  int K, int act){
  __shared__ float As[16][68];   // [k][row]
  __shared__ float Ws[16][68];   // [k][col]
  int tid = threadIdx.x;
  int tx = tid & 15, ty = tid >> 4;
  int brow = blockIdx.y * 64, bcol = blockIdx.x * 64;
  float acc[4][4] = {};
  for (int ko = 0; ko < K; ko += 16){
    #pragma unroll
    for (int l = tid; l < 1024; l += 256){
      int r = l >> 4, kk = l & 15;
      As[kk][r] = A[(brow + r) * lda + ko + kk];
    }
    #pragma unroll
    for (int l = tid; l < 1024; l += 256){
      int kk = l >> 6, c = l & 63;
      Ws[kk][c] = W[(ko + kk) * ldw + bcol + c];
    }
    __syncthreads();
    #pragma unroll
    for (int kk = 0; kk < 16; ++kk){
      float a0 = As[kk][ty * 4 + 0], a1 = As[kk][ty * 4 + 1];
      float a2 = As[kk][ty * 4 + 2], a3 = As[kk][ty * 4 + 3];
      float w0 = Ws[kk][tx * 4 + 0], w1 = Ws[kk][tx * 4 + 1];
      float w2 = Ws[kk][tx * 4 + 2], w3 = Ws[kk][tx * 4 + 3];
      acc[0][0] = fmaf(a0, w0, acc[0][0]); acc[0][1] = fmaf(a0, w1, acc[0][1]);
      acc[0][2] = fmaf(a0, w2, acc[0][2]); acc[0][3] = fmaf(a0, w3, acc[0][3]);
      acc[1][0] = fmaf(a1, w0, acc[1][0]); acc[1][1] = fmaf(a1, w1, acc[1][1]);
      acc[1][2] = fmaf(a1, w2, acc[1][2]); acc[1][3] = fmaf(a1, w3, acc[1][3]);
      acc[2][0] = fmaf(a2, w0, acc[2][0]); acc[2][1] = fmaf(a2, w1, acc[2][1]);
      acc[2][2] = fmaf(a2, w2, acc[2][2]); acc[2][3] = fmaf(a2, w3, acc[2][3]);
      acc[3][0] = fmaf(a3, w0, acc[3][0]); acc[3][1] = fmaf(a3, w1, acc[3][1]);
      acc[3][2] = fmaf(a3, w2, acc[3][2]); acc[3][3] = fmaf(a3, w3, acc[3][3]);
    }
    __syncthreads();
  }
  #pragma unroll
  for (int i = 0; i < 4; ++i){
    int r = brow + ty * 4 + i;
    #pragma unroll
    for (int j = 0; j < 4; ++j){
      int c = bcol + tx * 4 + j;
      float v = acc[i][j];
      if (bias) v += bias[c];
      if (act) v = gelu_f(v);
      C[r * ldc + c] = v;
    }
  }
}

// ---------------- attention scores: q·k^T/8 (+mask) -------------------------
// grid: x = jt (S/64), y = it (S/64), z = b*NH+h
__global__ __launch_bounds__(256) void attn_scores(const float* __restrict__ qkv,
                                                   const float* __restrict__ mask,
                                                   float* __restrict__ scores){
  int bh = blockIdx.z, b = bh >> 3, h = bh & 7;
  int io = blockIdx.y * 64, jo = blockIdx.x * 64;
  __shared__ float qs[64][68];  // [d][i]
  __shared__ float ks[64][68];  // [d][j]
  int tid = threadIdx.x, tx = tid & 15, ty = tid >> 4;
  for (int l = tid; l < 4096; l += 256){
    int r = l >> 6, d = l & 63;
    qs[d][r] = qkv[(b * Sq + io + r) * 1536 + h * 64 + d];
    ks[d][r] = qkv[(b * Sq + jo + r) * 1536 + 512 + h * 64 + d];
  }
  __syncthreads();
  float acc[4][4] = {};
  #pragma unroll 4
  for (int d = 0; d < 64; ++d){
    float a0 = qs[d][ty * 4 + 0], a1 = qs[d][ty * 4 + 1];
    float a2 = qs[d][ty * 4 + 2], a3 = qs[d][ty * 4 + 3];
    float w0 = ks[d][tx * 4 + 0], w1 = ks[d][tx * 4 + 1];
    float w2 = ks[d][tx * 4 + 2], w3 = ks[d][tx * 4 + 3];
    acc[0][0] = fmaf(a0, w0, acc[0][0]); acc[0][1] = fmaf(a0, w1, acc[0][1]);
    acc[0][2] = fmaf(a0, w2, acc[0][2]); acc[0][3] = fmaf(a0, w3, acc[0][3]);
    acc[1][0] = fmaf(a1, w0, acc[1][0]); acc[1][1] = fmaf(a1, w1, acc[1][1]);
    acc[1][2] = fmaf(a1, w2, acc[1][2]); acc[1][3] = fmaf(a1, w3, acc[1][3]);
    acc[2][0] = fmaf(a2, w0, acc[2][0]); acc[2][1] = fmaf(a2, w1, acc[2][1]);
    acc[2][2] = fmaf(a2, w2, acc[2][2]); acc[2][3] = fmaf(a2, w3, acc[2][3]);
    acc[3][0] = fmaf(a3, w0, acc[3][0]); acc[3][1] = fmaf(a3, w1, acc[3][1]);
    acc[3][2] = fmaf(a3, w2, acc[3][2]); acc[3][3] = fmaf(a3, w3, acc[3][3]);
  }
  #pragma unroll
  for (int i = 0; i < 4; ++i){
    int ii = io + ty * 4 + i;
    #pragma unroll
    for (int j = 0; j < 4; ++j){
      int jj = jo + tx * 4 + j;
      float v = acc[i][j] * 0.125f;
      if (mask) v += mask[(b * Sq + ii) * Sq + jj];
      scores[((size_t)bh * Sq + ii) * Sq + jj] = v;
    }
  }
}

// ---------------- row softmax over width 512 (in place) ---------------------
__global__ __launch_bounds__(256) void softmax_rows(float* __restrict__ scores){
  int row = blockIdx.x * 4 + (threadIdx.x >> 6);
  int lane = threadIdx.x & 63;
  float* sr = scores + (size_t)row * Sq;
  float x[8]; float mx = -1e30f;
  #pragma unroll
  for (int k = 0; k < 8; ++k){ x[k] = sr[lane + 64 * k]; mx = fmaxf(mx, x[k]); }
  mx = waveReduceMax(mx);
  float s = 0.f;
  #pragma unroll
  for (int k = 0; k < 8; ++k){ x[k] = __expf(x[k] - mx); s += x[k]; }
  s = waveReduceSum(s);
  float inv = 1.0f / s;
  #pragma unroll
  for (int k = 0; k < 8; ++k) sr[lane + 64 * k] = x[k] * inv;
}

// ---------------- attention PV: probs @ V → ctx -----------------------------
// grid: x = it (S/64), y = b*NH+h
__global__ __launch_bounds__(256) void attn_pv(const float* __restrict__ probs,
                                               const float* __restrict__ qkv,
                                               float* __restrict__ ctx){
  int bh = blockIdx.y, b = bh >> 3, h = bh & 7;
  int io = blockIdx.x * 64;
  __shared__ float ps[16][68];  // [j][i]
  __shared__ float vs[16][68];  // [j][d]
  int tid = threadIdx.x, tx = tid & 15, ty = tid >> 4;
  float acc[4][4] = {};
  for (int jo = 0; jo < Sq; jo += 16){
    #pragma unroll
    for (int l = tid; l < 1024; l += 256){
      int r = l >> 4, jj = l & 15;
      ps[jj][r] = probs[((size_t)bh * Sq + io + r) * Sq + jo + jj];
    }
    #pragma unroll
    for (int l = tid; l < 1024; l += 256){
      int jj = l >> 6, d = l & 63;
      vs[jj][d] = qkv[(b * Sq + jo + jj) * 1536 + 1024 + h * 64 + d];
    }
    __syncthreads();
    #pragma unroll
    for (int kk = 0; kk < 16; ++kk){
      float a0 = ps[kk][ty * 4 + 0], a1 = ps[kk][ty * 4 + 1];
      float a2 = ps[kk][ty * 4 + 2], a3 = ps[kk][ty * 4 + 3];
      float w0 = vs[kk][tx * 4 + 0], w1 = vs[kk][tx * 4 + 1];
      float w2 = vs[kk][tx * 4 + 2], w3 = vs[kk][tx * 4 + 3];
      acc[0][0] = fmaf(a0, w0, acc[0][0]); acc[0][1] = fmaf(a0, w1, acc[0][1]);
      acc[0][2] = fmaf(a0, w2, acc[0][2]); acc[0][3] = fmaf(a0, w3, acc[0][3]);
      acc[1][0] = fmaf(a1, w0, acc[1][0]); acc[1][1] = fmaf(a1, w1, acc[1][1]);
      acc[1][2] = fmaf(a1, w2, acc[1][2]); acc[1][3] = fmaf(a1, w3, acc[1][3]);
      acc[2][0] = fmaf(a2, w0, acc[2][0]); acc[2][1] = fmaf(a2, w1, acc[2][1]);
      acc[2][2] = fmaf(a2, w2, acc[2][2]); acc[2][3] = fmaf(a2, w3, acc[2][3]);
      acc[3][0] = fmaf(a3, w0, acc[3][0]); acc[3][1] = fmaf(a3, w1, acc[3][1]);
      acc[3][2] = fmaf(a3, w2, acc[3][2]); acc[3][3] = fmaf(a3, w3, acc[3][3]);
    }
    __syncthreads();
  }
  #pragma unroll
  for (int i = 0; i < 4; ++i){
    int r = b * Sq + io + ty * 4 + i;
    #pragma unroll
    for (int j = 0; j < 4; ++j){
      ctx[r * Hq + h * 64 + tx * 4 + j] = acc[i][j];
    }
  }
}

// ---------------- row LayerNorm (+residual, +gelu) width 512 ----------------
__global__ __launch_bounds__(256) void ln_rows(const float* __restrict__ in,
                                               const float* __restrict__ res,
                                               const float* __restrict__ g,
                                               const float* __restrict__ bb,
                                               float* __restrict__ out, int do_gelu){
  int row = blockIdx.x * 4 + (threadIdx.x >> 6);
  int lane = threadIdx.x & 63;
  const float* ir = in + (size_t)row * Hq;
  const float* rr = res ? res + (size_t)row * Hq : nullptr;
  float x[8]; float s = 0.f, sq = 0.f;
  #pragma unroll
  for (int k = 0; k < 8; ++k){
    int c = lane + 64 * k;
    float v = ir[c];
    if (rr) v += rr[c];
    x[k] = v; s += v; sq += v * v;
  }
  s = waveReduceSum(s); sq = waveReduceSum(sq);
  float mean = s * (1.0f / Hq);
  float var = fmaxf(sq * (1.0f / Hq) - mean * mean, 0.f);
  float rstd = rsqrtf(var + 1e-5f);
  float* orow = out + (size_t)row * Hq;
  #pragma unroll
  for (int k = 0; k < 8; ++k){
    int c = lane + 64 * k;
    float y = (x[k] - mean) * rstd * g[c] + bb[c];
    if (do_gelu) y = gelu_f(y);
    orow[c] = y;
  }
}

// ---------------- mixer second matmul + softmax over T ----------------------
__global__ __launch_bounds__(256) void mixer2_softmax(const float* __restrict__ m,
                                                      const float* __restrict__ W2,
                                                      const float* __restrict__ b2,
                                                      float* __restrict__ mix){
  int row = blockIdx.x * 4 + (threadIdx.x >> 6);
  int lane = threadIdx.x & 63;
  const float* mr = m + (size_t)row * Hq;
  float a0 = 0.f, a1 = 0.f, a2 = 0.f;
  for (int k = lane; k < Hq; k += 64){
    float v = mr[k];
    const float* w = W2 + k * 3;
    a0 = fmaf(v, w[0], a0); a1 = fmaf(v, w[1], a1); a2 = fmaf(v, w[2], a2);
  }
  a0 = waveReduceSum(a0); a1 = waveReduceSum(a1); a2 = waveReduceSum(a2);
  a0 += b2[0]; a1 += b2[1]; a2 += b2[2];
  float mx = fmaxf(a0, fmaxf(a1, a2));
  float e0 = __expf(a0 - mx), e1 = __expf(a1 - mx), e2 = __expf(a2 - mx);
  float inv = 1.0f / (e0 + e1 + e2);
  if (lane == 0){
    mix[row * 3 + 0] = e0 * inv;
    mix[row * 3 + 1] = e1 * inv;
    mix[row * 3 + 2] = e2 * inv;
  }
}

// ---------------- weighted sum of timescale outputs -------------------------
__global__ __launch_bounds__(256) void weighted_kernel(const float* __restrict__ comb,
                                                       const float* __restrict__ mix,
                                                       float* __restrict__ out){
  int idx = blockIdx.x * 256 + threadIdx.x;  // < 2048*512
  int r = idx >> 9, c = idx & 511;
  const float* cr = comb + (size_t)r * 1536;
  float m0 = mix[r * 3 + 0], m1 = mix[r * 3 + 1], m2 = mix[r * 3 + 2];
  out[idx] = m0 * cr[c] + m1 * cr[512 + c] + m2 * cr[1024 + c];
}

extern "C" void kernel_launch(void* const* d_in, const int* in_sizes, int n_in,
                              void* d_out, int out_size, void* d_ws, size_t ws_size,
                              hipStream_t stream){
  const float* x         = (const float*)d_in[0];
  const float* ts        = (const float*)d_in[1];
  const float* enc_W     = (const float*)d_in[2];
  const float* enc_b     = (const float*)d_in[3];
  const float* enc_ln_g  = (const float*)d_in[4];
  const float* enc_ln_b  = (const float*)d_in[5];
  const float* qkv_W     = (const float*)d_in[6];
  const float* qkv_b     = (const float*)d_in[7];
  const float* aout_W    = (const float*)d_in[8];
  const float* aout_b    = (const float*)d_in[9];
  const float* mx_W1     = (const float*)d_in[10];
  const float* mx_b1     = (const float*)d_in[11];
  const float* mx_ln_g   = (const float*)d_in[12];
  const float* mx_ln_b   = (const float*)d_in[13];
  const float* mx_W2     = (const float*)d_in[14];
  const float* mx_b2     = (const float*)d_in[15];
  const float* el_qkv_W  = (const float*)d_in[16];
  const float* el_qkv_b  = (const float*)d_in[17];
  const float* el_out_W  = (const float*)d_in[18];
  const float* el_out_b  = (const float*)d_in[19];
  const float* el_ln1_g  = (const float*)d_in[20];
  const float* el_ln1_b  = (const float*)d_in[21];
  const float* el_ff_W1  = (const float*)d_in[22];
  const float* el_ff_b1  = (const float*)d_in[23];
  const float* el_ff_W2  = (const float*)d_in[24];
  const float* el_ff_b2  = (const float*)d_in[25];
  const float* el_ln2_g  = (const float*)d_in[26];
  const float* el_ln2_b  = (const float*)d_in[27];
  const float* op_W      = (const float*)d_in[28];
  const float* op_b      = (const float*)d_in[29];
  const float* op_ln_g   = (const float*)d_in[30];
  const float* op_ln_b   = (const float*)d_in[31];

  float* ws = (float*)d_ws;
  size_t o = 0;
  float* MASKB  = ws + o; o += (size_t)Tq * Bq * Sq * Sq;   // 3,145,728
  float* COMB   = ws + o; o += (size_t)BSq * 1536;          // 3,145,728
  float* QKV    = ws + o; o += (size_t)BSq * 1536;          // 3,145,728
  float* SCORES = ws + o; o += (size_t)Bq * NHq * Sq * Sq;  // 8,388,608 (also FFN buf)
  float* CTX    = ws + o; o += (size_t)BSq * Hq;
  float* WEI    = ws + o; o += (size_t)BSq * Hq;            // also op-proj tmp
  float* MBUF   = ws + o; o += (size_t)BSq * Hq;
  float* MIX    = ws + o; o += (size_t)BSq * 4;
  float* SA     = ws + o; o += (size_t)BSq * Hq;            // also FFN output
  float* H1     = ws + o; o += (size_t)BSq * Hq;
  float* H2     = ws + o; o += (size_t)BSq * Hq;
  float* ENC    = ws + o; o += (size_t)Tq * ENCSTRIDE;
  float* FFB    = SCORES;   // [2048][2048] fits in scores region

  // 1. temporal masks
  enc_prep<<<Tq, 256, 0, stream>>>(enc_W, enc_b, ENC);
  mask_kernel<<<BSq, 256, 0, stream>>>(ts, ENC, enc_ln_g, enc_ln_b, MASKB);

  // 2. per-timescale masked attention → COMB[:, t*512:(t+1)*512]
  for (int t = 0; t < Tq; ++t){
    gemm_tiled<<<dim3(24, 32), 256, 0, stream>>>(x, Hq, qkv_W + (size_t)t * Hq * 1536, 1536,
                                                 qkv_b + t * 1536, QKV, 1536, Hq, 0);
    attn_scores<<<dim3(8, 8, 32), 256, 0, stream>>>(QKV, MASKB + (size_t)t * Bq * Sq * Sq, SCORES);
    softmax_rows<<<4096, 256, 0, stream>>>(SCORES);
    attn_pv<<<dim3(8, 32), 256, 0, stream>>>(SCORES, QKV, CTX);
    gemm_tiled<<<dim3(8, 32), 256, 0, stream>>>(CTX, Hq, aout_W + (size_t)t * Hq * Hq, Hq,
                                                aout_b + t * Hq, COMB + t * Hq, 1536, Hq, 0);
  }

  // 3. time mixer
  gemm_tiled<<<dim3(8, 32), 256, 0, stream>>>(COMB, 1536, mx_W1, Hq, mx_b1, MBUF, Hq, 1536, 0);
  ln_rows<<<512, 256, 0, stream>>>(MBUF, nullptr, mx_ln_g, mx_ln_b, MBUF, 1);
  mixer2_softmax<<<512, 256, 0, stream>>>(MBUF, mx_W2, mx_b2, MIX);
  weighted_kernel<<<4096, 256, 0, stream>>>(COMB, MIX, WEI);

  // 4. transformer encoder layer (post-norm)
  gemm_tiled<<<dim3(24, 32), 256, 0, stream>>>(WEI, Hq, el_qkv_W, 1536, el_qkv_b, QKV, 1536, Hq, 0);
  attn_scores<<<dim3(8, 8, 32), 256, 0, stream>>>(QKV, nullptr, SCORES);
  softmax_rows<<<4096, 256, 0, stream>>>(SCORES);
  attn_pv<<<dim3(8, 32), 256, 0, stream>>>(SCORES, QKV, CTX);
  gemm_tiled<<<dim3(8, 32), 256, 0, stream>>>(CTX, Hq, el_out_W, Hq, el_out_b, SA, Hq, Hq, 0);
  ln_rows<<<512, 256, 0, stream>>>(WEI, SA, el_ln1_g, el_ln1_b, H1, 0);
  gemm_tiled<<<dim3(32, 32), 256, 0, stream>>>(H1, Hq, el_ff_W1, 2048, el_ff_b1, FFB, 2048, Hq, 1);
  gemm_tiled<<<dim3(8, 32), 256, 0, stream>>>(FFB, 2048, el_ff_W2, Hq, el_ff_b2, SA, Hq, 2048, 0);
  ln_rows<<<512, 256, 0, stream>>>(H1, SA, el_ln2_g, el_ln2_b, H2, 0);

  // 5. output projection + final LN
  gemm_tiled<<<dim3(8, 32), 256, 0, stream>>>(H2, Hq, op_W, Hq, op_b, WEI, Hq, Hq, 0);
  ln_rows<<<512, 256, 0, stream>>>(WEI, nullptr, op_ln_g, op_ln_b, (float*)d_out, 0);
}

// Round 2
// 648.270 us; speedup vs baseline: 3.0167x; 3.0167x over previous
//
#include <hip/hip_runtime.h>
#include <hip/hip_bf16.h>
#include <math.h>

#define Bq 4
#define Sq 512
#define Hq 512
#define NHq 8
#define DHq 64
#define Tq 3
#define DTSq 170
#define BSq 2048
#define ENCSTRIDE 520
#define NLUT 2048
#define MAGMAXf 5.6304994f

typedef float f32x4 __attribute__((ext_vector_type(4)));
typedef __bf16 bf16x4 __attribute__((ext_vector_type(4)));
typedef __bf16 bf16x8 __attribute__((ext_vector_type(8)));

__device__ __forceinline__ float gelu_f(float x){
  return 0.5f * x * (1.0f + erff(x * 0.70710678118654752f));
}

__device__ __forceinline__ bf16x4 cvt4(float a, float b, float c, float d){
  bf16x4 r; r[0]=(__bf16)a; r[1]=(__bf16)b; r[2]=(__bf16)c; r[3]=(__bf16)d; return r;
}

__device__ __forceinline__ float waveReduceSum(float v){
  #pragma unroll
  for (int off = 32; off > 0; off >>= 1) v += __shfl_xor(v, off);
  return v;
}
__device__ __forceinline__ float waveReduceMax(float v){
  #pragma unroll
  for (int off = 32; off > 0; off >>= 1) v = fmaxf(v, __shfl_xor(v, off));
  return v;
}

__device__ __forceinline__ float blockReduce(float v, float* red){
  int tid = threadIdx.x;
  __syncthreads();
  red[tid] = v; __syncthreads();
  for (int s = 128; s > 0; s >>= 1){
    if (tid < s) red[tid] += red[tid + s];
    __syncthreads();
  }
  return red[0];
}

// ---------------- encoder prep: centered vectors + covariance scalars -------
__global__ __launch_bounds__(256) void enc_prep(const float* __restrict__ encW,
                                                const float* __restrict__ encB,
                                                float* __restrict__ out){
  int t = blockIdx.x, tid = threadIdx.x;
  __shared__ float red[256];
  const float* W0 = encW + t * 2 * DTSq;
  const float* W1 = W0 + DTSq;
  const float* Bv = encB + t * DTSq;
  float w0 = (tid < DTSq) ? W0[tid] : 0.f;
  float w1 = (tid < DTSq) ? W1[tid] : 0.f;
  float bv = (tid < DTSq) ? Bv[tid] : 0.f;
  const float invD = 1.0f / (float)DTSq;
  float m0 = blockReduce(w0, red) * invD;
  float m1 = blockReduce(w1, red) * invD;
  float mb = blockReduce(bv, red) * invD;
  float c0 = (tid < DTSq) ? (w0 - m0) : 0.f;
  float c1 = (tid < DTSq) ? (w1 - m1) : 0.f;
  float cb = (tid < DTSq) ? (bv - mb) : 0.f;
  float* op = out + t * ENCSTRIDE;
  if (tid < DTSq){
    op[tid] = c0; op[DTSq + tid] = c1; op[2 * DTSq + tid] = cb;
  }
  float pa = blockReduce(c0 * c0, red) * invD;
  float pb = blockReduce(c1 * c1, red) * invD;
  float pc = blockReduce(c0 * c1, red) * invD;
  float pd = blockReduce(c0 * cb, red) * invD;
  float pe = blockReduce(c1 * cb, red) * invD;
  float pf = blockReduce(cb * cb, red) * invD;
  if (tid == 0){
    op[3 * DTSq + 0] = pa; op[3 * DTSq + 1] = pb; op[3 * DTSq + 2] = pc;
    op[3 * DTSq + 3] = pd; op[3 * DTSq + 4] = pe; op[3 * DTSq + 5] = pf;
  }
}

// ---------------- mask LUT build: lut[t*3+dsel][NLUT] over mag --------------
__global__ __launch_bounds__(256) void mask_lut_build(const float* __restrict__ enc,
                                                      const float* __restrict__ g,
                                                      const float* __restrict__ be,
                                                      float* __restrict__ lut){
  int td = blockIdx.x;            // t*3 + dsel
  int t = td / 3, dsel = td % 3;
  float d = (float)(dsel - 1);
  __shared__ float sw0[DTSq], sw1[DTSq], sbc[DTSq], sg[DTSq], sbe[DTSq];
  const float* ep = enc + t * ENCSTRIDE;
  for (int c = threadIdx.x; c < DTSq; c += 256){
    sw0[c] = ep[c]; sw1[c] = ep[DTSq + c]; sbc[c] = ep[2 * DTSq + c];
    sg[c] = g[t * DTSq + c]; sbe[c] = be[t * DTSq + c];
  }
  __syncthreads();
  float A  = ep[3 * DTSq + 0], Bs = ep[3 * DTSq + 1], Cs = ep[3 * DTSq + 2];
  float Ds = ep[3 * DTSq + 3], Es = ep[3 * DTSq + 4], Fs = ep[3 * DTSq + 5];
  int e = blockIdx.y * 256 + threadIdx.x;
  float tscale = (t == 0) ? 1.f : ((t == 1) ? 0.1f : 0.01f);
  float m = (MAGMAXf / (float)(NLUT - 1)) * (float)e * tscale;
  float var = fabsf(d) * A + m * m * Bs + Fs + 2.f * (d * m * Cs + d * Ds + m * Es);
  float rs = rsqrtf(var + 1e-5f);
  float sum = 0.f;
  for (int c = 0; c < DTSq; ++c){
    float ee = fmaf(m, sw1[c], fmaf(d, sw0[c], sbc[c]));
    float n = fmaf(ee * rs, sg[c], sbe[c]);
    sum += n * 0.5f * (1.0f + erff(n * 0.70710678118654752f));
  }
  lut[td * NLUT + e] = sum * (1.0f / (float)DTSq);
}

// ---------------- mask fill via LUT interpolation ---------------------------
__global__ __launch_bounds__(256) void mask_fill(const float* __restrict__ ts,
                                                 const float* __restrict__ lut,
                                                 float* __restrict__ maskbuf){
  int bi = blockIdx.x;            // b*S + i
  int b = bi >> 9, i = bi & 511;
  float tsi = ts[bi];
  for (int j0 = 0; j0 < Sq; j0 += 256){
    int j = j0 + threadIdx.x;
    float dt = tsi - ts[(b << 9) + j];
    int dsel = (dt > 0.f) ? 2 : ((dt < 0.f) ? 0 : 1);
    float mag = log1pf(fabsf(dt) * (1.0f / 3600.0f));
    float u = mag * ((float)(NLUT - 1) / MAGMAXf);
    int i0 = (int)u; if (i0 > NLUT - 2) i0 = NLUT - 2;
    float f = u - (float)i0;
    #pragma unroll
    for (int t = 0; t < Tq; ++t){
      const float* lp = lut + (t * 3 + dsel) * NLUT + i0;
      float v = lp[0] + f * (lp[1] - lp[0]);
      maskbuf[(((size_t)(t * Bq + b) * Sq + i) * Sq) + j] = v;
    }
  }
}

// ---------------- bf16 MFMA GEMM: C = act(A@B + bias) -----------------------
// A[M,K] fp32 row-major lda; B[K,N] fp32 row-major ldw. Tile 128x128, BK=32.
__global__ __launch_bounds__(256) void gemm_mfma(const float* __restrict__ A, int lda,
                                                 const float* __restrict__ B, int ldw,
                                                 const float* __restrict__ bias,
                                                 float* __restrict__ C, int ldc,
                                                 int K, int act){
  __shared__ __bf16 As[128][40];   // [row][k], pad 32->40
  __shared__ __bf16 Bs[128][40];   // [col][k]
  int tid = threadIdx.x;
  int brow = blockIdx.y * 128, bcol = blockIdx.x * 128;
  int lane = tid & 63, w = tid >> 6;
  int wr = (w >> 1) * 64, wc = (w & 1) * 64;
  int lr = lane & 15, lg = lane >> 4;
  f32x4 acc[4][4];
  #pragma unroll
  for (int m = 0; m < 4; ++m)
    #pragma unroll
    for (int n = 0; n < 4; ++n) acc[m][n] = (f32x4){0.f, 0.f, 0.f, 0.f};
  int ar = tid >> 1, ak = (tid & 1) * 4;
  int bc_ = tid & 127, bg = (tid >> 7) * 4;
  for (int ko = 0; ko < K; ko += 32){
    #pragma unroll
    for (int q = 0; q < 4; ++q){
      int k0 = ak + q * 8;
      float4 v = *(const float4*)&A[(size_t)(brow + ar) * lda + ko + k0];
      *(bf16x4*)&As[ar][k0] = cvt4(v.x, v.y, v.z, v.w);
    }
    #pragma unroll
    for (int q = 0; q < 4; ++q){
      int k0 = bg + q * 8;
      const float* bp = &B[(size_t)(ko + k0) * ldw + bcol + bc_];
      *(bf16x4*)&Bs[bc_][k0] = cvt4(bp[0], bp[ldw], bp[2 * ldw], bp[3 * ldw]);
    }
    __syncthreads();
    bf16x8 a[4], bf[4];
    #pragma unroll
    for (int m = 0; m < 4; ++m) a[m] = *(const bf16x8*)&As[wr + m * 16 + lr][lg * 8];
    #pragma unroll
    for (int n = 0; n < 4; ++n) bf[n] = *(const bf16x8*)&Bs[wc + n * 16 + lr][lg * 8];
    #pragma unroll
    for (int m = 0; m < 4; ++m)
      #pragma unroll
      for (int n = 0; n < 4; ++n)
        acc[m][n] = __builtin_amdgcn_mfma_f32_16x16x32_bf16(a[m], bf[n], acc[m][n], 0, 0, 0);
    __syncthreads();
  }
  #pragma unroll
  for (int m = 0; m < 4; ++m){
    #pragma unroll
    for (int n = 0; n < 4; ++n){
      int col = bcol + wc + n * 16 + lr;
      float bv = bias ? bias[col] : 0.f;
      #pragma unroll
      for (int j = 0; j < 4; ++j){
        int row = brow + wr + m * 16 + lg * 4 + j;
        float v = acc[m][n][j] + bv;
        if (act) v = gelu_f(v);
        C[(size_t)row * ldc + col] = v;
      }
    }
  }
}

// ---------------- attention scores via MFMA: q·k^T/8 (+mask) ----------------
// grid: x = jt (S/128), y = it (S/128), z = b*NH+h
__global__ __launch_bounds__(256) void attn_scores_mfma(const float* __restrict__ qkv,
                                                        const float* __restrict__ mask,
                                                        float* __restrict__ scores){
  int bh = blockIdx.z, b = bh >> 3, h = bh & 7;
  int io = blockIdx.y * 128, jo = blockIdx.x * 128;
  __shared__ __bf16 Qs[128][72];   // [i][d], pad 64->72
  __shared__ __bf16 Ks[128][72];   // [j][d]
  int tid = threadIdx.x;
  int r = tid >> 1, d0b = (tid & 1) * 4;
  #pragma unroll
  for (int q = 0; q < 8; ++q){
    int d0 = d0b + q * 8;
    float4 qv = *(const float4*)&qkv[(size_t)(b * Sq + io + r) * 1536 + h * 64 + d0];
    float4 kv = *(const float4*)&qkv[(size_t)(b * Sq + jo + r) * 1536 + 512 + h * 64 + d0];
    *(bf16x4*)&Qs[r][d0] = cvt4(qv.x, qv.y, qv.z, qv.w);
    *(bf16x4*)&Ks[r][d0] = cvt4(kv.x, kv.y, kv.z, kv.w);
  }
  __syncthreads();
  int lane = tid & 63, w = tid >> 6;
  int wr = (w >> 1) * 64, wc = (w & 1) * 64;
  int lr = lane & 15, lg = lane >> 4;
  f32x4 acc[4][4];
  #pragma unroll
  for (int m = 0; m < 4; ++m)
    #pragma unroll
    for (int n = 0; n < 4; ++n) acc[m][n] = (f32x4){0.f, 0.f, 0.f, 0.f};
  #pragma unroll
  for (int s = 0; s < 2; ++s){
    bf16x8 a[4], bf[4];
    #pragma unroll
    for (int m = 0; m < 4; ++m) a[m] = *(const bf16x8*)&Qs[wr + m * 16 + lr][s * 32 + lg * 8];
    #pragma unroll
    for (int n = 0; n < 4; ++n) bf[n] = *(const bf16x8*)&Ks[wc + n * 16 + lr][s * 32 + lg * 8];
    #pragma unroll
    for (int m = 0; m < 4; ++m)
      #pragma unroll
      for (int n = 0; n < 4; ++n)
        acc[m][n] = __builtin_amdgcn_mfma_f32_16x16x32_bf16(a[m], bf[n], acc[m][n], 0, 0, 0);
  }
  #pragma unroll
  for (int m = 0; m < 4; ++m){
    #pragma unroll
    for (int n = 0; n < 4; ++n){
      int jj = jo + wc + n * 16 + lr;
      #pragma unroll
      for (int j = 0; j < 4; ++j){
        int ii = io + wr + m * 16 + lg * 4 + j;
        float v = acc[m][n][j] * 0.125f;
        if (mask) v += mask[(size_t)(b * Sq + ii) * Sq + jj];
        scores[((size_t)bh * Sq + ii) * Sq + jj] = v;
      }
    }
  }
}

// ---------------- row softmax over width 512 (in place) ---------------------
__global__ __launch_bounds__(256) void softmax_rows(float* __restrict__ scores){
  int row = blockIdx.x * 4 + (threadIdx.x >> 6);
  int lane = threadIdx.x & 63;
  float* sr = scores + (size_t)row * Sq;
  float x[8]; float mx = -1e30f;
  #pragma unroll
  for (int k = 0; k < 8; ++k){ x[k] = sr[lane + 64 * k]; mx = fmaxf(mx, x[k]); }
  mx = waveReduceMax(mx);
  float s = 0.f;
  #pragma unroll
  for (int k = 0; k < 8; ++k){ x[k] = __expf(x[k] - mx); s += x[k]; }
  s = waveReduceSum(s);
  float inv = 1.0f / s;
  #pragma unroll
  for (int k = 0; k < 8; ++k) sr[lane + 64 * k] = x[k] * inv;
}

// ---------------- attention PV via MFMA: probs @ V → ctx --------------------
// grid: x = it (S/128), y = b*NH+h. BM=128, BN=64, BK=32.
__global__ __launch_bounds__(256) void attn_pv_mfma(const float* __restrict__ probs,
                                                    const float* __restrict__ qkv,
                                                    float* __restrict__ ctx){
  int bh = blockIdx.y, b = bh >> 3, h = bh & 7;
  int io = blockIdx.x * 128;
  __shared__ __bf16 Ps[128][40];   // [i][j-chunk]
  __shared__ __bf16 Vs[64][40];    // [d][j-chunk]
  int tid = threadIdx.x;
  int pr = tid >> 1, pk = (tid & 1) * 4;
  int vd = tid & 63, vg = (tid >> 6) * 4;
  int lane = tid & 63, w = tid >> 6;
  int wr = w * 32;
  int lr = lane & 15, lg = lane >> 4;
  f32x4 acc[2][4];
  #pragma unroll
  for (int m = 0; m < 2; ++m)
    #pragma unroll
    for (int n = 0; n < 4; ++n) acc[m][n] = (f32x4){0.f, 0.f, 0.f, 0.f};
  for (int jo = 0; jo < Sq; jo += 32){
    #pragma unroll
    for (int q = 0; q < 4; ++q){
      int k0 = pk + q * 8;
      float4 v = *(const float4*)&probs[((size_t)bh * Sq + io + pr) * Sq + jo + k0];
      *(bf16x4*)&Ps[pr][k0] = cvt4(v.x, v.y, v.z, v.w);
    }
    #pragma unroll
    for (int q = 0; q < 2; ++q){
      int k0 = vg + q * 16;
      const float* vp = &qkv[(size_t)(b * Sq + jo + k0) * 1536 + 1024 + h * 64 + vd];
      *(bf16x4*)&Vs[vd][k0] = cvt4(vp[0], vp[1536], vp[2 * 1536], vp[3 * 1536]);
    }
    __syncthreads();
    bf16x8 a[2], bf[4];
    #pragma unroll
    for (int m = 0; m < 2; ++m) a[m] = *(const bf16x8*)&Ps[wr + m * 16 + lr][lg * 8];
    #pragma unroll
    for (int n = 0; n < 4; ++n) bf[n] = *(const bf16x8*)&Vs[n * 16 + lr][lg * 8];
    #pragma unroll
    for (int m = 0; m < 2; ++m)
      #pragma unroll
      for (int n = 0; n < 4; ++n)
        acc[m][n] = __builtin_amdgcn_mfma_f32_16x16x32_bf16(a[m], bf[n], acc[m][n], 0, 0, 0);
    __syncthreads();
  }
  #pragma unroll
  for (int m = 0; m < 2; ++m){
    #pragma unroll
    for (int n = 0; n < 4; ++n){
      int col = h * 64 + n * 16 + lr;
      #pragma unroll
      for (int j = 0; j < 4; ++j){
        int row = b * Sq + io + wr + m * 16 + lg * 4 + j;
        ctx[(size_t)row * Hq + col] = acc[m][n][j];
      }
    }
  }
}

// ---------------- row LayerNorm (+residual, +gelu) width 512 ----------------
__global__ __launch_bounds__(256) void ln_rows(const float* __restrict__ in,
                                               const float* __restrict__ res,
                                               const float* __restrict__ g,
                                               const float* __restrict__ bb,
                                               float* __restrict__ out, int do_gelu){
  int row = blockIdx.x * 4 + (threadIdx.x >> 6);
  int lane = threadIdx.x & 63;
  const float* ir = in + (size_t)row * Hq;
  const float* rr = res ? res + (size_t)row * Hq : nullptr;
  float x[8]; float s = 0.f, sq = 0.f;
  #pragma unroll
  for (int k = 0; k < 8; ++k){
    int c = lane + 64 * k;
    float v = ir[c];
    if (rr) v += rr[c];
    x[k] = v; s += v; sq += v * v;
  }
  s = waveReduceSum(s); sq = waveReduceSum(sq);
  float mean = s * (1.0f / Hq);
  float var = fmaxf(sq * (1.0f / Hq) - mean * mean, 0.f);
  float rstd = rsqrtf(var + 1e-5f);
  float* orow = out + (size_t)row * Hq;
  #pragma unroll
  for (int k = 0; k < 8; ++k){
    int c = lane + 64 * k;
    float y = (x[k] - mean) * rstd * g[c] + bb[c];
    if (do_gelu) y = gelu_f(y);
    orow[c] = y;
  }
}

// ---------------- mixer second matmul + softmax over T ----------------------
__global__ __launch_bounds__(256) void mixer2_softmax(const float* __restrict__ m,
                                                      const float* __restrict__ W2,
                                                      const float* __restrict__ b2,
                                                      float* __restrict__ mix){
  int row = blockIdx.x * 4 + (threadIdx.x >> 6);
  int lane = threadIdx.x & 63;
  const float* mr = m + (size_t)row * Hq;
  float a0 = 0.f, a1 = 0.f, a2 = 0.f;
  for (int k = lane; k < Hq; k += 64){
    float v = mr[k];
    const float* w = W2 + k * 3;
    a0 = fmaf(v, w[0], a0); a1 = fmaf(v, w[1], a1); a2 = fmaf(v, w[2], a2);
  }
  a0 = waveReduceSum(a0); a1 = waveReduceSum(a1); a2 = waveReduceSum(a2);
  a0 += b2[0]; a1 += b2[1]; a2 += b2[2];
  float mx = fmaxf(a0, fmaxf(a1, a2));
  float e0 = __expf(a0 - mx), e1 = __expf(a1 - mx), e2 = __expf(a2 - mx);
  float inv = 1.0f / (e0 + e1 + e2);
  if (lane == 0){
    mix[row * 3 + 0] = e0 * inv;
    mix[row * 3 + 1] = e1 * inv;
    mix[row * 3 + 2] = e2 * inv;
  }
}

// ---------------- weighted sum of timescale outputs -------------------------
__global__ __launch_bounds__(256) void weighted_kernel(const float* __restrict__ comb,
                                                       const float* __restrict__ mix,
                                                       float* __restrict__ out){
  int idx = blockIdx.x * 256 + threadIdx.x;  // < 2048*512
  int r = idx >> 9, c = idx & 511;
  const float* cr = comb + (size_t)r * 1536;
  float m0 = mix[r * 3 + 0], m1 = mix[r * 3 + 1], m2 = mix[r * 3 + 2];
  out[idx] = m0 * cr[c] + m1 * cr[512 + c] + m2 * cr[1024 + c];
}

extern "C" void kernel_launch(void* const* d_in, const int* in_sizes, int n_in,
                              void* d_out, int out_size, void* d_ws, size_t ws_size,
                              hipStream_t stream){
  const float* x         = (const float*)d_in[0];
  const float* ts        = (const float*)d_in[1];
  const float* enc_W     = (const float*)d_in[2];
  const float* enc_b     = (const float*)d_in[3];
  const float* enc_ln_g  = (const float*)d_in[4];
  const float* enc_ln_b  = (const float*)d_in[5];
  const float* qkv_W     = (const float*)d_in[6];
  const float* qkv_b     = (const float*)d_in[7];
  const float* aout_W    = (const float*)d_in[8];
  const float* aout_b    = (const float*)d_in[9];
  const float* mx_W1     = (const float*)d_in[10];
  const float* mx_b1     = (const float*)d_in[11];
  const float* mx_ln_g   = (const float*)d_in[12];
  const float* mx_ln_b   = (const float*)d_in[13];
  const float* mx_W2     = (const float*)d_in[14];
  const float* mx_b2     = (const float*)d_in[15];
  const float* el_qkv_W  = (const float*)d_in[16];
  const float* el_qkv_b  = (const float*)d_in[17];
  const float* el_out_W  = (const float*)d_in[18];
  const float* el_out_b  = (const float*)d_in[19];
  const float* el_ln1_g  = (const float*)d_in[20];
  const float* el_ln1_b  = (const float*)d_in[21];
  const float* el_ff_W1  = (const float*)d_in[22];
  const float* el_ff_b1  = (const float*)d_in[23];
  const float* el_ff_W2  = (const float*)d_in[24];
  const float* el_ff_b2  = (const float*)d_in[25];
  const float* el_ln2_g  = (const float*)d_in[26];
  const float* el_ln2_b  = (const float*)d_in[27];
  const float* op_W      = (const float*)d_in[28];
  const float* op_b      = (const float*)d_in[29];
  const float* op_ln_g   = (const float*)d_in[30];
  const float* op_ln_b   = (const float*)d_in[31];

  float* ws = (float*)d_ws;
  size_t o = 0;
  float* MASKB  = ws + o; o += (size_t)Tq * Bq * Sq * Sq;
  float* COMB   = ws + o; o += (size_t)BSq * 1536;
  float* QKV    = ws + o; o += (size_t)BSq * 1536;
  float* SCORES = ws + o; o += (size_t)Bq * NHq * Sq * Sq;  // also FFN buf
  float* CTX    = ws + o; o += (size_t)BSq * Hq;
  float* WEI    = ws + o; o += (size_t)BSq * Hq;
  float* MBUF   = ws + o; o += (size_t)BSq * Hq;
  float* MIX    = ws + o; o += (size_t)BSq * 4;
  float* SA     = ws + o; o += (size_t)BSq * Hq;
  float* H1     = ws + o; o += (size_t)BSq * Hq;
  float* H2     = ws + o; o += (size_t)BSq * Hq;
  float* ENC    = ws + o; o += (size_t)Tq * ENCSTRIDE;
  float* LUTB   = ws + o; o += (size_t)9 * NLUT;
  float* FFB    = SCORES;

  // 1. temporal masks (analytic LN + LUT over the univariate mag dependence)
  enc_prep<<<Tq, 256, 0, stream>>>(enc_W, enc_b, ENC);
  mask_lut_build<<<dim3(9, NLUT / 256), 256, 0, stream>>>(ENC, enc_ln_g, enc_ln_b, LUTB);
  mask_fill<<<BSq, 256, 0, stream>>>(ts, LUTB, MASKB);

  // 2. per-timescale masked attention → COMB[:, t*512:(t+1)*512]
  for (int t = 0; t < Tq; ++t){
    gemm_mfma<<<dim3(12, 16), 256, 0, stream>>>(x, Hq, qkv_W + (size_t)t * Hq * 1536, 1536,
                                                qkv_b + t * 1536, QKV, 1536, Hq, 0);
    attn_scores_mfma<<<dim3(4, 4, 32), 256, 0, stream>>>(QKV, MASKB + (size_t)t * Bq * Sq * Sq, SCORES);
    softmax_rows<<<4096, 256, 0, stream>>>(SCORES);
    attn_pv_mfma<<<dim3(4, 32), 256, 0, stream>>>(SCORES, QKV, CTX);
    gemm_mfma<<<dim3(4, 16), 256, 0, stream>>>(CTX, Hq, aout_W + (size_t)t * Hq * Hq, Hq,
                                               aout_b + t * Hq, COMB + t * Hq, 1536, Hq, 0);
  }

  // 3. time mixer
  gemm_mfma<<<dim3(4, 16), 256, 0, stream>>>(COMB, 1536, mx_W1, Hq, mx_b1, MBUF, Hq, 1536, 0);
  ln_rows<<<512, 256, 0, stream>>>(MBUF, nullptr, mx_ln_g, mx_ln_b, MBUF, 1);
  mixer2_softmax<<<512, 256, 0, stream>>>(MBUF, mx_W2, mx_b2, MIX);
  weighted_kernel<<<4096, 256, 0, stream>>>(COMB, MIX, WEI);

  // 4. transformer encoder layer (post-norm)
  gemm_mfma<<<dim3(12, 16), 256, 0, stream>>>(WEI, Hq, el_qkv_W, 1536, el_qkv_b, QKV, 1536, Hq, 0);
  attn_scores_mfma<<<dim3(4, 4, 32), 256, 0, stream>>>(QKV, nullptr, SCORES);
  softmax_rows<<<4096, 256, 0, stream>>>(SCORES);
  attn_pv_mfma<<<dim3(4, 32), 256, 0, stream>>>(SCORES, QKV, CTX);
  gemm_mfma<<<dim3(4, 16), 256, 0, stream>>>(CTX, Hq, el_out_W, Hq, el_out_b, SA, Hq, Hq, 0);
  ln_rows<<<512, 256, 0, stream>>>(WEI, SA, el_ln1_g, el_ln1_b, H1, 0);
  gemm_mfma<<<dim3(16, 16), 256, 0, stream>>>(H1, Hq, el_ff_W1, 2048, el_ff_b1, FFB, 2048, Hq, 1);
  gemm_mfma<<<dim3(4, 16), 256, 0, stream>>>(FFB, 2048, el_ff_W2, Hq, el_ff_b2, SA, Hq, 2048, 0);
  ln_rows<<<512, 256, 0, stream>>>(H1, SA, el_ln2_g, el_ln2_b, H2, 0);

  // 5. output projection + final LN
  gemm_mfma<<<dim3(4, 16), 256, 0, stream>>>(H2, Hq, op_W, Hq, op_b, WEI, Hq, Hq, 0);
  ln_rows<<<512, 256, 0, stream>>>(WEI, nullptr, op_ln_g, op_ln_b, (float*)d_out, 0);
}

// Round 3
// 429.145 us; speedup vs baseline: 4.5571x; 1.5106x over previous
//
#include <hip/hip_runtime.h>
#include <hip/hip_bf16.h>
#include <math.h>

#define Bq 4
#define Sq 512
#define Hq 512
#define NHq 8
#define Tq 3
#define DTSq 170
#define BSq 2048
#define ENCSTRIDE 520
#define NLUT 2048
#define MAGMAXf 5.6304994f

typedef float f32x4 __attribute__((ext_vector_type(4)));
typedef __bf16 bf16x4 __attribute__((ext_vector_type(4)));
typedef __bf16 bf16x8 __attribute__((ext_vector_type(8)));

__device__ __forceinline__ float gelu_f(float x){
  return 0.5f * x * (1.0f + erff(x * 0.70710678118654752f));
}

__device__ __forceinline__ float waveReduceSum(float v){
  #pragma unroll
  for (int off = 32; off > 0; off >>= 1) v += __shfl_xor(v, off);
  return v;
}
__device__ __forceinline__ float waveReduceMax(float v){
  #pragma unroll
  for (int off = 32; off > 0; off >>= 1) v = fmaxf(v, __shfl_xor(v, off));
  return v;
}

__device__ __forceinline__ float blockReduce(float v, float* red){
  int tid = threadIdx.x;
  __syncthreads();
  red[tid] = v; __syncthreads();
  for (int s = 128; s > 0; s >>= 1){
    if (tid < s) red[tid] += red[tid + s];
    __syncthreads();
  }
  return red[0];
}

// ---------------- encoder prep: centered vectors + covariance scalars -------
__global__ __launch_bounds__(256) void enc_prep(const float* __restrict__ encW,
                                                const float* __restrict__ encB,
                                                float* __restrict__ out){
  int t = blockIdx.x, tid = threadIdx.x;
  __shared__ float red[256];
  const float* W0 = encW + t * 2 * DTSq;
  const float* W1 = W0 + DTSq;
  const float* Bv = encB + t * DTSq;
  float w0 = (tid < DTSq) ? W0[tid] : 0.f;
  float w1 = (tid < DTSq) ? W1[tid] : 0.f;
  float bv = (tid < DTSq) ? Bv[tid] : 0.f;
  const float invD = 1.0f / (float)DTSq;
  float m0 = blockReduce(w0, red) * invD;
  float m1 = blockReduce(w1, red) * invD;
  float mb = blockReduce(bv, red) * invD;
  float c0 = (tid < DTSq) ? (w0 - m0) : 0.f;
  float c1 = (tid < DTSq) ? (w1 - m1) : 0.f;
  float cb = (tid < DTSq) ? (bv - mb) : 0.f;
  float* op = out + t * ENCSTRIDE;
  if (tid < DTSq){
    op[tid] = c0; op[DTSq + tid] = c1; op[2 * DTSq + tid] = cb;
  }
  float pa = blockReduce(c0 * c0, red) * invD;
  float pb = blockReduce(c1 * c1, red) * invD;
  float pc = blockReduce(c0 * c1, red) * invD;
  float pd = blockReduce(c0 * cb, red) * invD;
  float pe = blockReduce(c1 * cb, red) * invD;
  float pf = blockReduce(cb * cb, red) * invD;
  if (tid == 0){
    op[3 * DTSq + 0] = pa; op[3 * DTSq + 1] = pb; op[3 * DTSq + 2] = pc;
    op[3 * DTSq + 3] = pd; op[3 * DTSq + 4] = pe; op[3 * DTSq + 5] = pf;
  }
}

// ---------------- mask LUT build ---------------------------------------------
__global__ __launch_bounds__(256) void mask_lut_build(const float* __restrict__ enc,
                                                      const float* __restrict__ g,
                                                      const float* __restrict__ be,
                                                      float* __restrict__ lut){
  int td = blockIdx.x;            // t*3 + dsel
  int t = td / 3, dsel = td % 3;
  float d = (float)(dsel - 1);
  __shared__ float sw0[DTSq], sw1[DTSq], sbc[DTSq], sg[DTSq], sbe[DTSq];
  const float* ep = enc + t * ENCSTRIDE;
  for (int c = threadIdx.x; c < DTSq; c += 256){
    sw0[c] = ep[c]; sw1[c] = ep[DTSq + c]; sbc[c] = ep[2 * DTSq + c];
    sg[c] = g[t * DTSq + c]; sbe[c] = be[t * DTSq + c];
  }
  __syncthreads();
  float A  = ep[3 * DTSq + 0], Bs = ep[3 * DTSq + 1], Cs = ep[3 * DTSq + 2];
  float Ds = ep[3 * DTSq + 3], Es = ep[3 * DTSq + 4], Fs = ep[3 * DTSq + 5];
  int e = blockIdx.y * 256 + threadIdx.x;
  float tscale = (t == 0) ? 1.f : ((t == 1) ? 0.1f : 0.01f);
  float m = (MAGMAXf / (float)(NLUT - 1)) * (float)e * tscale;
  float var = fabsf(d) * A + m * m * Bs + Fs + 2.f * (d * m * Cs + d * Ds + m * Es);
  float rs = rsqrtf(var + 1e-5f);
  float sum = 0.f;
  for (int c = 0; c < DTSq; ++c){
    float ee = fmaf(m, sw1[c], fmaf(d, sw0[c], sbc[c]));
    float n = fmaf(ee * rs, sg[c], sbe[c]);
    sum += n * 0.5f * (1.0f + erff(n * 0.70710678118654752f));
  }
  lut[td * NLUT + e] = sum * (1.0f / (float)DTSq);
}

// ---------------- mask fill via LUT interpolation (bf16 out) -----------------
__global__ __launch_bounds__(256) void mask_fill(const float* __restrict__ ts,
                                                 const float* __restrict__ lut,
                                                 __bf16* __restrict__ maskbuf){
  int bi = blockIdx.x;            // b*S + i
  int b = bi >> 9, i = bi & 511;
  float tsi = ts[bi];
  for (int j0 = 0; j0 < Sq; j0 += 256){
    int j = j0 + threadIdx.x;
    float dt = tsi - ts[(b << 9) + j];
    int dsel = (dt > 0.f) ? 2 : ((dt < 0.f) ? 0 : 1);
    float mag = log1pf(fabsf(dt) * (1.0f / 3600.0f));
    float u = mag * ((float)(NLUT - 1) / MAGMAXf);
    int i0 = (int)u; if (i0 > NLUT - 2) i0 = NLUT - 2;
    float f = u - (float)i0;
    #pragma unroll
    for (int t = 0; t < Tq; ++t){
      const float* lp = lut + (t * 3 + dsel) * NLUT + i0;
      float v = lp[0] + f * (lp[1] - lp[0]);
      maskbuf[(((size_t)(t * Bq + b) * Sq + i) * Sq) + j] = (__bf16)v;
    }
  }
}

// ---------------- weight transpose-convert: W[K][N] f32 -> WT[N][K] bf16 -----
__global__ __launch_bounds__(256) void cvt_wT(const float* __restrict__ W, int ldw, size_t sWz,
                                              __bf16* __restrict__ WT, int ldt, size_t sTz){
  int z = blockIdx.z;
  W  += (size_t)z * sWz;
  WT += (size_t)z * sTz;
  int n0 = blockIdx.x * 64, k0 = blockIdx.y * 64;
  __shared__ float T[64][65];
  int tid = threadIdx.x;
  #pragma unroll
  for (int q = 0; q < 16; ++q){
    int lin = q * 256 + tid;
    int r = lin >> 6, c = lin & 63;
    T[r][c] = W[(size_t)(k0 + r) * ldw + n0 + c];
  }
  __syncthreads();
  #pragma unroll
  for (int q = 0; q < 16; ++q){
    int lin = q * 256 + tid;
    int n = lin >> 6, k = lin & 63;
    WT[(size_t)(n0 + n) * ldt + k0 + k] = (__bf16)T[k][n];
  }
}

// ---------------- elementwise f32 -> bf16 ------------------------------------
__global__ __launch_bounds__(256) void cvt_bf(const float* __restrict__ in,
                                              __bf16* __restrict__ out, int n){
  int idx = (blockIdx.x * 256 + threadIdx.x) * 4;
  if (idx < n){
    float4 v = *(const float4*)&in[idx];
    bf16x4 r; r[0]=(__bf16)v.x; r[1]=(__bf16)v.y; r[2]=(__bf16)v.z; r[3]=(__bf16)v.w;
    *(bf16x4*)&out[idx] = r;
  }
}

// ---------------- bf16 MFMA GEMM: C = act(A @ BT^T + bias) -------------------
// A[M][lda] bf16; BT[N][ldb] bf16 (B transposed, k-contiguous). BM x 64 tile.
template<int BM>
__global__ __launch_bounds__(256) void gemm_bf(
    const __bf16* __restrict__ A, int lda, size_t sAz,
    const __bf16* __restrict__ BT, int ldb, size_t sBz,
    const float* __restrict__ bias, int sBiasz,
    float* __restrict__ C32, __bf16* __restrict__ C16, int ldc, size_t sCz,
    int K, int act)
{
  constexpr int MF = BM / 32;
  __shared__ __bf16 As[BM][72];
  __shared__ __bf16 Bs[64][72];
  int tid = threadIdx.x;
  int z = blockIdx.z;
  A  += (size_t)z * sAz;
  BT += (size_t)z * sBz;
  const float* bz = bias ? bias + (size_t)z * sBiasz : nullptr;
  size_t cbase = (size_t)z * sCz;
  int brow = blockIdx.y * BM, bcol = blockIdx.x * 64;
  int lane = tid & 63, w = tid >> 6;
  int wr = (w >> 1) * (BM / 2), wc = (w & 1) * 32;
  int lr = lane & 15, lg = lane >> 4;
  f32x4 acc[MF][2];
  #pragma unroll
  for (int m = 0; m < MF; ++m)
    #pragma unroll
    for (int n = 0; n < 2; ++n) acc[m][n] = (f32x4){0.f, 0.f, 0.f, 0.f};
  for (int ko = 0; ko < K; ko += 64){
    #pragma unroll
    for (int q = 0; q < MF; ++q){
      int lin = q * 256 + tid;
      int r = lin >> 3, c0 = (lin & 7) * 8;
      *(bf16x8*)&As[r][c0] = *(const bf16x8*)&A[(size_t)(brow + r) * lda + ko + c0];
    }
    #pragma unroll
    for (int q = 0; q < 2; ++q){
      int lin = q * 256 + tid;
      int r = lin >> 3, c0 = (lin & 7) * 8;
      *(bf16x8*)&Bs[r][c0] = *(const bf16x8*)&BT[(size_t)(bcol + r) * ldb + ko + c0];
    }
    __syncthreads();
    #pragma unroll
    for (int s = 0; s < 2; ++s){
      bf16x8 af[MF], bfr[2];
      #pragma unroll
      for (int m = 0; m < MF; ++m) af[m] = *(const bf16x8*)&As[wr + m * 16 + lr][s * 32 + lg * 8];
      #pragma unroll
      for (int n = 0; n < 2; ++n) bfr[n] = *(const bf16x8*)&Bs[wc + n * 16 + lr][s * 32 + lg * 8];
      #pragma unroll
      for (int m = 0; m < MF; ++m)
        #pragma unroll
        for (int n = 0; n < 2; ++n)
          acc[m][n] = __builtin_amdgcn_mfma_f32_16x16x32_bf16(af[m], bfr[n], acc[m][n], 0, 0, 0);
    }
    __syncthreads();
  }
  #pragma unroll
  for (int m = 0; m < MF; ++m){
    #pragma unroll
    for (int n = 0; n < 2; ++n){
      int col = bcol + wc + n * 16 + lr;
      float bv = bz ? bz[col] : 0.f;
      #pragma unroll
      for (int j = 0; j < 4; ++j){
        int row = brow + wr + m * 16 + lg * 4 + j;
        float v = acc[m][n][j] + bv;
        if (act) v = gelu_f(v);
        size_t idx = cbase + (size_t)row * ldc + col;
        if (C32) C32[idx] = v;
        if (C16) C16[idx] = (__bf16)v;
      }
    }
  }
}

// ---------------- attention scores: q·k^T/8 (+mask) --------------------------
__global__ __launch_bounds__(256) void attn_scores_bf(
    const __bf16* __restrict__ qkv,   // [2048][1536] (one timescale)
    const __bf16* __restrict__ mask,  // [4][512][512] bf16 or null
    float* __restrict__ scores)       // [32][512][512]
{
  int bh = blockIdx.z, b = bh >> 3, h = bh & 7;
  int io = blockIdx.y * 128, jo = blockIdx.x * 128;
  __shared__ __bf16 Qs[128][72], Ks[128][72];
  int tid = threadIdx.x;
  #pragma unroll
  for (int q = 0; q < 4; ++q){
    int lin = q * 256 + tid;
    int r = lin >> 3, c0 = (lin & 7) * 8;
    *(bf16x8*)&Qs[r][c0] = *(const bf16x8*)&qkv[(size_t)(b * Sq + io + r) * 1536 + h * 64 + c0];
    *(bf16x8*)&Ks[r][c0] = *(const bf16x8*)&qkv[(size_t)(b * Sq + jo + r) * 1536 + 512 + h * 64 + c0];
  }
  __syncthreads();
  int lane = tid & 63, w = tid >> 6;
  int wr = (w >> 1) * 64, wc = (w & 1) * 64;
  int lr = lane & 15, lg = lane >> 4;
  f32x4 acc[4][4];
  #pragma unroll
  for (int m = 0; m < 4; ++m)
    #pragma unroll
    for (int n = 0; n < 4; ++n) acc[m][n] = (f32x4){0.f, 0.f, 0.f, 0.f};
  #pragma unroll
  for (int s = 0; s < 2; ++s){
    bf16x8 af[4], bfr[4];
    #pragma unroll
    for (int m = 0; m < 4; ++m) af[m] = *(const bf16x8*)&Qs[wr + m * 16 + lr][s * 32 + lg * 8];
    #pragma unroll
    for (int n = 0; n < 4; ++n) bfr[n] = *(const bf16x8*)&Ks[wc + n * 16 + lr][s * 32 + lg * 8];
    #pragma unroll
    for (int m = 0; m < 4; ++m)
      #pragma unroll
      for (int n = 0; n < 4; ++n)
        acc[m][n] = __builtin_amdgcn_mfma_f32_16x16x32_bf16(af[m], bfr[n], acc[m][n], 0, 0, 0);
  }
  #pragma unroll
  for (int m = 0; m < 4; ++m){
    #pragma unroll
    for (int n = 0; n < 4; ++n){
      int jj = jo + wc + n * 16 + lr;
      #pragma unroll
      for (int j = 0; j < 4; ++j){
        int ii = io + wr + m * 16 + lg * 4 + j;
        float v = acc[m][n][j] * 0.125f;
        if (mask) v += (float)mask[(size_t)(b * Sq + ii) * Sq + jj];
        scores[((size_t)bh * Sq + ii) * Sq + jj] = v;
      }
    }
  }
}

// ---------------- row softmax fp32 -> bf16 probs (in place, half row) --------
__global__ __launch_bounds__(256) void softmax_bf(float* __restrict__ scores){
  int row = blockIdx.x * 4 + (threadIdx.x >> 6);
  int lane = threadIdx.x & 63;
  float* sr = scores + (size_t)row * Sq;
  float x[8]; float mx = -1e30f;
  #pragma unroll
  for (int k = 0; k < 8; ++k){ x[k] = sr[lane + 64 * k]; mx = fmaxf(mx, x[k]); }
  mx = waveReduceMax(mx);
  float s = 0.f;
  #pragma unroll
  for (int k = 0; k < 8; ++k){ x[k] = __expf(x[k] - mx); s += x[k]; }
  s = waveReduceSum(s);
  float inv = 1.0f / s;
  __bf16* pr = (__bf16*)sr;      // probs overlay: row stride 1024 bf16 elems
  #pragma unroll
  for (int k = 0; k < 8; ++k) pr[lane + 64 * k] = (__bf16)(x[k] * inv);
}

// ---------------- V transpose per head: [s][d] -> [d][s] ---------------------
__global__ __launch_bounds__(256) void transpose_v(const __bf16* __restrict__ qkv,
                                                   __bf16* __restrict__ vt){
  int bh = blockIdx.y, b = bh >> 3, h = bh & 7;
  int so = blockIdx.x * 64;
  __shared__ __bf16 T[64][72];
  int tid = threadIdx.x;
  #pragma unroll
  for (int q = 0; q < 16; ++q){
    int lin = q * 256 + tid;
    int r = lin >> 6, c = lin & 63;
    T[r][c] = qkv[(size_t)(b * Sq + so + r) * 1536 + 1024 + h * 64 + c];
  }
  __syncthreads();
  #pragma unroll
  for (int q = 0; q < 16; ++q){
    int lin = q * 256 + tid;
    int d = lin >> 6, s = lin & 63;
    vt[((size_t)bh * 64 + d) * Sq + so + s] = T[s][d];
  }
}

// ---------------- attention PV: probs @ V^T-tiles -> ctx bf16 ----------------
__global__ __launch_bounds__(256) void attn_pv_bf(
    const __bf16* __restrict__ probs, // rows [bh*512+i], ld 1024
    const __bf16* __restrict__ vt,    // [32][64][512]
    __bf16* __restrict__ ctx)         // [2048][512]
{
  int bh = blockIdx.y, b = bh >> 3, h = bh & 7;
  int io = blockIdx.x * 64;
  __shared__ __bf16 Ps[64][72], Vs[64][72];
  int tid = threadIdx.x;
  int lane = tid & 63, w = tid >> 6;
  int wr = (w >> 1) * 32, wc = (w & 1) * 32;
  int lr = lane & 15, lg = lane >> 4;
  f32x4 acc[2][2];
  #pragma unroll
  for (int m = 0; m < 2; ++m)
    #pragma unroll
    for (int n = 0; n < 2; ++n) acc[m][n] = (f32x4){0.f, 0.f, 0.f, 0.f};
  for (int jo = 0; jo < Sq; jo += 64){
    #pragma unroll
    for (int q = 0; q < 2; ++q){
      int lin = q * 256 + tid;
      int r = lin >> 3, c0 = (lin & 7) * 8;
      *(bf16x8*)&Ps[r][c0] = *(const bf16x8*)&probs[((size_t)bh * Sq + io + r) * 1024 + jo + c0];
      *(bf16x8*)&Vs[r][c0] = *(const bf16x8*)&vt[((size_t)bh * 64 + r) * Sq + jo + c0];
    }
    __syncthreads();
    #pragma unroll
    for (int s = 0; s < 2; ++s){
      bf16x8 af[2], bfr[2];
      #pragma unroll
      for (int m = 0; m < 2; ++m) af[m] = *(const bf16x8*)&Ps[wr + m * 16 + lr][s * 32 + lg * 8];
      #pragma unroll
      for (int n = 0; n < 2; ++n) bfr[n] = *(const bf16x8*)&Vs[wc + n * 16 + lr][s * 32 + lg * 8];
      #pragma unroll
      for (int m = 0; m < 2; ++m)
        #pragma unroll
        for (int n = 0; n < 2; ++n)
          acc[m][n] = __builtin_amdgcn_mfma_f32_16x16x32_bf16(af[m], bfr[n], acc[m][n], 0, 0, 0);
    }
    __syncthreads();
  }
  #pragma unroll
  for (int m = 0; m < 2; ++m){
    #pragma unroll
    for (int n = 0; n < 2; ++n){
      int col = wc + n * 16 + lr;
      #pragma unroll
      for (int j = 0; j < 4; ++j){
        int rowl = wr + m * 16 + lg * 4 + j;
        ctx[(size_t)(b * Sq + io + rowl) * Hq + h * 64 + col] = (__bf16)acc[m][n][j];
      }
    }
  }
}

// ---------------- row LayerNorm (+residual, +gelu), dual-dtype out -----------
__global__ __launch_bounds__(256) void ln_rows(const float* __restrict__ in,
                                               const float* __restrict__ res,
                                               const float* __restrict__ g,
                                               const float* __restrict__ bb,
                                               float* __restrict__ out32,
                                               __bf16* __restrict__ out16,
                                               int do_gelu){
  int row = blockIdx.x * 4 + (threadIdx.x >> 6);
  int lane = threadIdx.x & 63;
  const float* ir = in + (size_t)row * Hq;
  const float* rr = res ? res + (size_t)row * Hq : nullptr;
  float x[8]; float s = 0.f, sq = 0.f;
  #pragma unroll
  for (int k = 0; k < 8; ++k){
    int c = lane + 64 * k;
    float v = ir[c];
    if (rr) v += rr[c];
    x[k] = v; s += v; sq += v * v;
  }
  s = waveReduceSum(s); sq = waveReduceSum(sq);
  float mean = s * (1.0f / Hq);
  float var = fmaxf(sq * (1.0f / Hq) - mean * mean, 0.f);
  float rstd = rsqrtf(var + 1e-5f);
  #pragma unroll
  for (int k = 0; k < 8; ++k){
    int c = lane + 64 * k;
    float y = (x[k] - mean) * rstd * g[c] + bb[c];
    if (do_gelu) y = gelu_f(y);
    if (out32) out32[(size_t)row * Hq + c] = y;
    if (out16) out16[(size_t)row * Hq + c] = (__bf16)y;
  }
}

// ---------------- mixer second matmul + softmax over T -----------------------
__global__ __launch_bounds__(256) void mixer2_softmax(const float* __restrict__ m,
                                                      const float* __restrict__ W2,
                                                      const float* __restrict__ b2,
                                                      float* __restrict__ mix){
  int row = blockIdx.x * 4 + (threadIdx.x >> 6);
  int lane = threadIdx.x & 63;
  const float* mr = m + (size_t)row * Hq;
  float a0 = 0.f, a1 = 0.f, a2 = 0.f;
  for (int k = lane; k < Hq; k += 64){
    float v = mr[k];
    const float* w = W2 + k * 3;
    a0 = fmaf(v, w[0], a0); a1 = fmaf(v, w[1], a1); a2 = fmaf(v, w[2], a2);
  }
  a0 = waveReduceSum(a0); a1 = waveReduceSum(a1); a2 = waveReduceSum(a2);
  a0 += b2[0]; a1 += b2[1]; a2 += b2[2];
  float mx = fmaxf(a0, fmaxf(a1, a2));
  float e0 = __expf(a0 - mx), e1 = __expf(a1 - mx), e2 = __expf(a2 - mx);
  float inv = 1.0f / (e0 + e1 + e2);
  if (lane == 0){
    mix[row * 3 + 0] = e0 * inv;
    mix[row * 3 + 1] = e1 * inv;
    mix[row * 3 + 2] = e2 * inv;
  }
}

// ---------------- weighted sum of timescale outputs --------------------------
__global__ __launch_bounds__(256) void weighted_kernel(const __bf16* __restrict__ comb,
                                                       const float* __restrict__ mix,
                                                       float* __restrict__ out32,
                                                       __bf16* __restrict__ out16){
  int idx = blockIdx.x * 256 + threadIdx.x;  // < 2048*512
  int r = idx >> 9, c = idx & 511;
  const __bf16* cr = comb + (size_t)r * 1536;
  float m0 = mix[r * 3 + 0], m1 = mix[r * 3 + 1], m2 = mix[r * 3 + 2];
  float v = m0 * (float)cr[c] + m1 * (float)cr[512 + c] + m2 * (float)cr[1024 + c];
  out32[idx] = v;
  out16[idx] = (__bf16)v;
}

extern "C" void kernel_launch(void* const* d_in, const int* in_sizes, int n_in,
                              void* d_out, int out_size, void* d_ws, size_t ws_size,
                              hipStream_t stream){
  const float* x         = (const float*)d_in[0];
  const float* ts        = (const float*)d_in[1];
  const float* enc_W     = (const float*)d_in[2];
  const float* enc_b     = (const float*)d_in[3];
  const float* enc_ln_g  = (const float*)d_in[4];
  const float* enc_ln_b  = (const float*)d_in[5];
  const float* qkv_W     = (const float*)d_in[6];
  const float* qkv_b     = (const float*)d_in[7];
  const float* aout_W    = (const float*)d_in[8];
  const float* aout_b    = (const float*)d_in[9];
  const float* mx_W1     = (const float*)d_in[10];
  const float* mx_b1     = (const float*)d_in[11];
  const float* mx_ln_g   = (const float*)d_in[12];
  const float* mx_ln_b   = (const float*)d_in[13];
  const float* mx_W2     = (const float*)d_in[14];
  const float* mx_b2     = (const float*)d_in[15];
  const float* el_qkv_W  = (const float*)d_in[16];
  const float* el_qkv_b  = (const float*)d_in[17];
  const float* el_out_W  = (const float*)d_in[18];
  const float* el_out_b  = (const float*)d_in[19];
  const float* el_ln1_g  = (const float*)d_in[20];
  const float* el_ln1_b  = (const float*)d_in[21];
  const float* el_ff_W1  = (const float*)d_in[22];
  const float* el_ff_b1  = (const float*)d_in[23];
  const float* el_ff_W2  = (const float*)d_in[24];
  const float* el_ff_b2  = (const float*)d_in[25];
  const float* el_ln2_g  = (const float*)d_in[26];
  const float* el_ln2_b  = (const float*)d_in[27];
  const float* op_W      = (const float*)d_in[28];
  const float* op_b      = (const float*)d_in[29];
  const float* op_ln_g   = (const float*)d_in[30];
  const float* op_ln_b   = (const float*)d_in[31];

  float* ws = (float*)d_ws;
  size_t o = 0;
  __bf16* MASKBb = (__bf16*)(ws + o); o += 1572864;           // [3][4][512][512]
  __bf16* XB     = (__bf16*)(ws + o); o += 524288;            // [2048][512]
  __bf16* qkvT   = (__bf16*)(ws + o); o += 1179648;           // [3][1536][512]
  __bf16* aoutT  = (__bf16*)(ws + o); o += 393216;            // [3][512][512]
  __bf16* mx1T   = (__bf16*)(ws + o); o += 393216;            // [512][1536]
  __bf16* elqkvT = (__bf16*)(ws + o); o += 393216;            // [1536][512]
  __bf16* eloutT = (__bf16*)(ws + o); o += 131072;            // [512][512]
  __bf16* ff1T   = (__bf16*)(ws + o); o += 524288;            // [2048][512]
  __bf16* ff2T   = (__bf16*)(ws + o); o += 524288;            // [512][2048]
  __bf16* opT    = (__bf16*)(ws + o); o += 131072;            // [512][512]
  __bf16* QKVb   = (__bf16*)(ws + o); o += 4718592;           // [3][2048][1536]
  __bf16* VTb    = (__bf16*)(ws + o); o += 524288;            // [32][64][512]
  float*  SCORES = ws + o;            o += 8388608;           // [32][512][512] f32 (PROBS/FFB alias)
  __bf16* CTXb   = (__bf16*)(ws + o); o += 1572864;           // [3][2048][512]
  __bf16* COMBb  = (__bf16*)(ws + o); o += 1572864;           // [2048][1536]
  float*  MBUF   = ws + o;            o += 1048576;           // also OPO
  float*  MIX    = ws + o;            o += 8192;
  float*  WEI    = ws + o;            o += 1048576;
  __bf16* WEIb   = (__bf16*)(ws + o); o += 524288;
  float*  SA     = ws + o;            o += 1048576;
  float*  H1     = ws + o;            o += 1048576;
  __bf16* H1b    = (__bf16*)(ws + o); o += 524288;
  float*  H2     = ws + o;            o += 1048576;
  __bf16* H2b    = (__bf16*)(ws + o); o += 524288;
  float*  ENC    = ws + o;            o += 1600;
  float*  LUTB   = ws + o;            o += 9 * NLUT;
  __bf16* PROBS  = (__bf16*)SCORES;   // ld 1024 (bf16 overlay on f32 rows)
  __bf16* FFB    = (__bf16*)SCORES;   // [2048][2048] bf16 after attention done
  float*  OPO    = MBUF;

  // 0. dtype conversions
  cvt_bf<<<1024, 256, 0, stream>>>(x, XB, BSq * Hq);
  cvt_wT<<<dim3(24, 8, 3), 256, 0, stream>>>(qkv_W, 1536, (size_t)512 * 1536, qkvT, 512, (size_t)1536 * 512);
  cvt_wT<<<dim3(8, 8, 3), 256, 0, stream>>>(aout_W, 512, (size_t)512 * 512, aoutT, 512, (size_t)512 * 512);
  cvt_wT<<<dim3(8, 24, 1), 256, 0, stream>>>(mx_W1, 512, 0, mx1T, 1536, 0);
  cvt_wT<<<dim3(24, 8, 1), 256, 0, stream>>>(el_qkv_W, 1536, 0, elqkvT, 512, 0);
  cvt_wT<<<dim3(8, 8, 1), 256, 0, stream>>>(el_out_W, 512, 0, eloutT, 512, 0);
  cvt_wT<<<dim3(32, 8, 1), 256, 0, stream>>>(el_ff_W1, 2048, 0, ff1T, 512, 0);
  cvt_wT<<<dim3(8, 32, 1), 256, 0, stream>>>(el_ff_W2, 512, 0, ff2T, 2048, 0);
  cvt_wT<<<dim3(8, 8, 1), 256, 0, stream>>>(op_W, 512, 0, opT, 512, 0);

  // 1. temporal masks
  enc_prep<<<Tq, 256, 0, stream>>>(enc_W, enc_b, ENC);
  mask_lut_build<<<dim3(9, NLUT / 256), 256, 0, stream>>>(ENC, enc_ln_g, enc_ln_b, LUTB);
  mask_fill<<<BSq, 256, 0, stream>>>(ts, LUTB, MASKBb);

  // 2. per-timescale masked attention
  gemm_bf<128><<<dim3(24, 16, 3), 256, 0, stream>>>(XB, 512, 0, qkvT, 512, (size_t)1536 * 512,
      qkv_b, 1536, nullptr, QKVb, 1536, (size_t)2048 * 1536, 512, 0);
  for (int t = 0; t < Tq; ++t){
    const __bf16* qk = QKVb + (size_t)t * 2048 * 1536;
    transpose_v<<<dim3(8, 32), 256, 0, stream>>>(qk, VTb);
    attn_scores_bf<<<dim3(4, 4, 32), 256, 0, stream>>>(qk, MASKBb + (size_t)t * 4 * 512 * 512, SCORES);
    softmax_bf<<<4096, 256, 0, stream>>>(SCORES);
    attn_pv_bf<<<dim3(8, 32), 256, 0, stream>>>(PROBS, VTb, CTXb + (size_t)t * 2048 * 512);
  }
  gemm_bf<64><<<dim3(8, 32, 3), 256, 0, stream>>>(CTXb, 512, (size_t)2048 * 512, aoutT, 512, (size_t)512 * 512,
      aout_b, 512, nullptr, COMBb, 1536, 512, 512, 0);

  // 3. time mixer
  gemm_bf<64><<<dim3(8, 32, 1), 256, 0, stream>>>(COMBb, 1536, 0, mx1T, 1536, 0,
      mx_b1, 0, MBUF, nullptr, 512, 0, 1536, 0);
  ln_rows<<<512, 256, 0, stream>>>(MBUF, nullptr, mx_ln_g, mx_ln_b, MBUF, nullptr, 1);
  mixer2_softmax<<<512, 256, 0, stream>>>(MBUF, mx_W2, mx_b2, MIX);
  weighted_kernel<<<4096, 256, 0, stream>>>(COMBb, MIX, WEI, WEIb);

  // 4. transformer encoder layer (post-norm)
  gemm_bf<128><<<dim3(24, 16, 1), 256, 0, stream>>>(WEIb, 512, 0, elqkvT, 512, 0,
      el_qkv_b, 0, nullptr, QKVb, 1536, 0, 512, 0);
  transpose_v<<<dim3(8, 32), 256, 0, stream>>>(QKVb, VTb);
  attn_scores_bf<<<dim3(4, 4, 32), 256, 0, stream>>>(QKVb, nullptr, SCORES);
  softmax_bf<<<4096, 256, 0, stream>>>(SCORES);
  attn_pv_bf<<<dim3(8, 32), 256, 0, stream>>>(PROBS, VTb, CTXb);
  gemm_bf<64><<<dim3(8, 32, 1), 256, 0, stream>>>(CTXb, 512, 0, eloutT, 512, 0,
      el_out_b, 0, SA, nullptr, 512, 0, 512, 0);
  ln_rows<<<512, 256, 0, stream>>>(WEI, SA, el_ln1_g, el_ln1_b, H1, H1b, 0);
  gemm_bf<128><<<dim3(32, 16, 1), 256, 0, stream>>>(H1b, 512, 0, ff1T, 512, 0,
      el_ff_b1, 0, nullptr, FFB, 2048, 0, 512, 1);
  gemm_bf<64><<<dim3(8, 32, 1), 256, 0, stream>>>(FFB, 2048, 0, ff2T, 2048, 0,
      el_ff_b2, 0, SA, nullptr, 512, 0, 2048, 0);
  ln_rows<<<512, 256, 0, stream>>>(H1, SA, el_ln2_g, el_ln2_b, H2, H2b, 0);

  // 5. output projection + final LN
  gemm_bf<64><<<dim3(8, 32, 1), 256, 0, stream>>>(H2b, 512, 0, opT, 512, 0,
      op_b, 0, OPO, nullptr, 512, 0, 512, 0);
  ln_rows<<<512, 256, 0, stream>>>(OPO, nullptr, op_ln_g, op_ln_b, (float*)d_out, nullptr, 0);
}

// Round 5
// 305.783 us; speedup vs baseline: 6.3956x; 1.4034x over previous
//
#include <hip/hip_runtime.h>
#include <hip/hip_bf16.h>
#include <math.h>

#define Bq 4
#define Sq 512
#define Hq 512
#define NHq 8
#define Tq 3
#define DTSq 170
#define BSq 2048
#define ENCSTRIDE 520
#define NLUT 2048
#define MAGMAXf 5.6304994f

typedef float f32x4 __attribute__((ext_vector_type(4)));
typedef __bf16 bf16x4 __attribute__((ext_vector_type(4)));
typedef __bf16 bf16x8 __attribute__((ext_vector_type(8)));

__device__ __forceinline__ float gelu_f(float x){
  return 0.5f * x * (1.0f + erff(x * 0.70710678118654752f));
}

__device__ __forceinline__ void gload16(const void* g, void* l){
  __builtin_amdgcn_global_load_lds((const __attribute__((address_space(1))) void*)g,
                                   (__attribute__((address_space(3))) void*)l, 16, 0, 0);
}

__device__ __forceinline__ float waveReduceSum(float v){
  #pragma unroll
  for (int off = 32; off > 0; off >>= 1) v += __shfl_xor(v, off);
  return v;
}
__device__ __forceinline__ float waveReduceMax(float v){
  #pragma unroll
  for (int off = 32; off > 0; off >>= 1) v = fmaxf(v, __shfl_xor(v, off));
  return v;
}

__device__ __forceinline__ float blockReduce(float v, float* red){
  int tid = threadIdx.x;
  __syncthreads();
  red[tid] = v; __syncthreads();
  for (int s = 128; s > 0; s >>= 1){
    if (tid < s) red[tid] += red[tid + s];
    __syncthreads();
  }
  return red[0];
}

// ---------------- encoder prep: centered vectors + covariance scalars -------
__global__ __launch_bounds__(256) void enc_prep(const float* __restrict__ encW,
                                                const float* __restrict__ encB,
                                                float* __restrict__ out){
  int t = blockIdx.x, tid = threadIdx.x;
  __shared__ float red[256];
  const float* W0 = encW + t * 2 * DTSq;
  const float* W1 = W0 + DTSq;
  const float* Bv = encB + t * DTSq;
  float w0 = (tid < DTSq) ? W0[tid] : 0.f;
  float w1 = (tid < DTSq) ? W1[tid] : 0.f;
  float bv = (tid < DTSq) ? Bv[tid] : 0.f;
  const float invD = 1.0f / (float)DTSq;
  float m0 = blockReduce(w0, red) * invD;
  float m1 = blockReduce(w1, red) * invD;
  float mb = blockReduce(bv, red) * invD;
  float c0 = (tid < DTSq) ? (w0 - m0) : 0.f;
  float c1 = (tid < DTSq) ? (w1 - m1) : 0.f;
  float cb = (tid < DTSq) ? (bv - mb) : 0.f;
  float* op = out + t * ENCSTRIDE;
  if (tid < DTSq){
    op[tid] = c0; op[DTSq + tid] = c1; op[2 * DTSq + tid] = cb;
  }
  float pa = blockReduce(c0 * c0, red) * invD;
  float pb = blockReduce(c1 * c1, red) * invD;
  float pc = blockReduce(c0 * c1, red) * invD;
  float pd = blockReduce(c0 * cb, red) * invD;
  float pe = blockReduce(c1 * cb, red) * invD;
  float pf = blockReduce(cb * cb, red) * invD;
  if (tid == 0){
    op[3 * DTSq + 0] = pa; op[3 * DTSq + 1] = pb; op[3 * DTSq + 2] = pc;
    op[3 * DTSq + 3] = pd; op[3 * DTSq + 4] = pe; op[3 * DTSq + 5] = pf;
  }
}

// ---------------- mask LUT build ---------------------------------------------
__global__ __launch_bounds__(256) void mask_lut_build(const float* __restrict__ enc,
                                                      const float* __restrict__ g,
                                                      const float* __restrict__ be,
                                                      float* __restrict__ lut){
  int td = blockIdx.x;            // t*3 + dsel
  int t = td / 3, dsel = td % 3;
  float d = (float)(dsel - 1);
  __shared__ float sw0[DTSq], sw1[DTSq], sbc[DTSq], sg[DTSq], sbe[DTSq];
  const float* ep = enc + t * ENCSTRIDE;
  for (int c = threadIdx.x; c < DTSq; c += 256){
    sw0[c] = ep[c]; sw1[c] = ep[DTSq + c]; sbc[c] = ep[2 * DTSq + c];
    sg[c] = g[t * DTSq + c]; sbe[c] = be[t * DTSq + c];
  }
  __syncthreads();
  float A  = ep[3 * DTSq + 0], Bs = ep[3 * DTSq + 1], Cs = ep[3 * DTSq + 2];
  float Ds = ep[3 * DTSq + 3], Es = ep[3 * DTSq + 4], Fs = ep[3 * DTSq + 5];
  int e = blockIdx.y * 256 + threadIdx.x;
  float tscale = (t == 0) ? 1.f : ((t == 1) ? 0.1f : 0.01f);
  float m = (MAGMAXf / (float)(NLUT - 1)) * (float)e * tscale;
  float var = fabsf(d) * A + m * m * Bs + Fs + 2.f * (d * m * Cs + d * Ds + m * Es);
  float rs = rsqrtf(var + 1e-5f);
  float sum = 0.f;
  for (int c = 0; c < DTSq; ++c){
    float ee = fmaf(m, sw1[c], fmaf(d, sw0[c], sbc[c]));
    float n = fmaf(ee * rs, sg[c], sbe[c]);
    sum += n * 0.5f * (1.0f + erff(n * 0.70710678118654752f));
  }
  lut[td * NLUT + e] = sum * (1.0f / (float)DTSq);
}

// ---------------- mask fill via LUT interpolation (bf16 out) -----------------
__global__ __launch_bounds__(256) void mask_fill(const float* __restrict__ ts,
                                                 const float* __restrict__ lut,
                                                 __bf16* __restrict__ maskbuf){
  int bi = blockIdx.x;            // b*S + i
  int b = bi >> 9, i = bi & 511;
  float tsi = ts[bi];
  for (int j0 = 0; j0 < Sq; j0 += 256){
    int j = j0 + threadIdx.x;
    float dt = tsi - ts[(b << 9) + j];
    int dsel = (dt > 0.f) ? 2 : ((dt < 0.f) ? 0 : 1);
    float mag = log1pf(fabsf(dt) * (1.0f / 3600.0f));
    float u = mag * ((float)(NLUT - 1) / MAGMAXf);
    int i0 = (int)u; if (i0 > NLUT - 2) i0 = NLUT - 2;
    float f = u - (float)i0;
    #pragma unroll
    for (int t = 0; t < Tq; ++t){
      const float* lp = lut + (t * 3 + dsel) * NLUT + i0;
      float v = lp[0] + f * (lp[1] - lp[0]);
      maskbuf[(((size_t)(t * Bq + b) * Sq + i) * Sq) + j] = (__bf16)v;
    }
  }
}

// ---------------- merged weight transpose-convert ---------------------------
struct CvtEnt { const float* W; __bf16* WT; int ldw, ldt, ntn, start; };
struct CvtArgs { CvtEnt e[12]; };

__global__ __launch_bounds__(256) void cvt_wT_all(CvtArgs a){
  int bid = blockIdx.x;
  int i = 0;
  #pragma unroll
  for (int k = 1; k < 12; ++k) if (bid >= a.e[k].start) i = k;
  const float* W = a.e[i].W;
  __bf16* WT = a.e[i].WT;
  int ldw = a.e[i].ldw, ldt = a.e[i].ldt;
  int local = bid - a.e[i].start;
  int tn = local % a.e[i].ntn, tk = local / a.e[i].ntn;
  int n0 = tn * 64, k0 = tk * 64;
  __shared__ float T[64][65];
  int tid = threadIdx.x;
  #pragma unroll
  for (int q = 0; q < 16; ++q){
    int lin = q * 256 + tid;
    int r = lin >> 6, c = lin & 63;
    T[r][c] = W[(size_t)(k0 + r) * ldw + n0 + c];
  }
  __syncthreads();
  #pragma unroll
  for (int q = 0; q < 16; ++q){
    int lin = q * 256 + tid;
    int n = lin >> 6, k = lin & 63;
    WT[(size_t)(n0 + n) * ldt + k0 + k] = (__bf16)T[k][n];
  }
}

// ---------------- elementwise f32 -> bf16 ------------------------------------
__global__ __launch_bounds__(256) void cvt_bf(const float* __restrict__ in,
                                              __bf16* __restrict__ out, int n){
  int idx = (blockIdx.x * 256 + threadIdx.x) * 4;
  if (idx < n){
    float4 v = *(const float4*)&in[idx];
    bf16x4 r; r[0]=(__bf16)v.x; r[1]=(__bf16)v.y; r[2]=(__bf16)v.z; r[3]=(__bf16)v.w;
    *(bf16x4*)&out[idx] = r;
  }
}

// ---------------- pipelined bf16 MFMA GEMM: C = act(A @ BT^T + bias) ---------
// A[M][lda] bf16 k-contig; BT[N][ldb] bf16 k-contig. Tile BM x 64, BK=64.
// Double-buffered LDS via global_load_lds(16B), swizzled source + swizzled read,
// counted vmcnt in steady state; vmcnt(0) drain on the LAST tile (r4 bug fix).
template<int BM>
__global__ __launch_bounds__(256) void gemm_pipe(
    const __bf16* __restrict__ A, int lda, size_t sAz,
    const __bf16* __restrict__ BT, int ldb, size_t sBz,
    const float* __restrict__ bias, int sBiasz,
    float* __restrict__ C32, __bf16* __restrict__ C16, int ldc, size_t sCz,
    int K, int act)
{
  constexpr int MF = BM / 32;             // m-frags per wave
  constexpr int ABYTES = BM * 128;        // bytes per A buf (64 cols bf16)
  constexpr int BBYTES = 64 * 128;
  __shared__ __bf16 lds[(2 * (ABYTES + BBYTES)) / 2];
  int tid = threadIdx.x;

  // XCD-chunked block swizzle (all grids here are multiples of 8)
  int gx = gridDim.x, nwg = gx * gridDim.y;
  int lin = blockIdx.x + gx * blockIdx.y;
  int q8 = nwg >> 3;
  int swz = (lin & 7) * q8 + (lin >> 3);
  int bx = swz % gx, by = swz / gx;

  int z = blockIdx.z;
  A  += (size_t)z * sAz;
  BT += (size_t)z * sBz;
  const float* bz = bias ? bias + (size_t)z * sBiasz : nullptr;
  size_t cbase = (size_t)z * sCz;
  int brow = by * BM, bcol = bx * 64;

  int lane = tid & 63, w = tid >> 6;
  int wr = (w >> 1) * (BM / 2), wc = (w & 1) * 32;
  int lr = lane & 15, lg = lane >> 4;

  f32x4 acc[MF][2];
  #pragma unroll
  for (int m = 0; m < MF; ++m)
    #pragma unroll
    for (int n = 0; n < 2; ++n) acc[m][n] = (f32x4){0.f, 0.f, 0.f, 0.f};

  char* lbase = (char*)lds;

  auto stage = [&](int buf, int ko){
    char* ab = lbase + buf * (ABYTES + BBYTES);
    #pragma unroll
    for (int qq = 0; qq < BM / 32; ++qq){
      int byte = (qq * 256 + tid) * 16;
      int row = byte >> 7, col8 = byte & 127;
      int src = col8 ^ ((row & 7) << 4);          // inverse-swizzled source
      gload16(&A[(size_t)(brow + row) * lda + ko + (src >> 1)], ab + byte);
    }
    char* bb = ab + ABYTES;
    #pragma unroll
    for (int qq = 0; qq < 2; ++qq){
      int byte = (qq * 256 + tid) * 16;
      int row = byte >> 7, col8 = byte & 127;
      int src = col8 ^ ((row & 7) << 4);
      gload16(&BT[(size_t)(bcol + row) * ldb + ko + (src >> 1)], bb + byte);
    }
  };

  stage(0, 0);
  int nk = K >> 6;
  for (int kt = 0; kt < nk; ++kt){
    int cur = kt & 1;
    if (kt + 1 < nk){
      stage(cur ^ 1, (kt + 1) << 6);
      // steady state: 2*stage loads outstanding; wait for current buffer's
      if constexpr (BM == 64) asm volatile("s_waitcnt vmcnt(4)" ::: "memory");
      else                    asm volatile("s_waitcnt vmcnt(6)" ::: "memory");
    } else {
      // last tile: only current buffer's loads outstanding -> full drain
      asm volatile("s_waitcnt vmcnt(0)" ::: "memory");
    }
    __builtin_amdgcn_s_barrier();
    __builtin_amdgcn_sched_barrier(0);
    char* ab = lbase + cur * (ABYTES + BBYTES);
    char* bb = ab + ABYTES;
    #pragma unroll
    for (int s = 0; s < 2; ++s){
      bf16x8 af[MF], bfr[2];
      #pragma unroll
      for (int m = 0; m < MF; ++m){
        int row = wr + m * 16 + lr;
        int col8 = (s * 64 + lg * 16) ^ ((row & 7) << 4);
        af[m] = *(const bf16x8*)(ab + row * 128 + col8);
      }
      #pragma unroll
      for (int n = 0; n < 2; ++n){
        int row = wc + n * 16 + lr;
        int col8 = (s * 64 + lg * 16) ^ ((row & 7) << 4);
        bfr[n] = *(const bf16x8*)(bb + row * 128 + col8);
      }
      #pragma unroll
      for (int m = 0; m < MF; ++m)
        #pragma unroll
        for (int n = 0; n < 2; ++n)
          acc[m][n] = __builtin_amdgcn_mfma_f32_16x16x32_bf16(af[m], bfr[n], acc[m][n], 0, 0, 0);
    }
    asm volatile("" ::: "memory");
    __builtin_amdgcn_s_barrier();
  }

  #pragma unroll
  for (int m = 0; m < MF; ++m){
    #pragma unroll
    for (int n = 0; n < 2; ++n){
      int col = bcol + wc + n * 16 + lr;
      float bv = bz ? bz[col] : 0.f;
      #pragma unroll
      for (int j = 0; j < 4; ++j){
        int row = brow + wr + m * 16 + lg * 4 + j;
        float v = acc[m][n][j] + bv;
        if (act) v = gelu_f(v);
        size_t idx = cbase + (size_t)row * ldc + col;
        if (C32) C32[idx] = v;
        if (C16) C16[idx] = (__bf16)v;
      }
    }
  }
}

// ---------------- attention scores: q·k^T/8 (+mask) --------------------------
__global__ __launch_bounds__(256) void attn_scores_bf(
    const __bf16* __restrict__ qkv,   // [2048][1536] (one timescale)
    const __bf16* __restrict__ mask,  // [4][512][512] bf16 or null
    float* __restrict__ scores)       // [32][512][512]
{
  int bh = blockIdx.z, b = bh >> 3, h = bh & 7;
  int io = blockIdx.y * 128, jo = blockIdx.x * 128;
  __shared__ __bf16 Qs[128][72], Ks[128][72];
  int tid = threadIdx.x;
  #pragma unroll
  for (int q = 0; q < 4; ++q){
    int lin = q * 256 + tid;
    int r = lin >> 3, c0 = (lin & 7) * 8;
    *(bf16x8*)&Qs[r][c0] = *(const bf16x8*)&qkv[(size_t)(b * Sq + io + r) * 1536 + h * 64 + c0];
    *(bf16x8*)&Ks[r][c0] = *(const bf16x8*)&qkv[(size_t)(b * Sq + jo + r) * 1536 + 512 + h * 64 + c0];
  }
  __syncthreads();
  int lane = tid & 63, w = tid >> 6;
  int wr = (w >> 1) * 64, wc = (w & 1) * 64;
  int lr = lane & 15, lg = lane >> 4;
  f32x4 acc[4][4];
  #pragma unroll
  for (int m = 0; m < 4; ++m)
    #pragma unroll
    for (int n = 0; n < 4; ++n) acc[m][n] = (f32x4){0.f, 0.f, 0.f, 0.f};
  #pragma unroll
  for (int s = 0; s < 2; ++s){
    bf16x8 af[4], bfr[4];
    #pragma unroll
    for (int m = 0; m < 4; ++m) af[m] = *(const bf16x8*)&Qs[wr + m * 16 + lr][s * 32 + lg * 8];
    #pragma unroll
    for (int n = 0; n < 4; ++n) bfr[n] = *(const bf16x8*)&Ks[wc + n * 16 + lr][s * 32 + lg * 8];
    #pragma unroll
    for (int m = 0; m < 4; ++m)
      #pragma unroll
      for (int n = 0; n < 4; ++n)
        acc[m][n] = __builtin_amdgcn_mfma_f32_16x16x32_bf16(af[m], bfr[n], acc[m][n], 0, 0, 0);
  }
  #pragma unroll
  for (int m = 0; m < 4; ++m){
    #pragma unroll
    for (int n = 0; n < 4; ++n){
      int jj = jo + wc + n * 16 + lr;
      #pragma unroll
      for (int j = 0; j < 4; ++j){
        int ii = io + wr + m * 16 + lg * 4 + j;
        float v = acc[m][n][j] * 0.125f;
        if (mask) v += (float)mask[(size_t)(b * Sq + ii) * Sq + jj];
        scores[((size_t)bh * Sq + ii) * Sq + jj] = v;
      }
    }
  }
}

// ---------------- row softmax fp32 -> bf16 probs (in place, half row) --------
__global__ __launch_bounds__(256) void softmax_bf(float* __restrict__ scores){
  int row = blockIdx.x * 4 + (threadIdx.x >> 6);
  int lane = threadIdx.x & 63;
  float* sr = scores + (size_t)row * Sq;
  float x[8]; float mx = -1e30f;
  #pragma unroll
  for (int k = 0; k < 8; ++k){ x[k] = sr[lane + 64 * k]; mx = fmaxf(mx, x[k]); }
  mx = waveReduceMax(mx);
  float s = 0.f;
  #pragma unroll
  for (int k = 0; k < 8; ++k){ x[k] = __expf(x[k] - mx); s += x[k]; }
  s = waveReduceSum(s);
  float inv = 1.0f / s;
  __bf16* pr = (__bf16*)sr;      // probs overlay: row stride 1024 bf16 elems
  #pragma unroll
  for (int k = 0; k < 8; ++k) pr[lane + 64 * k] = (__bf16)(x[k] * inv);
}

// ---------------- V transpose per head (z-batched over t) --------------------
__global__ __launch_bounds__(256) void transpose_v(const __bf16* __restrict__ qkv, size_t sQz,
                                                   __bf16* __restrict__ vt, size_t sVz){
  int t = blockIdx.z;
  qkv += (size_t)t * sQz;
  vt  += (size_t)t * sVz;
  int bh = blockIdx.y, b = bh >> 3, h = bh & 7;
  int so = blockIdx.x * 64;
  __shared__ __bf16 T[64][72];
  int tid = threadIdx.x;
  #pragma unroll
  for (int q = 0; q < 16; ++q){
    int lin = q * 256 + tid;
    int r = lin >> 6, c = lin & 63;
    T[r][c] = qkv[(size_t)(b * Sq + so + r) * 1536 + 1024 + h * 64 + c];
  }
  __syncthreads();
  #pragma unroll
  for (int q = 0; q < 16; ++q){
    int lin = q * 256 + tid;
    int d = lin >> 6, s = lin & 63;
    vt[((size_t)bh * 64 + d) * Sq + so + s] = T[s][d];
  }
}

// ---------------- attention PV: probs @ V^T-tiles -> ctx bf16 ----------------
__global__ __launch_bounds__(256) void attn_pv_bf(
    const __bf16* __restrict__ probs, // rows [bh*512+i], ld 1024
    const __bf16* __restrict__ vt,    // [32][64][512]
    __bf16* __restrict__ ctx)         // [2048][512]
{
  int bh = blockIdx.y, b = bh >> 3, h = bh & 7;
  int io = blockIdx.x * 64;
  __shared__ __bf16 Ps[64][72], Vs[64][72];
  int tid = threadIdx.x;
  int lane = tid & 63, w = tid >> 6;
  int wr = (w >> 1) * 32, wc = (w & 1) * 32;
  int lr = lane & 15, lg = lane >> 4;
  f32x4 acc[2][2];
  #pragma unroll
  for (int m = 0; m < 2; ++m)
    #pragma unroll
    for (int n = 0; n < 2; ++n) acc[m][n] = (f32x4){0.f, 0.f, 0.f, 0.f};
  for (int jo = 0; jo < Sq; jo += 64){
    #pragma unroll
    for (int q = 0; q < 2; ++q){
      int lin = q * 256 + tid;
      int r = lin >> 3, c0 = (lin & 7) * 8;
      *(bf16x8*)&Ps[r][c0] = *(const bf16x8*)&probs[((size_t)bh * Sq + io + r) * 1024 + jo + c0];
      *(bf16x8*)&Vs[r][c0] = *(const bf16x8*)&vt[((size_t)bh * 64 + r) * Sq + jo + c0];
    }
    __syncthreads();
    #pragma unroll
    for (int s = 0; s < 2; ++s){
      bf16x8 af[2], bfr[2];
      #pragma unroll
      for (int m = 0; m < 2; ++m) af[m] = *(const bf16x8*)&Ps[wr + m * 16 + lr][s * 32 + lg * 8];
      #pragma unroll
      for (int n = 0; n < 2; ++n) bfr[n] = *(const bf16x8*)&Vs[wc + n * 16 + lr][s * 32 + lg * 8];
      #pragma unroll
      for (int m = 0; m < 2; ++m)
        #pragma unroll
        for (int n = 0; n < 2; ++n)
          acc[m][n] = __builtin_amdgcn_mfma_f32_16x16x32_bf16(af[m], bfr[n], acc[m][n], 0, 0, 0);
    }
    __syncthreads();
  }
  #pragma unroll
  for (int m = 0; m < 2; ++m){
    #pragma unroll
    for (int n = 0; n < 2; ++n){
      int col = wc + n * 16 + lr;
      #pragma unroll
      for (int j = 0; j < 4; ++j){
        int rowl = wr + m * 16 + lg * 4 + j;
        ctx[(size_t)(b * Sq + io + rowl) * Hq + h * 64 + col] = (__bf16)acc[m][n][j];
      }
    }
  }
}

// ---------------- row LayerNorm (+residual), dual-dtype out ------------------
__global__ __launch_bounds__(256) void ln_rows(const float* __restrict__ in,
                                               const float* __restrict__ res,
                                               const float* __restrict__ g,
                                               const float* __restrict__ bb,
                                               float* __restrict__ out32,
                                               __bf16* __restrict__ out16,
                                               int do_gelu){
  int row = blockIdx.x * 4 + (threadIdx.x >> 6);
  int lane = threadIdx.x & 63;
  const float* ir = in + (size_t)row * Hq;
  const float* rr = res ? res + (size_t)row * Hq : nullptr;
  float x[8]; float s = 0.f, sq = 0.f;
  #pragma unroll
  for (int k = 0; k < 8; ++k){
    int c = lane + 64 * k;
    float v = ir[c];
    if (rr) v += rr[c];
    x[k] = v; s += v; sq += v * v;
  }
  s = waveReduceSum(s); sq = waveReduceSum(sq);
  float mean = s * (1.0f / Hq);
  float var = fmaxf(sq * (1.0f / Hq) - mean * mean, 0.f);
  float rstd = rsqrtf(var + 1e-5f);
  #pragma unroll
  for (int k = 0; k < 8; ++k){
    int c = lane + 64 * k;
    float y = (x[k] - mean) * rstd * g[c] + bb[c];
    if (do_gelu) y = gelu_f(y);
    if (out32) out32[(size_t)row * Hq + c] = y;
    if (out16) out16[(size_t)row * Hq + c] = (__bf16)y;
  }
}

// ---------------- fused: LN + gelu + mixer2 matmul + softmax over T ----------
__global__ __launch_bounds__(256) void ln_mixer_softmax(const float* __restrict__ in,
                                                        const float* __restrict__ g,
                                                        const float* __restrict__ bb,
                                                        const float* __restrict__ W2,
                                                        const float* __restrict__ b2,
                                                        float* __restrict__ mix){
  int row = blockIdx.x * 4 + (threadIdx.x >> 6);
  int lane = threadIdx.x & 63;
  const float* ir = in + (size_t)row * Hq;
  float x[8]; float s = 0.f, sq = 0.f;
  #pragma unroll
  for (int k = 0; k < 8; ++k){
    int c = lane + 64 * k;
    float v = ir[c];
    x[k] = v; s += v; sq += v * v;
  }
  s = waveReduceSum(s); sq = waveReduceSum(sq);
  float mean = s * (1.0f / Hq);
  float var = fmaxf(sq * (1.0f / Hq) - mean * mean, 0.f);
  float rstd = rsqrtf(var + 1e-5f);
  float a0 = 0.f, a1 = 0.f, a2 = 0.f;
  #pragma unroll
  for (int k = 0; k < 8; ++k){
    int c = lane + 64 * k;
    float y = gelu_f((x[k] - mean) * rstd * g[c] + bb[c]);
    const float* w = W2 + c * 3;
    a0 = fmaf(y, w[0], a0); a1 = fmaf(y, w[1], a1); a2 = fmaf(y, w[2], a2);
  }
  a0 = waveReduceSum(a0); a1 = waveReduceSum(a1); a2 = waveReduceSum(a2);
  a0 += b2[0]; a1 += b2[1]; a2 += b2[2];
  float mx = fmaxf(a0, fmaxf(a1, a2));
  float e0 = __expf(a0 - mx), e1 = __expf(a1 - mx), e2 = __expf(a2 - mx);
  float inv = 1.0f / (e0 + e1 + e2);
  if (lane == 0){
    mix[row * 3 + 0] = e0 * inv;
    mix[row * 3 + 1] = e1 * inv;
    mix[row * 3 + 2] = e2 * inv;
  }
}

// ---------------- weighted sum of timescale outputs --------------------------
__global__ __launch_bounds__(256) void weighted_kernel(const __bf16* __restrict__ comb,
                                                       const float* __restrict__ mix,
                                                       float* __restrict__ out32,
                                                       __bf16* __restrict__ out16){
  int idx = blockIdx.x * 256 + threadIdx.x;  // < 2048*512
  int r = idx >> 9, c = idx & 511;
  const __bf16* cr = comb + (size_t)r * 1536;
  float m0 = mix[r * 3 + 0], m1 = mix[r * 3 + 1], m2 = mix[r * 3 + 2];
  float v = m0 * (float)cr[c] + m1 * (float)cr[512 + c] + m2 * (float)cr[1024 + c];
  out32[idx] = v;
  out16[idx] = (__bf16)v;
}

extern "C" void kernel_launch(void* const* d_in, const int* in_sizes, int n_in,
                              void* d_out, int out_size, void* d_ws, size_t ws_size,
                              hipStream_t stream){
  const float* x         = (const float*)d_in[0];
  const float* ts        = (const float*)d_in[1];
  const float* enc_W     = (const float*)d_in[2];
  const float* enc_b     = (const float*)d_in[3];
  const float* enc_ln_g  = (const float*)d_in[4];
  const float* enc_ln_b  = (const float*)d_in[5];
  const float* qkv_W     = (const float*)d_in[6];
  const float* qkv_b     = (const float*)d_in[7];
  const float* aout_W    = (const float*)d_in[8];
  const float* aout_b    = (const float*)d_in[9];
  const float* mx_W1     = (const float*)d_in[10];
  const float* mx_b1     = (const float*)d_in[11];
  const float* mx_ln_g   = (const float*)d_in[12];
  const float* mx_ln_b   = (const float*)d_in[13];
  const float* mx_W2     = (const float*)d_in[14];
  const float* mx_b2     = (const float*)d_in[15];
  const float* el_qkv_W  = (const float*)d_in[16];
  const float* el_qkv_b  = (const float*)d_in[17];
  const float* el_out_W  = (const float*)d_in[18];
  const float* el_out_b  = (const float*)d_in[19];
  const float* el_ln1_g  = (const float*)d_in[20];
  const float* el_ln1_b  = (const float*)d_in[21];
  const float* el_ff_W1  = (const float*)d_in[22];
  const float* el_ff_b1  = (const float*)d_in[23];
  const float* el_ff_W2  = (const float*)d_in[24];
  const float* el_ff_b2  = (const float*)d_in[25];
  const float* el_ln2_g  = (const float*)d_in[26];
  const float* el_ln2_b  = (const float*)d_in[27];
  const float* op_W      = (const float*)d_in[28];
  const float* op_b      = (const float*)d_in[29];
  const float* op_ln_g   = (const float*)d_in[30];
  const float* op_ln_b   = (const float*)d_in[31];

  float* ws = (float*)d_ws;
  size_t o = 0;
  __bf16* MASKBb = (__bf16*)(ws + o); o += 1572864;           // [3][4][512][512]
  __bf16* XB     = (__bf16*)(ws + o); o += 524288;            // [2048][512]
  __bf16* qkvT   = (__bf16*)(ws + o); o += 1179648;           // [3][1536][512]
  __bf16* aoutT  = (__bf16*)(ws + o); o += 393216;            // [3][512][512]
  __bf16* mx1T   = (__bf16*)(ws + o); o += 393216;            // [512][1536]
  __bf16* elqkvT = (__bf16*)(ws + o); o += 393216;            // [1536][512]
  __bf16* eloutT = (__bf16*)(ws + o); o += 131072;            // [512][512]
  __bf16* ff1T   = (__bf16*)(ws + o); o += 524288;            // [2048][512]
  __bf16* ff2T   = (__bf16*)(ws + o); o += 524288;            // [512][2048]
  __bf16* opT    = (__bf16*)(ws + o); o += 131072;            // [512][512]
  __bf16* QKVb   = (__bf16*)(ws + o); o += 4718592;           // [3][2048][1536]
  __bf16* VTb    = (__bf16*)(ws + o); o += 1572864;           // [3][32][64][512]
  float*  SCORES = ws + o;            o += 8388608;           // [32][512][512] f32 (PROBS/FFB alias)
  __bf16* CTXb   = (__bf16*)(ws + o); o += 1572864;           // [3][2048][512]
  __bf16* COMBb  = (__bf16*)(ws + o); o += 1572864;           // [2048][1536]
  float*  MBUF   = ws + o;            o += 1048576;           // mixer1 out, also OPO
  float*  MIX    = ws + o;            o += 8192;
  float*  WEI    = ws + o;            o += 1048576;
  __bf16* WEIb   = (__bf16*)(ws + o); o += 524288;
  float*  SA     = ws + o;            o += 1048576;
  float*  H1     = ws + o;            o += 1048576;
  __bf16* H1b    = (__bf16*)(ws + o); o += 524288;
  float*  H2     = ws + o;            o += 1048576;
  __bf16* H2b    = (__bf16*)(ws + o); o += 524288;
  float*  ENC    = ws + o;            o += 1600;
  float*  LUTB   = ws + o;            o += 9 * NLUT;
  __bf16* PROBS  = (__bf16*)SCORES;   // ld 1024 (bf16 overlay on f32 rows)
  __bf16* FFB    = (__bf16*)SCORES;   // [2048][2048] bf16 after attention done
  float*  OPO    = MBUF;

  // 0. dtype conversions (merged)
  cvt_bf<<<1024, 256, 0, stream>>>(x, XB, BSq * Hq);
  {
    CvtArgs ca;
    for (int t = 0; t < 3; ++t)
      ca.e[t] = {qkv_W + (size_t)t * 512 * 1536, qkvT + (size_t)t * 1536 * 512, 1536, 512, 24, 192 * t};
    for (int t = 0; t < 3; ++t)
      ca.e[3 + t] = {aout_W + (size_t)t * 512 * 512, aoutT + (size_t)t * 512 * 512, 512, 512, 8, 576 + 64 * t};
    ca.e[6]  = {mx_W1,    mx1T,   512,  1536, 8,  768};
    ca.e[7]  = {el_qkv_W, elqkvT, 1536, 512,  24, 960};
    ca.e[8]  = {el_out_W, eloutT, 512,  512,  8,  1152};
    ca.e[9]  = {el_ff_W1, ff1T,   2048, 512,  32, 1216};
    ca.e[10] = {el_ff_W2, ff2T,   512,  2048, 8,  1472};
    ca.e[11] = {op_W,     opT,    512,  512,  8,  1728};
    cvt_wT_all<<<1792, 256, 0, stream>>>(ca);
  }

  // 1. temporal masks
  enc_prep<<<Tq, 256, 0, stream>>>(enc_W, enc_b, ENC);
  mask_lut_build<<<dim3(9, NLUT / 256), 256, 0, stream>>>(ENC, enc_ln_g, enc_ln_b, LUTB);
  mask_fill<<<BSq, 256, 0, stream>>>(ts, LUTB, MASKBb);

  // 2. per-timescale masked attention
  gemm_pipe<128><<<dim3(24, 16, 3), 256, 0, stream>>>(XB, 512, 0, qkvT, 512, (size_t)1536 * 512,
      qkv_b, 1536, nullptr, QKVb, 1536, (size_t)2048 * 1536, 512, 0);
  transpose_v<<<dim3(8, 32, 3), 256, 0, stream>>>(QKVb, (size_t)2048 * 1536, VTb, (size_t)32 * 64 * 512);
  for (int t = 0; t < Tq; ++t){
    const __bf16* qk = QKVb + (size_t)t * 2048 * 1536;
    attn_scores_bf<<<dim3(4, 4, 32), 256, 0, stream>>>(qk, MASKBb + (size_t)t * 4 * 512 * 512, SCORES);
    softmax_bf<<<4096, 256, 0, stream>>>(SCORES);
    attn_pv_bf<<<dim3(8, 32), 256, 0, stream>>>(PROBS, VTb + (size_t)t * 32 * 64 * 512,
                                                CTXb + (size_t)t * 2048 * 512);
  }
  gemm_pipe<64><<<dim3(8, 32, 3), 256, 0, stream>>>(CTXb, 512, (size_t)2048 * 512, aoutT, 512, (size_t)512 * 512,
      aout_b, 512, nullptr, COMBb, 1536, 512, 512, 0);

  // 3. time mixer
  gemm_pipe<64><<<dim3(8, 32, 1), 256, 0, stream>>>(COMBb, 1536, 0, mx1T, 1536, 0,
      mx_b1, 0, MBUF, nullptr, 512, 0, 1536, 0);
  ln_mixer_softmax<<<512, 256, 0, stream>>>(MBUF, mx_ln_g, mx_ln_b, mx_W2, mx_b2, MIX);
  weighted_kernel<<<4096, 256, 0, stream>>>(COMBb, MIX, WEI, WEIb);

  // 4. transformer encoder layer (post-norm)
  gemm_pipe<128><<<dim3(24, 16, 1), 256, 0, stream>>>(WEIb, 512, 0, elqkvT, 512, 0,
      el_qkv_b, 0, nullptr, QKVb, 1536, 0, 512, 0);
  transpose_v<<<dim3(8, 32, 1), 256, 0, stream>>>(QKVb, 0, VTb, 0);
  attn_scores_bf<<<dim3(4, 4, 32), 256, 0, stream>>>(QKVb, nullptr, SCORES);
  softmax_bf<<<4096, 256, 0, stream>>>(SCORES);
  attn_pv_bf<<<dim3(8, 32), 256, 0, stream>>>(PROBS, VTb, CTXb);
  gemm_pipe<64><<<dim3(8, 32, 1), 256, 0, stream>>>(CTXb, 512, 0, eloutT, 512, 0,
      el_out_b, 0, SA, nullptr, 512, 0, 512, 0);
  ln_rows<<<512, 256, 0, stream>>>(WEI, SA, el_ln1_g, el_ln1_b, H1, H1b, 0);
  gemm_pipe<128><<<dim3(32, 16, 1), 256, 0, stream>>>(H1b, 512, 0, ff1T, 512, 0,
      el_ff_b1, 0, nullptr, FFB, 2048, 0, 512, 1);
  gemm_pipe<64><<<dim3(8, 32, 1), 256, 0, stream>>>(FFB, 2048, 0, ff2T, 2048, 0,
      el_ff_b2, 0, SA, nullptr, 512, 0, 2048, 0);
  ln_rows<<<512, 256, 0, stream>>>(H1, SA, el_ln2_g, el_ln2_b, H2, H2b, 0);

  // 5. output projection + final LN
  gemm_pipe<64><<<dim3(8, 32, 1), 256, 0, stream>>>(H2b, 512, 0, opT, 512, 0,
      op_b, 0, OPO, nullptr, 512, 0, 512, 0);
  ln_rows<<<512, 256, 0, stream>>>(OPO, nullptr, op_ln_g, op_ln_b, (float*)d_out, nullptr, 0);
}

// Round 7
// 226.644 us; speedup vs baseline: 8.6288x; 1.3492x over previous
//
#include <hip/hip_runtime.h>
#include <hip/hip_bf16.h>
#include <math.h>

#define Bq 4
#define Sq 512
#define Hq 512
#define NHq 8
#define Tq 3
#define DTSq 170
#define BSq 2048
#define ENCSTRIDE 520
#define NLUT 2048
#define MAGMAXf 5.6304994f

typedef float f32x4 __attribute__((ext_vector_type(4)));
typedef __bf16 bf16x4 __attribute__((ext_vector_type(4)));
typedef __bf16 bf16x8 __attribute__((ext_vector_type(8)));

__device__ __forceinline__ float gelu_f(float x){
  return 0.5f * x * (1.0f + erff(x * 0.70710678118654752f));
}

__device__ __forceinline__ void gload16(const void* g, void* l){
  __builtin_amdgcn_global_load_lds((const __attribute__((address_space(1))) void*)g,
                                   (__attribute__((address_space(3))) void*)l, 16, 0, 0);
}

__device__ __forceinline__ float waveReduceSum(float v){
  #pragma unroll
  for (int off = 32; off > 0; off >>= 1) v += __shfl_xor(v, off);
  return v;
}

__device__ __forceinline__ float blockReduce(float v, float* red){
  int tid = threadIdx.x;
  __syncthreads();
  red[tid] = v; __syncthreads();
  for (int s = 128; s > 0; s >>= 1){
    if (tid < s) red[tid] += red[tid + s];
    __syncthreads();
  }
  return red[0];
}

// ---------------- encoder prep: centered vectors + covariance scalars -------
__global__ __launch_bounds__(256) void enc_prep(const float* __restrict__ encW,
                                                const float* __restrict__ encB,
                                                float* __restrict__ out){
  int t = blockIdx.x, tid = threadIdx.x;
  __shared__ float red[256];
  const float* W0 = encW + t * 2 * DTSq;
  const float* W1 = W0 + DTSq;
  const float* Bv = encB + t * DTSq;
  float w0 = (tid < DTSq) ? W0[tid] : 0.f;
  float w1 = (tid < DTSq) ? W1[tid] : 0.f;
  float bv = (tid < DTSq) ? Bv[tid] : 0.f;
  const float invD = 1.0f / (float)DTSq;
  float m0 = blockReduce(w0, red) * invD;
  float m1 = blockReduce(w1, red) * invD;
  float mb = blockReduce(bv, red) * invD;
  float c0 = (tid < DTSq) ? (w0 - m0) : 0.f;
  float c1 = (tid < DTSq) ? (w1 - m1) : 0.f;
  float cb = (tid < DTSq) ? (bv - mb) : 0.f;
  float* op = out + t * ENCSTRIDE;
  if (tid < DTSq){
    op[tid] = c0; op[DTSq + tid] = c1; op[2 * DTSq + tid] = cb;
  }
  float pa = blockReduce(c0 * c0, red) * invD;
  float pb = blockReduce(c1 * c1, red) * invD;
  float pc = blockReduce(c0 * c1, red) * invD;
  float pd = blockReduce(c0 * cb, red) * invD;
  float pe = blockReduce(c1 * cb, red) * invD;
  float pf = blockReduce(cb * cb, red) * invD;
  if (tid == 0){
    op[3 * DTSq + 0] = pa; op[3 * DTSq + 1] = pb; op[3 * DTSq + 2] = pc;
    op[3 * DTSq + 3] = pd; op[3 * DTSq + 4] = pe; op[3 * DTSq + 5] = pf;
  }
}

// ---------------- mask LUT build ---------------------------------------------
__global__ __launch_bounds__(256) void mask_lut_build(const float* __restrict__ enc,
                                                      const float* __restrict__ g,
                                                      const float* __restrict__ be,
                                                      float* __restrict__ lut){
  int td = blockIdx.x;            // t*3 + dsel
  int t = td / 3, dsel = td % 3;
  float d = (float)(dsel - 1);
  __shared__ float sw0[DTSq], sw1[DTSq], sbc[DTSq], sg[DTSq], sbe[DTSq];
  const float* ep = enc + t * ENCSTRIDE;
  for (int c = threadIdx.x; c < DTSq; c += 256){
    sw0[c] = ep[c]; sw1[c] = ep[DTSq + c]; sbc[c] = ep[2 * DTSq + c];
    sg[c] = g[t * DTSq + c]; sbe[c] = be[t * DTSq + c];
  }
  __syncthreads();
  float A  = ep[3 * DTSq + 0], Bs = ep[3 * DTSq + 1], Cs = ep[3 * DTSq + 2];
  float Ds = ep[3 * DTSq + 3], Es = ep[3 * DTSq + 4], Fs = ep[3 * DTSq + 5];
  int e = blockIdx.y * 256 + threadIdx.x;
  float tscale = (t == 0) ? 1.f : ((t == 1) ? 0.1f : 0.01f);
  float m = (MAGMAXf / (float)(NLUT - 1)) * (float)e * tscale;
  float var = fabsf(d) * A + m * m * Bs + Fs + 2.f * (d * m * Cs + d * Ds + m * Es);
  float rs = rsqrtf(var + 1e-5f);
  float sum = 0.f;
  for (int c = 0; c < DTSq; ++c){
    float ee = fmaf(m, sw1[c], fmaf(d, sw0[c], sbc[c]));
    float n = fmaf(ee * rs, sg[c], sbe[c]);
    sum += n * 0.5f * (1.0f + erff(n * 0.70710678118654752f));
  }
  lut[td * NLUT + e] = sum * (1.0f / (float)DTSq);
}

// ---------------- mask fill via LUT interpolation (bf16 out) -----------------
__global__ __launch_bounds__(256) void mask_fill(const float* __restrict__ ts,
                                                 const float* __restrict__ lut,
                                                 __bf16* __restrict__ maskbuf){
  int bi = blockIdx.x;            // b*S + i
  int b = bi >> 9, i = bi & 511;
  float tsi = ts[bi];
  for (int j0 = 0; j0 < Sq; j0 += 256){
    int j = j0 + threadIdx.x;
    float dt = tsi - ts[(b << 9) + j];
    int dsel = (dt > 0.f) ? 2 : ((dt < 0.f) ? 0 : 1);
    float mag = log1pf(fabsf(dt) * (1.0f / 3600.0f));
    float u = mag * ((float)(NLUT - 1) / MAGMAXf);
    int i0 = (int)u; if (i0 > NLUT - 2) i0 = NLUT - 2;
    float f = u - (float)i0;
    #pragma unroll
    for (int t = 0; t < Tq; ++t){
      const float* lp = lut + (t * 3 + dsel) * NLUT + i0;
      float v = lp[0] + f * (lp[1] - lp[0]);
      maskbuf[(((size_t)(t * Bq + b) * Sq + i) * Sq) + j] = (__bf16)v;
    }
  }
}

// ---------------- merged weight transpose-convert ---------------------------
struct CvtEnt { const float* W; __bf16* WT; int ldw, ldt, ntn, start; };
struct CvtArgs { CvtEnt e[12]; };

__global__ __launch_bounds__(256) void cvt_wT_all(CvtArgs a){
  int bid = blockIdx.x;
  int i = 0;
  #pragma unroll
  for (int k = 1; k < 12; ++k) if (bid >= a.e[k].start) i = k;
  const float* W = a.e[i].W;
  __bf16* WT = a.e[i].WT;
  int ldw = a.e[i].ldw, ldt = a.e[i].ldt;
  int local = bid - a.e[i].start;
  int tn = local % a.e[i].ntn, tk = local / a.e[i].ntn;
  int n0 = tn * 64, k0 = tk * 64;
  __shared__ float T[64][65];
  int tid = threadIdx.x;
  #pragma unroll
  for (int q = 0; q < 16; ++q){
    int lin = q * 256 + tid;
    int r = lin >> 6, c = lin & 63;
    T[r][c] = W[(size_t)(k0 + r) * ldw + n0 + c];
  }
  __syncthreads();
  #pragma unroll
  for (int q = 0; q < 16; ++q){
    int lin = q * 256 + tid;
    int n = lin >> 6, k = lin & 63;
    WT[(size_t)(n0 + n) * ldt + k0 + k] = (__bf16)T[k][n];
  }
}

// ---------------- elementwise f32 -> bf16 ------------------------------------
__global__ __launch_bounds__(256) void cvt_bf(const float* __restrict__ in,
                                              __bf16* __restrict__ out, int n){
  int idx = (blockIdx.x * 256 + threadIdx.x) * 4;
  if (idx < n){
    float4 v = *(const float4*)&in[idx];
    bf16x4 r; r[0]=(__bf16)v.x; r[1]=(__bf16)v.y; r[2]=(__bf16)v.z; r[3]=(__bf16)v.w;
    *(bf16x4*)&out[idx] = r;
  }
}

// ---------------- pipelined bf16 MFMA GEMM: C = act(A @ BT^T + bias) ---------
template<int BM>
__global__ __launch_bounds__(256) void gemm_pipe(
    const __bf16* __restrict__ A, int lda, size_t sAz,
    const __bf16* __restrict__ BT, int ldb, size_t sBz,
    const float* __restrict__ bias, int sBiasz,
    float* __restrict__ C32, __bf16* __restrict__ C16, int ldc, size_t sCz,
    int K, int act)
{
  constexpr int MF = BM / 32;             // m-frags per wave
  constexpr int ABYTES = BM * 128;        // bytes per A buf (64 cols bf16)
  constexpr int BBYTES = 64 * 128;
  __shared__ __bf16 lds[(2 * (ABYTES + BBYTES)) / 2];
  int tid = threadIdx.x;

  // XCD-chunked block swizzle (all grids here are multiples of 8)
  int gx = gridDim.x, nwg = gx * gridDim.y;
  int lin = blockIdx.x + gx * blockIdx.y;
  int q8 = nwg >> 3;
  int swz = (lin & 7) * q8 + (lin >> 3);
  int bx = swz % gx, by = swz / gx;

  int z = blockIdx.z;
  A  += (size_t)z * sAz;
  BT += (size_t)z * sBz;
  const float* bz = bias ? bias + (size_t)z * sBiasz : nullptr;
  size_t cbase = (size_t)z * sCz;
  int brow = by * BM, bcol = bx * 64;

  int lane = tid & 63, w = tid >> 6;
  int wr = (w >> 1) * (BM / 2), wc = (w & 1) * 32;
  int lr = lane & 15, lg = lane >> 4;

  f32x4 acc[MF][2];
  #pragma unroll
  for (int m = 0; m < MF; ++m)
    #pragma unroll
    for (int n = 0; n < 2; ++n) acc[m][n] = (f32x4){0.f, 0.f, 0.f, 0.f};

  char* lbase = (char*)lds;

  auto stage = [&](int buf, int ko){
    char* ab = lbase + buf * (ABYTES + BBYTES);
    #pragma unroll
    for (int qq = 0; qq < BM / 32; ++qq){
      int byte = (qq * 256 + tid) * 16;
      int row = byte >> 7, col8 = byte & 127;
      int src = col8 ^ ((row & 7) << 4);          // inverse-swizzled source
      gload16(&A[(size_t)(brow + row) * lda + ko + (src >> 1)], ab + byte);
    }
    char* bb = ab + ABYTES;
    #pragma unroll
    for (int qq = 0; qq < 2; ++qq){
      int byte = (qq * 256 + tid) * 16;
      int row = byte >> 7, col8 = byte & 127;
      int src = col8 ^ ((row & 7) << 4);
      gload16(&BT[(size_t)(bcol + row) * ldb + ko + (src >> 1)], bb + byte);
    }
  };

  stage(0, 0);
  int nk = K >> 6;
  for (int kt = 0; kt < nk; ++kt){
    int cur = kt & 1;
    if (kt + 1 < nk){
      stage(cur ^ 1, (kt + 1) << 6);
      if constexpr (BM == 64) asm volatile("s_waitcnt vmcnt(4)" ::: "memory");
      else                    asm volatile("s_waitcnt vmcnt(6)" ::: "memory");
    } else {
      asm volatile("s_waitcnt vmcnt(0)" ::: "memory");
    }
    __builtin_amdgcn_s_barrier();
    __builtin_amdgcn_sched_barrier(0);
    char* ab = lbase + cur * (ABYTES + BBYTES);
    char* bb = ab + ABYTES;
    #pragma unroll
    for (int s = 0; s < 2; ++s){
      bf16x8 af[MF], bfr[2];
      #pragma unroll
      for (int m = 0; m < MF; ++m){
        int row = wr + m * 16 + lr;
        int col8 = (s * 64 + lg * 16) ^ ((row & 7) << 4);
        af[m] = *(const bf16x8*)(ab + row * 128 + col8);
      }
      #pragma unroll
      for (int n = 0; n < 2; ++n){
        int row = wc + n * 16 + lr;
        int col8 = (s * 64 + lg * 16) ^ ((row & 7) << 4);
        bfr[n] = *(const bf16x8*)(bb + row * 128 + col8);
      }
      #pragma unroll
      for (int m = 0; m < MF; ++m)
        #pragma unroll
        for (int n = 0; n < 2; ++n)
          acc[m][n] = __builtin_amdgcn_mfma_f32_16x16x32_bf16(af[m], bfr[n], acc[m][n], 0, 0, 0);
    }
    asm volatile("" ::: "memory");
    __builtin_amdgcn_s_barrier();
  }

  #pragma unroll
  for (int m = 0; m < MF; ++m){
    #pragma unroll
    for (int n = 0; n < 2; ++n){
      int col = bcol + wc + n * 16 + lr;
      float bv = bz ? bz[col] : 0.f;
      #pragma unroll
      for (int j = 0; j < 4; ++j){
        int row = brow + wr + m * 16 + lg * 4 + j;
        float v = acc[m][n][j] + bv;
        if (act) v = gelu_f(v);
        size_t idx = cbase + (size_t)row * ldc + col;
        if (C32) C32[idx] = v;
        if (C16) C16[idx] = (__bf16)v;
      }
    }
  }
}

// ---------------- flash attention: QK^T/8 (+mask) -> online softmax -> PV ----
// grid: x=io tiles (8), y=bh (32), z=t. 256 threads (4 waves, 16 Q-rows each).
__global__ __launch_bounds__(256) void flash_attn(
    const __bf16* __restrict__ qkv, size_t sQz,   // [2048][1536]
    const __bf16* __restrict__ vt,  size_t sVz,   // [32][64][512]
    const __bf16* __restrict__ mask, size_t sMz,  // [4][512][512] bf16 or null
    __bf16* __restrict__ ctx, size_t sCz)         // [2048][512]
{
  int t = blockIdx.z;
  qkv += (size_t)t * sQz;
  vt  += (size_t)t * sVz;
  ctx += (size_t)t * sCz;
  const __bf16* mk = mask ? mask + (size_t)t * sMz : nullptr;

  // XCD-chunked swizzle within z-slice: 256 blocks -> chunks of 32 per XCD
  int lin = blockIdx.x + (blockIdx.y << 3);
  int swz = (lin & 7) * 32 + (lin >> 3);
  int io = (swz & 7) * 64;
  int bh = swz >> 3;
  int b = bh >> 3, h = bh & 7;

  __shared__ __bf16 Qs[64][72], Ks[64][72], Vs[64][72];
  __shared__ __bf16 Ps[4][16][72];
  int tid = threadIdx.x, lane = tid & 63, w = tid >> 6;
  int lr = lane & 15, lg = lane >> 4;

  // load Q tile [64][64]
  #pragma unroll
  for (int q = 0; q < 2; ++q){
    int linr = q * 256 + tid;
    int r = linr >> 3, c0 = (linr & 7) * 8;
    *(bf16x8*)&Qs[r][c0] = *(const bf16x8*)&qkv[(size_t)(b * Sq + io + r) * 1536 + h * 64 + c0];
  }

  f32x4 o[4];                       // O: col d = n*16+lr, row = lg*4+reg
  #pragma unroll
  for (int n = 0; n < 4; ++n) o[n] = (f32x4){0.f, 0.f, 0.f, 0.f};
  float mrow[4] = {-1e30f, -1e30f, -1e30f, -1e30f};
  float lrow[4] = {0.f, 0.f, 0.f, 0.f};

  for (int jo = 0; jo < Sq; jo += 64){
    __syncthreads();                // prev iter done with Ks/Vs (also orders Q load)
    #pragma unroll
    for (int q = 0; q < 2; ++q){
      int linr = q * 256 + tid;
      int r = linr >> 3, c0 = (linr & 7) * 8;
      *(bf16x8*)&Ks[r][c0] = *(const bf16x8*)&qkv[(size_t)(b * Sq + jo + r) * 1536 + 512 + h * 64 + c0];
      *(bf16x8*)&Vs[r][c0] = *(const bf16x8*)&vt[((size_t)bh * 64 + r) * Sq + jo + c0];
    }
    __syncthreads();

    // S = Q K^T for this wave's 16 rows x 64 cols
    f32x4 s4[4];
    #pragma unroll
    for (int n = 0; n < 4; ++n) s4[n] = (f32x4){0.f, 0.f, 0.f, 0.f};
    #pragma unroll
    for (int s = 0; s < 2; ++s){
      bf16x8 af = *(const bf16x8*)&Qs[w * 16 + lr][s * 32 + lg * 8];
      #pragma unroll
      for (int n = 0; n < 4; ++n){
        bf16x8 bfr = *(const bf16x8*)&Ks[n * 16 + lr][s * 32 + lg * 8];
        s4[n] = __builtin_amdgcn_mfma_f32_16x16x32_bf16(af, bfr, s4[n], 0, 0, 0);
      }
    }

    // scale + mask
    float sv[4][4];
    #pragma unroll
    for (int n = 0; n < 4; ++n){
      #pragma unroll
      for (int reg = 0; reg < 4; ++reg){
        float v = s4[n][reg] * 0.125f;
        if (mk){
          int irow = io + w * 16 + lg * 4 + reg;
          v += (float)mk[((size_t)b * Sq + irow) * Sq + jo + n * 16 + lr];
        }
        sv[n][reg] = v;
      }
    }

    // online softmax per row (reg): reduce over n frags + 16 lr lanes
    #pragma unroll
    for (int reg = 0; reg < 4; ++reg){
      float pmax = fmaxf(fmaxf(sv[0][reg], sv[1][reg]), fmaxf(sv[2][reg], sv[3][reg]));
      #pragma unroll
      for (int off = 1; off < 16; off <<= 1) pmax = fmaxf(pmax, __shfl_xor(pmax, off));
      float mnew = fmaxf(mrow[reg], pmax);
      float corr = __expf(mrow[reg] - mnew);
      mrow[reg] = mnew;
      float rs = 0.f;
      #pragma unroll
      for (int n = 0; n < 4; ++n){
        float p = __expf(sv[n][reg] - mnew);
        sv[n][reg] = p;
        rs += p;
      }
      #pragma unroll
      for (int off = 1; off < 16; off <<= 1) rs += __shfl_xor(rs, off);
      lrow[reg] = lrow[reg] * corr + rs;
      #pragma unroll
      for (int n = 0; n < 4; ++n) o[n][reg] *= corr;   // FIX: per-row rescale (r6 bug: broadcast)
    }

    // P -> LDS (per-wave region), then PV accumulate
    #pragma unroll
    for (int n = 0; n < 4; ++n)
      #pragma unroll
      for (int reg = 0; reg < 4; ++reg)
        Ps[w][lg * 4 + reg][n * 16 + lr] = (__bf16)sv[n][reg];
    #pragma unroll
    for (int s = 0; s < 2; ++s){
      bf16x8 af = *(const bf16x8*)&Ps[w][lr][s * 32 + lg * 8];
      #pragma unroll
      for (int n = 0; n < 4; ++n){
        bf16x8 bfr = *(const bf16x8*)&Vs[n * 16 + lr][s * 32 + lg * 8];
        o[n] = __builtin_amdgcn_mfma_f32_16x16x32_bf16(af, bfr, o[n], 0, 0, 0);
      }
    }
  }

  // normalize + write ctx
  #pragma unroll
  for (int reg = 0; reg < 4; ++reg){
    float inv = 1.0f / lrow[reg];
    int row = b * Sq + io + w * 16 + lg * 4 + reg;
    #pragma unroll
    for (int n = 0; n < 4; ++n)
      ctx[(size_t)row * Hq + h * 64 + n * 16 + lr] = (__bf16)(o[n][reg] * inv);
  }
}

// ---------------- row LayerNorm (+residual), dual-dtype out ------------------
__global__ __launch_bounds__(256) void ln_rows(const float* __restrict__ in,
                                               const float* __restrict__ res,
                                               const float* __restrict__ g,
                                               const float* __restrict__ bb,
                                               float* __restrict__ out32,
                                               __bf16* __restrict__ out16,
                                               int do_gelu){
  int row = blockIdx.x * 4 + (threadIdx.x >> 6);
  int lane = threadIdx.x & 63;
  const float* ir = in + (size_t)row * Hq;
  const float* rr = res ? res + (size_t)row * Hq : nullptr;
  float x[8]; float s = 0.f, sq = 0.f;
  #pragma unroll
  for (int k = 0; k < 8; ++k){
    int c = lane + 64 * k;
    float v = ir[c];
    if (rr) v += rr[c];
    x[k] = v; s += v; sq += v * v;
  }
  s = waveReduceSum(s); sq = waveReduceSum(sq);
  float mean = s * (1.0f / Hq);
  float var = fmaxf(sq * (1.0f / Hq) - mean * mean, 0.f);
  float rstd = rsqrtf(var + 1e-5f);
  #pragma unroll
  for (int k = 0; k < 8; ++k){
    int c = lane + 64 * k;
    float y = (x[k] - mean) * rstd * g[c] + bb[c];
    if (do_gelu) y = gelu_f(y);
    if (out32) out32[(size_t)row * Hq + c] = y;
    if (out16) out16[(size_t)row * Hq + c] = (__bf16)y;
  }
}

// ------- fused: LN + gelu + mixer2 + softmax over T + weighted combine -------
__global__ __launch_bounds__(256) void ln_mixer_weighted(const float* __restrict__ in,
                                                         const float* __restrict__ g,
                                                         const float* __restrict__ bb,
                                                         const float* __restrict__ W2,
                                                         const float* __restrict__ b2,
                                                         const __bf16* __restrict__ comb,
                                                         float* __restrict__ out32,
                                                         __bf16* __restrict__ out16){
  int row = blockIdx.x * 4 + (threadIdx.x >> 6);
  int lane = threadIdx.x & 63;
  const float* ir = in + (size_t)row * Hq;
  float x[8]; float s = 0.f, sq = 0.f;
  #pragma unroll
  for (int k = 0; k < 8; ++k){
    int c = lane + 64 * k;
    float v = ir[c];
    x[k] = v; s += v; sq += v * v;
  }
  s = waveReduceSum(s); sq = waveReduceSum(sq);
  float mean = s * (1.0f / Hq);
  float var = fmaxf(sq * (1.0f / Hq) - mean * mean, 0.f);
  float rstd = rsqrtf(var + 1e-5f);
  float a0 = 0.f, a1 = 0.f, a2 = 0.f;
  #pragma unroll
  for (int k = 0; k < 8; ++k){
    int c = lane + 64 * k;
    float y = gelu_f((x[k] - mean) * rstd * g[c] + bb[c]);
    const float* wv = W2 + c * 3;
    a0 = fmaf(y, wv[0], a0); a1 = fmaf(y, wv[1], a1); a2 = fmaf(y, wv[2], a2);
  }
  a0 = waveReduceSum(a0) + b2[0];
  a1 = waveReduceSum(a1) + b2[1];
  a2 = waveReduceSum(a2) + b2[2];
  float mx = fmaxf(a0, fmaxf(a1, a2));
  float e0 = __expf(a0 - mx), e1 = __expf(a1 - mx), e2 = __expf(a2 - mx);
  float inv = 1.0f / (e0 + e1 + e2);
  float m0 = e0 * inv, m1 = e1 * inv, m2 = e2 * inv;
  const __bf16* cr = comb + (size_t)row * 1536;
  #pragma unroll
  for (int k = 0; k < 8; ++k){
    int c = lane + 64 * k;
    float v = m0 * (float)cr[c] + m1 * (float)cr[512 + c] + m2 * (float)cr[1024 + c];
    out32[(size_t)row * Hq + c] = v;
    out16[(size_t)row * Hq + c] = (__bf16)v;
  }
}

// ---------------- V transpose per head (z-batched over t) --------------------
__global__ __launch_bounds__(256) void transpose_v(const __bf16* __restrict__ qkv, size_t sQz,
                                                   __bf16* __restrict__ vt, size_t sVz){
  int t = blockIdx.z;
  qkv += (size_t)t * sQz;
  vt  += (size_t)t * sVz;
  int bh = blockIdx.y, b = bh >> 3, h = bh & 7;
  int so = blockIdx.x * 64;
  __shared__ __bf16 T[64][72];
  int tid = threadIdx.x;
  #pragma unroll
  for (int q = 0; q < 16; ++q){
    int lin = q * 256 + tid;
    int r = lin >> 6, c = lin & 63;
    T[r][c] = qkv[(size_t)(b * Sq + so + r) * 1536 + 1024 + h * 64 + c];
  }
  __syncthreads();
  #pragma unroll
  for (int q = 0; q < 16; ++q){
    int lin = q * 256 + tid;
    int d = lin >> 6, s = lin & 63;
    vt[((size_t)bh * 64 + d) * Sq + so + s] = T[s][d];
  }
}

extern "C" void kernel_launch(void* const* d_in, const int* in_sizes, int n_in,
                              void* d_out, int out_size, void* d_ws, size_t ws_size,
                              hipStream_t stream){
  const float* x         = (const float*)d_in[0];
  const float* ts        = (const float*)d_in[1];
  const float* enc_W     = (const float*)d_in[2];
  const float* enc_b     = (const float*)d_in[3];
  const float* enc_ln_g  = (const float*)d_in[4];
  const float* enc_ln_b  = (const float*)d_in[5];
  const float* qkv_W     = (const float*)d_in[6];
  const float* qkv_b     = (const float*)d_in[7];
  const float* aout_W    = (const float*)d_in[8];
  const float* aout_b    = (const float*)d_in[9];
  const float* mx_W1     = (const float*)d_in[10];
  const float* mx_b1     = (const float*)d_in[11];
  const float* mx_ln_g   = (const float*)d_in[12];
  const float* mx_ln_b   = (const float*)d_in[13];
  const float* mx_W2     = (const float*)d_in[14];
  const float* mx_b2     = (const float*)d_in[15];
  const float* el_qkv_W  = (const float*)d_in[16];
  const float* el_qkv_b  = (const float*)d_in[17];
  const float* el_out_W  = (const float*)d_in[18];
  const float* el_out_b  = (const float*)d_in[19];
  const float* el_ln1_g  = (const float*)d_in[20];
  const float* el_ln1_b  = (const float*)d_in[21];
  const float* el_ff_W1  = (const float*)d_in[22];
  const float* el_ff_b1  = (const float*)d_in[23];
  const float* el_ff_W2  = (const float*)d_in[24];
  const float* el_ff_b2  = (const float*)d_in[25];
  const float* el_ln2_g  = (const float*)d_in[26];
  const float* el_ln2_b  = (const float*)d_in[27];
  const float* op_W      = (const float*)d_in[28];
  const float* op_b      = (const float*)d_in[29];
  const float* op_ln_g   = (const float*)d_in[30];
  const float* op_ln_b   = (const float*)d_in[31];

  float* ws = (float*)d_ws;
  size_t o = 0;
  __bf16* MASKBb = (__bf16*)(ws + o); o += 1572864;           // [3][4][512][512]
  __bf16* XB     = (__bf16*)(ws + o); o += 524288;            // [2048][512]
  __bf16* qkvT   = (__bf16*)(ws + o); o += 1179648;           // [3][1536][512]
  __bf16* aoutT  = (__bf16*)(ws + o); o += 393216;            // [3][512][512]
  __bf16* mx1T   = (__bf16*)(ws + o); o += 393216;            // [512][1536]
  __bf16* elqkvT = (__bf16*)(ws + o); o += 393216;            // [1536][512]
  __bf16* eloutT = (__bf16*)(ws + o); o += 131072;            // [512][512]
  __bf16* ff1T   = (__bf16*)(ws + o); o += 524288;            // [2048][512]
  __bf16* ff2T   = (__bf16*)(ws + o); o += 524288;            // [512][2048]
  __bf16* opT    = (__bf16*)(ws + o); o += 131072;            // [512][512]
  __bf16* QKVb   = (__bf16*)(ws + o); o += 4718592;           // [3][2048][1536]
  __bf16* VTb    = (__bf16*)(ws + o); o += 1572864;           // [3][32][64][512]
  __bf16* FFBb   = (__bf16*)(ws + o); o += 2097152;           // [2048][2048]
  __bf16* CTXb   = (__bf16*)(ws + o); o += 1572864;           // [3][2048][512]
  __bf16* COMBb  = (__bf16*)(ws + o); o += 1572864;           // [2048][1536]
  float*  MBUF   = ws + o;            o += 1048576;           // mixer1 out, also OPO
  float*  WEI    = ws + o;            o += 1048576;
  __bf16* WEIb   = (__bf16*)(ws + o); o += 524288;
  float*  SA     = ws + o;            o += 1048576;
  float*  H1     = ws + o;            o += 1048576;
  __bf16* H1b    = (__bf16*)(ws + o); o += 524288;
  float*  H2     = ws + o;            o += 1048576;
  __bf16* H2b    = (__bf16*)(ws + o); o += 524288;
  float*  ENC    = ws + o;            o += 1600;
  float*  LUTB   = ws + o;            o += 9 * NLUT;
  float*  OPO    = MBUF;

  // 0. dtype conversions (merged)
  cvt_bf<<<1024, 256, 0, stream>>>(x, XB, BSq * Hq);
  {
    CvtArgs ca;
    for (int t = 0; t < 3; ++t)
      ca.e[t] = {qkv_W + (size_t)t * 512 * 1536, qkvT + (size_t)t * 1536 * 512, 1536, 512, 24, 192 * t};
    for (int t = 0; t < 3; ++t)
      ca.e[3 + t] = {aout_W + (size_t)t * 512 * 512, aoutT + (size_t)t * 512 * 512, 512, 512, 8, 576 + 64 * t};
    ca.e[6]  = {mx_W1,    mx1T,   512,  1536, 8,  768};
    ca.e[7]  = {el_qkv_W, elqkvT, 1536, 512,  24, 960};
    ca.e[8]  = {el_out_W, eloutT, 512,  512,  8,  1152};
    ca.e[9]  = {el_ff_W1, ff1T,   2048, 512,  32, 1216};
    ca.e[10] = {el_ff_W2, ff2T,   512,  2048, 8,  1472};
    ca.e[11] = {op_W,     opT,    512,  512,  8,  1728};
    cvt_wT_all<<<1792, 256, 0, stream>>>(ca);
  }

  // 1. temporal masks
  enc_prep<<<Tq, 256, 0, stream>>>(enc_W, enc_b, ENC);
  mask_lut_build<<<dim3(9, NLUT / 256), 256, 0, stream>>>(ENC, enc_ln_g, enc_ln_b, LUTB);
  mask_fill<<<BSq, 256, 0, stream>>>(ts, LUTB, MASKBb);

  // 2. per-timescale masked attention (flash, t-batched)
  gemm_pipe<128><<<dim3(24, 16, 3), 256, 0, stream>>>(XB, 512, 0, qkvT, 512, (size_t)1536 * 512,
      qkv_b, 1536, nullptr, QKVb, 1536, (size_t)2048 * 1536, 512, 0);
  transpose_v<<<dim3(8, 32, 3), 256, 0, stream>>>(QKVb, (size_t)2048 * 1536, VTb, (size_t)32 * 64 * 512);
  flash_attn<<<dim3(8, 32, 3), 256, 0, stream>>>(QKVb, (size_t)2048 * 1536,
      VTb, (size_t)32 * 64 * 512, MASKBb, (size_t)4 * 512 * 512, CTXb, (size_t)2048 * 512);
  gemm_pipe<64><<<dim3(8, 32, 3), 256, 0, stream>>>(CTXb, 512, (size_t)2048 * 512, aoutT, 512, (size_t)512 * 512,
      aout_b, 512, nullptr, COMBb, 1536, 512, 512, 0);

  // 3. time mixer (fused LN+gelu+mixer2+softmax+weighted)
  gemm_pipe<64><<<dim3(8, 32, 1), 256, 0, stream>>>(COMBb, 1536, 0, mx1T, 1536, 0,
      mx_b1, 0, MBUF, nullptr, 512, 0, 1536, 0);
  ln_mixer_weighted<<<512, 256, 0, stream>>>(MBUF, mx_ln_g, mx_ln_b, mx_W2, mx_b2, COMBb, WEI, WEIb);

  // 4. transformer encoder layer (post-norm)
  gemm_pipe<128><<<dim3(24, 16, 1), 256, 0, stream>>>(WEIb, 512, 0, elqkvT, 512, 0,
      el_qkv_b, 0, nullptr, QKVb, 1536, 0, 512, 0);
  transpose_v<<<dim3(8, 32, 1), 256, 0, stream>>>(QKVb, 0, VTb, 0);
  flash_attn<<<dim3(8, 32, 1), 256, 0, stream>>>(QKVb, 0, VTb, 0, nullptr, 0, CTXb, 0);
  gemm_pipe<64><<<dim3(8, 32, 1), 256, 0, stream>>>(CTXb, 512, 0, eloutT, 512, 0,
      el_out_b, 0, SA, nullptr, 512, 0, 512, 0);
  ln_rows<<<512, 256, 0, stream>>>(WEI, SA, el_ln1_g, el_ln1_b, H1, H1b, 0);
  gemm_pipe<128><<<dim3(32, 16, 1), 256, 0, stream>>>(H1b, 512, 0, ff1T, 512, 0,
      el_ff_b1, 0, nullptr, FFBb, 2048, 0, 512, 1);
  gemm_pipe<64><<<dim3(8, 32, 1), 256, 0, stream>>>(FFBb, 2048, 0, ff2T, 2048, 0,
      el_ff_b2, 0, SA, nullptr, 512, 0, 2048, 0);
  ln_rows<<<512, 256, 0, stream>>>(H1, SA, el_ln2_g, el_ln2_b, H2, H2b, 0);

  // 5. output projection + final LN
  gemm_pipe<64><<<dim3(8, 32, 1), 256, 0, stream>>>(H2b, 512, 0, opT, 512, 0,
      op_b, 0, OPO, nullptr, 512, 0, 512, 0);
  ln_rows<<<512, 256, 0, stream>>>(OPO, nullptr, op_ln_g, op_ln_b, (float*)d_out, nullptr, 0);
}

// Round 8
// 216.979 us; speedup vs baseline: 9.0131x; 1.0445x over previous
//
#include <hip/hip_runtime.h>
#include <hip/hip_bf16.h>
#include <math.h>

#define Bq 4
#define Sq 512
#define Hq 512
#define NHq 8
#define Tq 3
#define DTSq 170
#define BSq 2048
#define ENCSTRIDE 520
#define NLUT 2048
#define MAGMAXf 5.6304994f

typedef float f32x4 __attribute__((ext_vector_type(4)));
typedef __bf16 bf16x4 __attribute__((ext_vector_type(4)));
typedef __bf16 bf16x8 __attribute__((ext_vector_type(8)));

__device__ __forceinline__ float gelu_f(float x){
  return 0.5f * x * (1.0f + erff(x * 0.70710678118654752f));
}

__device__ __forceinline__ void gload16(const void* g, void* l){
  __builtin_amdgcn_global_load_lds((const __attribute__((address_space(1))) void*)g,
                                   (__attribute__((address_space(3))) void*)l, 16, 0, 0);
}

__device__ __forceinline__ float waveReduceSum(float v){
  #pragma unroll
  for (int off = 32; off > 0; off >>= 1) v += __shfl_xor(v, off);
  return v;
}

__device__ __forceinline__ float blockReduce(float v, float* red){
  int tid = threadIdx.x;
  __syncthreads();
  red[tid] = v; __syncthreads();
  for (int s = 128; s > 0; s >>= 1){
    if (tid < s) red[tid] += red[tid + s];
    __syncthreads();
  }
  return red[0];
}

// ---------------- encoder prep: centered vectors + covariance scalars -------
__global__ __launch_bounds__(256) void enc_prep(const float* __restrict__ encW,
                                                const float* __restrict__ encB,
                                                float* __restrict__ out){
  int t = blockIdx.x, tid = threadIdx.x;
  __shared__ float red[256];
  const float* W0 = encW + t * 2 * DTSq;
  const float* W1 = W0 + DTSq;
  const float* Bv = encB + t * DTSq;
  float w0 = (tid < DTSq) ? W0[tid] : 0.f;
  float w1 = (tid < DTSq) ? W1[tid] : 0.f;
  float bv = (tid < DTSq) ? Bv[tid] : 0.f;
  const float invD = 1.0f / (float)DTSq;
  float m0 = blockReduce(w0, red) * invD;
  float m1 = blockReduce(w1, red) * invD;
  float mb = blockReduce(bv, red) * invD;
  float c0 = (tid < DTSq) ? (w0 - m0) : 0.f;
  float c1 = (tid < DTSq) ? (w1 - m1) : 0.f;
  float cb = (tid < DTSq) ? (bv - mb) : 0.f;
  float* op = out + t * ENCSTRIDE;
  if (tid < DTSq){
    op[tid] = c0; op[DTSq + tid] = c1; op[2 * DTSq + tid] = cb;
  }
  float pa = blockReduce(c0 * c0, red) * invD;
  float pb = blockReduce(c1 * c1, red) * invD;
  float pc = blockReduce(c0 * c1, red) * invD;
  float pd = blockReduce(c0 * cb, red) * invD;
  float pe = blockReduce(c1 * cb, red) * invD;
  float pf = blockReduce(cb * cb, red) * invD;
  if (tid == 0){
    op[3 * DTSq + 0] = pa; op[3 * DTSq + 1] = pb; op[3 * DTSq + 2] = pc;
    op[3 * DTSq + 3] = pd; op[3 * DTSq + 4] = pe; op[3 * DTSq + 5] = pf;
  }
}

// ---------------- mask LUT build ---------------------------------------------
__global__ __launch_bounds__(256) void mask_lut_build(const float* __restrict__ enc,
                                                      const float* __restrict__ g,
                                                      const float* __restrict__ be,
                                                      float* __restrict__ lut){
  int td = blockIdx.x;            // t*3 + dsel
  int t = td / 3, dsel = td % 3;
  float d = (float)(dsel - 1);
  __shared__ float sw0[DTSq], sw1[DTSq], sbc[DTSq], sg[DTSq], sbe[DTSq];
  const float* ep = enc + t * ENCSTRIDE;
  for (int c = threadIdx.x; c < DTSq; c += 256){
    sw0[c] = ep[c]; sw1[c] = ep[DTSq + c]; sbc[c] = ep[2 * DTSq + c];
    sg[c] = g[t * DTSq + c]; sbe[c] = be[t * DTSq + c];
  }
  __syncthreads();
  float A  = ep[3 * DTSq + 0], Bs = ep[3 * DTSq + 1], Cs = ep[3 * DTSq + 2];
  float Ds = ep[3 * DTSq + 3], Es = ep[3 * DTSq + 4], Fs = ep[3 * DTSq + 5];
  int e = blockIdx.y * 256 + threadIdx.x;
  float tscale = (t == 0) ? 1.f : ((t == 1) ? 0.1f : 0.01f);
  float m = (MAGMAXf / (float)(NLUT - 1)) * (float)e * tscale;
  float var = fabsf(d) * A + m * m * Bs + Fs + 2.f * (d * m * Cs + d * Ds + m * Es);
  float rs = rsqrtf(var + 1e-5f);
  float sum = 0.f;
  for (int c = 0; c < DTSq; ++c){
    float ee = fmaf(m, sw1[c], fmaf(d, sw0[c], sbc[c]));
    float n = fmaf(ee * rs, sg[c], sbe[c]);
    sum += n * 0.5f * (1.0f + erff(n * 0.70710678118654752f));
  }
  lut[td * NLUT + e] = sum * (1.0f / (float)DTSq);
}

// ---------------- mask fill via LUT interpolation (bf16 out) -----------------
__global__ __launch_bounds__(256) void mask_fill(const float* __restrict__ ts,
                                                 const float* __restrict__ lut,
                                                 __bf16* __restrict__ maskbuf){
  int bi = blockIdx.x;            // b*S + i
  int b = bi >> 9, i = bi & 511;
  float tsi = ts[bi];
  for (int j0 = 0; j0 < Sq; j0 += 256){
    int j = j0 + threadIdx.x;
    float dt = tsi - ts[(b << 9) + j];
    int dsel = (dt > 0.f) ? 2 : ((dt < 0.f) ? 0 : 1);
    float mag = log1pf(fabsf(dt) * (1.0f / 3600.0f));
    float u = mag * ((float)(NLUT - 1) / MAGMAXf);
    int i0 = (int)u; if (i0 > NLUT - 2) i0 = NLUT - 2;
    float f = u - (float)i0;
    #pragma unroll
    for (int t = 0; t < Tq; ++t){
      const float* lp = lut + (t * 3 + dsel) * NLUT + i0;
      float v = lp[0] + f * (lp[1] - lp[0]);
      maskbuf[(((size_t)(t * Bq + b) * Sq + i) * Sq) + j] = (__bf16)v;
    }
  }
}

// ---------------- merged weight transpose-convert ---------------------------
struct CvtEnt { const float* W; __bf16* WT; int ldw, ldt, ntn, start; };
struct CvtArgs { CvtEnt e[12]; };

__global__ __launch_bounds__(256) void cvt_wT_all(CvtArgs a){
  int bid = blockIdx.x;
  int i = 0;
  #pragma unroll
  for (int k = 1; k < 12; ++k) if (bid >= a.e[k].start) i = k;
  const float* W = a.e[i].W;
  __bf16* WT = a.e[i].WT;
  int ldw = a.e[i].ldw, ldt = a.e[i].ldt;
  int local = bid - a.e[i].start;
  int tn = local % a.e[i].ntn, tk = local / a.e[i].ntn;
  int n0 = tn * 64, k0 = tk * 64;
  __shared__ float T[64][65];
  int tid = threadIdx.x;
  #pragma unroll
  for (int q = 0; q < 16; ++q){
    int lin = q * 256 + tid;
    int r = lin >> 6, c = lin & 63;
    T[r][c] = W[(size_t)(k0 + r) * ldw + n0 + c];
  }
  __syncthreads();
  #pragma unroll
  for (int q = 0; q < 16; ++q){
    int lin = q * 256 + tid;
    int n = lin >> 6, k = lin & 63;
    WT[(size_t)(n0 + n) * ldt + k0 + k] = (__bf16)T[k][n];
  }
}

// ---------------- elementwise f32 -> bf16 ------------------------------------
__global__ __launch_bounds__(256) void cvt_bf(const float* __restrict__ in,
                                              __bf16* __restrict__ out, int n){
  int idx = (blockIdx.x * 256 + threadIdx.x) * 4;
  if (idx < n){
    float4 v = *(const float4*)&in[idx];
    bf16x4 r; r[0]=(__bf16)v.x; r[1]=(__bf16)v.y; r[2]=(__bf16)v.z; r[3]=(__bf16)v.w;
    *(bf16x4*)&out[idx] = r;
  }
}

// ---------------- pipelined bf16 MFMA GEMM: C = act(A @ BT^T + bias) ---------
template<int BM>
__global__ __launch_bounds__(256) void gemm_pipe(
    const __bf16* __restrict__ A, int lda, size_t sAz,
    const __bf16* __restrict__ BT, int ldb, size_t sBz,
    const float* __restrict__ bias, int sBiasz,
    float* __restrict__ C32, __bf16* __restrict__ C16, int ldc, size_t sCz,
    int K, int act)
{
  constexpr int MF = BM / 32;             // m-frags per wave
  constexpr int ABYTES = BM * 128;        // bytes per A buf (64 cols bf16)
  constexpr int BBYTES = 64 * 128;
  __shared__ __bf16 lds[(2 * (ABYTES + BBYTES)) / 2];
  int tid = threadIdx.x;

  // XCD-chunked block swizzle (all grids here are multiples of 8)
  int gx = gridDim.x, nwg = gx * gridDim.y;
  int lin = blockIdx.x + gx * blockIdx.y;
  int q8 = nwg >> 3;
  int swz = (lin & 7) * q8 + (lin >> 3);
  int bx = swz % gx, by = swz / gx;

  int z = blockIdx.z;
  A  += (size_t)z * sAz;
  BT += (size_t)z * sBz;
  const float* bz = bias ? bias + (size_t)z * sBiasz : nullptr;
  size_t cbase = (size_t)z * sCz;
  int brow = by * BM, bcol = bx * 64;

  int lane = tid & 63, w = tid >> 6;
  int wr = (w >> 1) * (BM / 2), wc = (w & 1) * 32;
  int lr = lane & 15, lg = lane >> 4;

  f32x4 acc[MF][2];
  #pragma unroll
  for (int m = 0; m < MF; ++m)
    #pragma unroll
    for (int n = 0; n < 2; ++n) acc[m][n] = (f32x4){0.f, 0.f, 0.f, 0.f};

  char* lbase = (char*)lds;

  auto stage = [&](int buf, int ko){
    char* ab = lbase + buf * (ABYTES + BBYTES);
    #pragma unroll
    for (int qq = 0; qq < BM / 32; ++qq){
      int byte = (qq * 256 + tid) * 16;
      int row = byte >> 7, col8 = byte & 127;
      int src = col8 ^ ((row & 7) << 4);          // inverse-swizzled source
      gload16(&A[(size_t)(brow + row) * lda + ko + (src >> 1)], ab + byte);
    }
    char* bb = ab + ABYTES;
    #pragma unroll
    for (int qq = 0; qq < 2; ++qq){
      int byte = (qq * 256 + tid) * 16;
      int row = byte >> 7, col8 = byte & 127;
      int src = col8 ^ ((row & 7) << 4);
      gload16(&BT[(size_t)(bcol + row) * ldb + ko + (src >> 1)], bb + byte);
    }
  };

  stage(0, 0);
  int nk = K >> 6;
  for (int kt = 0; kt < nk; ++kt){
    int cur = kt & 1;
    if (kt + 1 < nk){
      stage(cur ^ 1, (kt + 1) << 6);
      if constexpr (BM == 64) asm volatile("s_waitcnt vmcnt(4)" ::: "memory");
      else                    asm volatile("s_waitcnt vmcnt(6)" ::: "memory");
    } else {
      asm volatile("s_waitcnt vmcnt(0)" ::: "memory");
    }
    __builtin_amdgcn_s_barrier();
    __builtin_amdgcn_sched_barrier(0);
    char* ab = lbase + cur * (ABYTES + BBYTES);
    char* bb = ab + ABYTES;
    #pragma unroll
    for (int s = 0; s < 2; ++s){
      bf16x8 af[MF], bfr[2];
      #pragma unroll
      for (int m = 0; m < MF; ++m){
        int row = wr + m * 16 + lr;
        int col8 = (s * 64 + lg * 16) ^ ((row & 7) << 4);
        af[m] = *(const bf16x8*)(ab + row * 128 + col8);
      }
      #pragma unroll
      for (int n = 0; n < 2; ++n){
        int row = wc + n * 16 + lr;
        int col8 = (s * 64 + lg * 16) ^ ((row & 7) << 4);
        bfr[n] = *(const bf16x8*)(bb + row * 128 + col8);
      }
      #pragma unroll
      for (int m = 0; m < MF; ++m)
        #pragma unroll
        for (int n = 0; n < 2; ++n)
          acc[m][n] = __builtin_amdgcn_mfma_f32_16x16x32_bf16(af[m], bfr[n], acc[m][n], 0, 0, 0);
    }
    asm volatile("" ::: "memory");
    __builtin_amdgcn_s_barrier();
  }

  #pragma unroll
  for (int m = 0; m < MF; ++m){
    #pragma unroll
    for (int n = 0; n < 2; ++n){
      int col = bcol + wc + n * 16 + lr;
      float bv = bz ? bz[col] : 0.f;
      #pragma unroll
      for (int j = 0; j < 4; ++j){
        int row = brow + wr + m * 16 + lg * 4 + j;
        float v = acc[m][n][j] + bv;
        if (act) v = gelu_f(v);
        size_t idx = cbase + (size_t)row * ldc + col;
        if (C32) C32[idx] = v;
        if (C16) C16[idx] = (__bf16)v;
      }
    }
  }
}

// ---------------- flash attention v2: async K/V pipeline ---------------------
// grid: x=io tiles (8), y=bh (32), z=t. 256 threads (4 waves, 16 Q-rows each).
// Q hoisted to registers; K/V double-buffered via global_load_lds (swizzled);
// counted vmcnt (mask loads issued first: FIFO [cur4][mask16][next4]).
template<bool HM>
__global__ __launch_bounds__(256) void flash_attn(
    const __bf16* __restrict__ qkv, size_t sQz,   // [2048][1536]
    const __bf16* __restrict__ vt,  size_t sVz,   // [32][64][512]
    const __bf16* __restrict__ mask, size_t sMz,  // [4][512][512] bf16
    __bf16* __restrict__ ctx, size_t sCz)         // [2048][512]
{
  int t = blockIdx.z;
  qkv += (size_t)t * sQz;
  vt  += (size_t)t * sVz;
  ctx += (size_t)t * sCz;
  const __bf16* mk = HM ? mask + (size_t)t * sMz : nullptr;

  // XCD-chunked swizzle within z-slice (256 blocks -> 32 per XCD)
  int lin = blockIdx.x + (blockIdx.y << 3);
  int swz = (lin & 7) * 32 + (lin >> 3);
  int io = (swz & 7) * 64;
  int bh = swz >> 3;
  int b = bh >> 3, h = bh & 7;

  constexpr int KB = 64 * 128;                    // bytes per K or V tile
  __shared__ __bf16 lds[(2 * 2 * KB) / 2];        // 32 KB: [buf][K|V]
  __shared__ __bf16 Ps[4][16][72];
  int tid = threadIdx.x, lane = tid & 63, w = tid >> 6;
  int lr = lane & 15, lg = lane >> 4;

  // Q fragments in registers (loop-invariant)
  const __bf16* qrow = &qkv[(size_t)(b * Sq + io + w * 16 + lr) * 1536 + h * 64];
  bf16x8 q0 = *(const bf16x8*)&qrow[lg * 8];
  bf16x8 q1 = *(const bf16x8*)&qrow[32 + lg * 8];

  char* lb = (char*)lds;
  auto stage = [&](int buf, int jo){
    char* kb = lb + buf * (2 * KB);
    #pragma unroll
    for (int qq = 0; qq < 2; ++qq){
      int byte = (qq * 256 + tid) * 16;
      int row = byte >> 7, col8 = byte & 127;
      int src = col8 ^ ((row & 7) << 4);
      gload16(&qkv[(size_t)(b * Sq + jo + row) * 1536 + 512 + h * 64 + (src >> 1)], kb + byte);
    }
    char* vb = kb + KB;
    #pragma unroll
    for (int qq = 0; qq < 2; ++qq){
      int byte = (qq * 256 + tid) * 16;
      int row = byte >> 7, col8 = byte & 127;
      int src = col8 ^ ((row & 7) << 4);
      gload16(&vt[((size_t)bh * 64 + row) * Sq + jo + (src >> 1)], vb + byte);
    }
  };

  f32x4 o[4];
  #pragma unroll
  for (int n = 0; n < 4; ++n) o[n] = (f32x4){0.f, 0.f, 0.f, 0.f};
  float mrow[4] = {-1e30f, -1e30f, -1e30f, -1e30f};
  float lrow[4] = {0.f, 0.f, 0.f, 0.f};

  stage(0, 0);
  #pragma unroll
  for (int kt = 0; kt < 8; ++kt){
    int cur = kt & 1;
    int jo = kt << 6;

    // mask loads for current tile (issued BEFORE stage(next): FIFO order)
    float mv[4][4];
    if (HM){
      #pragma unroll
      for (int n = 0; n < 4; ++n)
        #pragma unroll
        for (int reg = 0; reg < 4; ++reg)
          mv[n][reg] = (float)mk[((size_t)(b * Sq + io + w * 16 + lg * 4 + reg)) * Sq + jo + n * 16 + lr];
    }

    if (kt + 1 < 8){
      stage(cur ^ 1, (kt + 1) << 6);
      if (HM) asm volatile("s_waitcnt vmcnt(20)" ::: "memory");  // cur4 drained; mask16+next4 in flight
      else    asm volatile("s_waitcnt vmcnt(4)"  ::: "memory");
    } else {
      asm volatile("s_waitcnt vmcnt(0)" ::: "memory");
    }
    __builtin_amdgcn_s_barrier();
    __builtin_amdgcn_sched_barrier(0);

    char* kb = lb + cur * (2 * KB);
    char* vb = kb + KB;

    // QK^T
    f32x4 s4[4];
    #pragma unroll
    for (int n = 0; n < 4; ++n) s4[n] = (f32x4){0.f, 0.f, 0.f, 0.f};
    __builtin_amdgcn_s_setprio(1);
    #pragma unroll
    for (int s = 0; s < 2; ++s){
      bf16x8 aq = s ? q1 : q0;
      #pragma unroll
      for (int n = 0; n < 4; ++n){
        int row = n * 16 + lr;
        int colb = (s * 64 + lg * 16) ^ ((row & 7) << 4);
        bf16x8 bk = *(const bf16x8*)(kb + row * 128 + colb);
        s4[n] = __builtin_amdgcn_mfma_f32_16x16x32_bf16(aq, bk, s4[n], 0, 0, 0);
      }
    }
    __builtin_amdgcn_s_setprio(0);

    // scale + mask
    float sv[4][4];
    #pragma unroll
    for (int n = 0; n < 4; ++n)
      #pragma unroll
      for (int reg = 0; reg < 4; ++reg)
        sv[n][reg] = s4[n][reg] * 0.125f + (HM ? mv[n][reg] : 0.f);

    // online softmax with defer-max (THR=8)
    #pragma unroll
    for (int reg = 0; reg < 4; ++reg){
      float pmax = fmaxf(fmaxf(sv[0][reg], sv[1][reg]), fmaxf(sv[2][reg], sv[3][reg]));
      #pragma unroll
      for (int off = 1; off < 16; off <<= 1) pmax = fmaxf(pmax, __shfl_xor(pmax, off));
      if (pmax > mrow[reg] + 8.0f){
        float corr = __expf(mrow[reg] - pmax);
        mrow[reg] = pmax;
        lrow[reg] *= corr;
        #pragma unroll
        for (int n = 0; n < 4; ++n) o[n][reg] *= corr;
      }
      float rs = 0.f;
      #pragma unroll
      for (int n = 0; n < 4; ++n){
        float p = __expf(sv[n][reg] - mrow[reg]);
        sv[n][reg] = p;
        rs += p;
      }
      #pragma unroll
      for (int off = 1; off < 16; off <<= 1) rs += __shfl_xor(rs, off);
      lrow[reg] += rs;
    }

    // P -> per-wave LDS region (no cross-wave barrier needed), then PV
    #pragma unroll
    for (int n = 0; n < 4; ++n)
      #pragma unroll
      for (int reg = 0; reg < 4; ++reg)
        Ps[w][lg * 4 + reg][n * 16 + lr] = (__bf16)sv[n][reg];
    __builtin_amdgcn_s_setprio(1);
    #pragma unroll
    for (int s = 0; s < 2; ++s){
      bf16x8 ap = *(const bf16x8*)&Ps[w][lr][s * 32 + lg * 8];
      #pragma unroll
      for (int n = 0; n < 4; ++n){
        int row = n * 16 + lr;
        int colb = (s * 64 + lg * 16) ^ ((row & 7) << 4);
        bf16x8 bv = *(const bf16x8*)(vb + row * 128 + colb);
        o[n] = __builtin_amdgcn_mfma_f32_16x16x32_bf16(ap, bv, o[n], 0, 0, 0);
      }
    }
    __builtin_amdgcn_s_setprio(0);

    asm volatile("" ::: "memory");
    __builtin_amdgcn_s_barrier();                 // protect buf reuse by next stage()
  }

  // normalize + write ctx
  #pragma unroll
  for (int reg = 0; reg < 4; ++reg){
    float inv = 1.0f / lrow[reg];
    int row = b * Sq + io + w * 16 + lg * 4 + reg;
    #pragma unroll
    for (int n = 0; n < 4; ++n)
      ctx[(size_t)row * Hq + h * 64 + n * 16 + lr] = (__bf16)(o[n][reg] * inv);
  }
}

// ---------------- row LayerNorm (+residual), dual-dtype out ------------------
__global__ __launch_bounds__(256) void ln_rows(const float* __restrict__ in,
                                               const float* __restrict__ res,
                                               const float* __restrict__ g,
                                               const float* __restrict__ bb,
                                               float* __restrict__ out32,
                                               __bf16* __restrict__ out16,
                                               int do_gelu){
  int row = blockIdx.x * 4 + (threadIdx.x >> 6);
  int lane = threadIdx.x & 63;
  const float* ir = in + (size_t)row * Hq;
  const float* rr = res ? res + (size_t)row * Hq : nullptr;
  float x[8]; float s = 0.f, sq = 0.f;
  #pragma unroll
  for (int k = 0; k < 8; ++k){
    int c = lane + 64 * k;
    float v = ir[c];
    if (rr) v += rr[c];
    x[k] = v; s += v; sq += v * v;
  }
  s = waveReduceSum(s); sq = waveReduceSum(sq);
  float mean = s * (1.0f / Hq);
  float var = fmaxf(sq * (1.0f / Hq) - mean * mean, 0.f);
  float rstd = rsqrtf(var + 1e-5f);
  #pragma unroll
  for (int k = 0; k < 8; ++k){
    int c = lane + 64 * k;
    float y = (x[k] - mean) * rstd * g[c] + bb[c];
    if (do_gelu) y = gelu_f(y);
    if (out32) out32[(size_t)row * Hq + c] = y;
    if (out16) out16[(size_t)row * Hq + c] = (__bf16)y;
  }
}

// ------- fused: LN + gelu + mixer2 + softmax over T + weighted combine -------
__global__ __launch_bounds__(256) void ln_mixer_weighted(const float* __restrict__ in,
                                                         const float* __restrict__ g,
                                                         const float* __restrict__ bb,
                                                         const float* __restrict__ W2,
                                                         const float* __restrict__ b2,
                                                         const __bf16* __restrict__ comb,
                                                         float* __restrict__ out32,
                                                         __bf16* __restrict__ out16){
  int row = blockIdx.x * 4 + (threadIdx.x >> 6);
  int lane = threadIdx.x & 63;
  const float* ir = in + (size_t)row * Hq;
  float x[8]; float s = 0.f, sq = 0.f;
  #pragma unroll
  for (int k = 0; k < 8; ++k){
    int c = lane + 64 * k;
    float v = ir[c];
    x[k] = v; s += v; sq += v * v;
  }
  s = waveReduceSum(s); sq = waveReduceSum(sq);
  float mean = s * (1.0f / Hq);
  float var = fmaxf(sq * (1.0f / Hq) - mean * mean, 0.f);
  float rstd = rsqrtf(var + 1e-5f);
  float a0 = 0.f, a1 = 0.f, a2 = 0.f;
  #pragma unroll
  for (int k = 0; k < 8; ++k){
    int c = lane + 64 * k;
    float y = gelu_f((x[k] - mean) * rstd * g[c] + bb[c]);
    const float* wv = W2 + c * 3;
    a0 = fmaf(y, wv[0], a0); a1 = fmaf(y, wv[1], a1); a2 = fmaf(y, wv[2], a2);
  }
  a0 = waveReduceSum(a0) + b2[0];
  a1 = waveReduceSum(a1) + b2[1];
  a2 = waveReduceSum(a2) + b2[2];
  float mx = fmaxf(a0, fmaxf(a1, a2));
  float e0 = __expf(a0 - mx), e1 = __expf(a1 - mx), e2 = __expf(a2 - mx);
  float inv = 1.0f / (e0 + e1 + e2);
  float m0 = e0 * inv, m1 = e1 * inv, m2 = e2 * inv;
  const __bf16* cr = comb + (size_t)row * 1536;
  #pragma unroll
  for (int k = 0; k < 8; ++k){
    int c = lane + 64 * k;
    float v = m0 * (float)cr[c] + m1 * (float)cr[512 + c] + m2 * (float)cr[1024 + c];
    out32[(size_t)row * Hq + c] = v;
    out16[(size_t)row * Hq + c] = (__bf16)v;
  }
}

// ---------------- V transpose per head (z-batched over t) --------------------
__global__ __launch_bounds__(256) void transpose_v(const __bf16* __restrict__ qkv, size_t sQz,
                                                   __bf16* __restrict__ vt, size_t sVz){
  int t = blockIdx.z;
  qkv += (size_t)t * sQz;
  vt  += (size_t)t * sVz;
  int bh = blockIdx.y, b = bh >> 3, h = bh & 7;
  int so = blockIdx.x * 64;
  __shared__ __bf16 T[64][72];
  int tid = threadIdx.x;
  #pragma unroll
  for (int q = 0; q < 16; ++q){
    int lin = q * 256 + tid;
    int r = lin >> 6, c = lin & 63;
    T[r][c] = qkv[(size_t)(b * Sq + so + r) * 1536 + 1024 + h * 64 + c];
  }
  __syncthreads();
  #pragma unroll
  for (int q = 0; q < 16; ++q){
    int lin = q * 256 + tid;
    int d = lin >> 6, s = lin & 63;
    vt[((size_t)bh * 64 + d) * Sq + so + s] = T[s][d];
  }
}

extern "C" void kernel_launch(void* const* d_in, const int* in_sizes, int n_in,
                              void* d_out, int out_size, void* d_ws, size_t ws_size,
                              hipStream_t stream){
  const float* x         = (const float*)d_in[0];
  const float* ts        = (const float*)d_in[1];
  const float* enc_W     = (const float*)d_in[2];
  const float* enc_b     = (const float*)d_in[3];
  const float* enc_ln_g  = (const float*)d_in[4];
  const float* enc_ln_b  = (const float*)d_in[5];
  const float* qkv_W     = (const float*)d_in[6];
  const float* qkv_b     = (const float*)d_in[7];
  const float* aout_W    = (const float*)d_in[8];
  const float* aout_b    = (const float*)d_in[9];
  const float* mx_W1     = (const float*)d_in[10];
  const float* mx_b1     = (const float*)d_in[11];
  const float* mx_ln_g   = (const float*)d_in[12];
  const float* mx_ln_b   = (const float*)d_in[13];
  const float* mx_W2     = (const float*)d_in[14];
  const float* mx_b2     = (const float*)d_in[15];
  const float* el_qkv_W  = (const float*)d_in[16];
  const float* el_qkv_b  = (const float*)d_in[17];
  const float* el_out_W  = (const float*)d_in[18];
  const float* el_out_b  = (const float*)d_in[19];
  const float* el_ln1_g  = (const float*)d_in[20];
  const float* el_ln1_b  = (const float*)d_in[21];
  const float* el_ff_W1  = (const float*)d_in[22];
  const float* el_ff_b1  = (const float*)d_in[23];
  const float* el_ff_W2  = (const float*)d_in[24];
  const float* el_ff_b2  = (const float*)d_in[25];
  const float* el_ln2_g  = (const float*)d_in[26];
  const float* el_ln2_b  = (const float*)d_in[27];
  const float* op_W      = (const float*)d_in[28];
  const float* op_b      = (const float*)d_in[29];
  const float* op_ln_g   = (const float*)d_in[30];
  const float* op_ln_b   = (const float*)d_in[31];

  float* ws = (float*)d_ws;
  size_t o = 0;
  __bf16* MASKBb = (__bf16*)(ws + o); o += 1572864;           // [3][4][512][512]
  __bf16* XB     = (__bf16*)(ws + o); o += 524288;            // [2048][512]
  __bf16* qkvT   = (__bf16*)(ws + o); o += 1179648;           // [3][1536][512]
  __bf16* aoutT  = (__bf16*)(ws + o); o += 393216;            // [3][512][512]
  __bf16* mx1T   = (__bf16*)(ws + o); o += 393216;            // [512][1536]
  __bf16* elqkvT = (__bf16*)(ws + o); o += 393216;            // [1536][512]
  __bf16* eloutT = (__bf16*)(ws + o); o += 131072;            // [512][512]
  __bf16* ff1T   = (__bf16*)(ws + o); o += 524288;            // [2048][512]
  __bf16* ff2T   = (__bf16*)(ws + o); o += 524288;            // [512][2048]
  __bf16* opT    = (__bf16*)(ws + o); o += 131072;            // [512][512]
  __bf16* QKVb   = (__bf16*)(ws + o); o += 4718592;           // [3][2048][1536]
  __bf16* VTb    = (__bf16*)(ws + o); o += 1572864;           // [3][32][64][512]
  __bf16* FFBb   = (__bf16*)(ws + o); o += 2097152;           // [2048][2048]
  __bf16* CTXb   = (__bf16*)(ws + o); o += 1572864;           // [3][2048][512]
  __bf16* COMBb  = (__bf16*)(ws + o); o += 1572864;           // [2048][1536]
  float*  MBUF   = ws + o;            o += 1048576;           // mixer1 out, also OPO
  float*  WEI    = ws + o;            o += 1048576;
  __bf16* WEIb   = (__bf16*)(ws + o); o += 524288;
  float*  SA     = ws + o;            o += 1048576;
  float*  H1     = ws + o;            o += 1048576;
  __bf16* H1b    = (__bf16*)(ws + o); o += 524288;
  float*  H2     = ws + o;            o += 1048576;
  __bf16* H2b    = (__bf16*)(ws + o); o += 524288;
  float*  ENC    = ws + o;            o += 1600;
  float*  LUTB   = ws + o;            o += 9 * NLUT;
  float*  OPO    = MBUF;

  // 0. dtype conversions (merged)
  cvt_bf<<<1024, 256, 0, stream>>>(x, XB, BSq * Hq);
  {
    CvtArgs ca;
    for (int t = 0; t < 3; ++t)
      ca.e[t] = {qkv_W + (size_t)t * 512 * 1536, qkvT + (size_t)t * 1536 * 512, 1536, 512, 24, 192 * t};
    for (int t = 0; t < 3; ++t)
      ca.e[3 + t] = {aout_W + (size_t)t * 512 * 512, aoutT + (size_t)t * 512 * 512, 512, 512, 8, 576 + 64 * t};
    ca.e[6]  = {mx_W1,    mx1T,   512,  1536, 8,  768};
    ca.e[7]  = {el_qkv_W, elqkvT, 1536, 512,  24, 960};
    ca.e[8]  = {el_out_W, eloutT, 512,  512,  8,  1152};
    ca.e[9]  = {el_ff_W1, ff1T,   2048, 512,  32, 1216};
    ca.e[10] = {el_ff_W2, ff2T,   512,  2048, 8,  1472};
    ca.e[11] = {op_W,     opT,    512,  512,  8,  1728};
    cvt_wT_all<<<1792, 256, 0, stream>>>(ca);
  }

  // 1. temporal masks
  enc_prep<<<Tq, 256, 0, stream>>>(enc_W, enc_b, ENC);
  mask_lut_build<<<dim3(9, NLUT / 256), 256, 0, stream>>>(ENC, enc_ln_g, enc_ln_b, LUTB);
  mask_fill<<<BSq, 256, 0, stream>>>(ts, LUTB, MASKBb);

  // 2. per-timescale masked attention (flash, t-batched)
  gemm_pipe<128><<<dim3(24, 16, 3), 256, 0, stream>>>(XB, 512, 0, qkvT, 512, (size_t)1536 * 512,
      qkv_b, 1536, nullptr, QKVb, 1536, (size_t)2048 * 1536, 512, 0);
  transpose_v<<<dim3(8, 32, 3), 256, 0, stream>>>(QKVb, (size_t)2048 * 1536, VTb, (size_t)32 * 64 * 512);
  flash_attn<true><<<dim3(8, 32, 3), 256, 0, stream>>>(QKVb, (size_t)2048 * 1536,
      VTb, (size_t)32 * 64 * 512, MASKBb, (size_t)4 * 512 * 512, CTXb, (size_t)2048 * 512);
  gemm_pipe<64><<<dim3(8, 32, 3), 256, 0, stream>>>(CTXb, 512, (size_t)2048 * 512, aoutT, 512, (size_t)512 * 512,
      aout_b, 512, nullptr, COMBb, 1536, 512, 512, 0);

  // 3. time mixer (fused LN+gelu+mixer2+softmax+weighted)
  gemm_pipe<64><<<dim3(8, 32, 1), 256, 0, stream>>>(COMBb, 1536, 0, mx1T, 1536, 0,
      mx_b1, 0, MBUF, nullptr, 512, 0, 1536, 0);
  ln_mixer_weighted<<<512, 256, 0, stream>>>(MBUF, mx_ln_g, mx_ln_b, mx_W2, mx_b2, COMBb, WEI, WEIb);

  // 4. transformer encoder layer (post-norm)
  gemm_pipe<128><<<dim3(24, 16, 1), 256, 0, stream>>>(WEIb, 512, 0, elqkvT, 512, 0,
      el_qkv_b, 0, nullptr, QKVb, 1536, 0, 512, 0);
  transpose_v<<<dim3(8, 32, 1), 256, 0, stream>>>(QKVb, 0, VTb, 0);
  flash_attn<false><<<dim3(8, 32, 1), 256, 0, stream>>>(QKVb, 0, VTb, 0, nullptr, 0, CTXb, 0);
  gemm_pipe<64><<<dim3(8, 32, 1), 256, 0, stream>>>(CTXb, 512, 0, eloutT, 512, 0,
      el_out_b, 0, SA, nullptr, 512, 0, 512, 0);
  ln_rows<<<512, 256, 0, stream>>>(WEI, SA, el_ln1_g, el_ln1_b, H1, H1b, 0);
  gemm_pipe<128><<<dim3(32, 16, 1), 256, 0, stream>>>(H1b, 512, 0, ff1T, 512, 0,
      el_ff_b1, 0, nullptr, FFBb, 2048, 0, 512, 1);
  gemm_pipe<64><<<dim3(8, 32, 1), 256, 0, stream>>>(FFBb, 2048, 0, ff2T, 2048, 0,
      el_ff_b2, 0, SA, nullptr, 512, 0, 2048, 0);
  ln_rows<<<512, 256, 0, stream>>>(H1, SA, el_ln2_g, el_ln2_b, H2, H2b, 0);

  // 5. output projection + final LN
  gemm_pipe<64><<<dim3(8, 32, 1), 256, 0, stream>>>(H2b, 512, 0, opT, 512, 0,
      op_b, 0, OPO, nullptr, 512, 0, 512, 0);
  ln_rows<<<512, 256, 0, stream>>>(OPO, nullptr, op_ln_g, op_ln_b, (float*)d_out, nullptr, 0);
}

// Round 9
// 214.888 us; speedup vs baseline: 9.1009x; 1.0097x over previous
//
#include <hip/hip_runtime.h>
#include <hip/hip_bf16.h>
#include <math.h>

#define Bq 4
#define Sq 512
#define Hq 512
#define NHq 8
#define Tq 3
#define DTSq 170
#define BSq 2048
#define NLUT 2048
#define MAGMAXf 5.6304994f

typedef float f32x4 __attribute__((ext_vector_type(4)));
typedef __bf16 bf16x4 __attribute__((ext_vector_type(4)));
typedef __bf16 bf16x8 __attribute__((ext_vector_type(8)));

__device__ __forceinline__ float gelu_f(float x){
  return 0.5f * x * (1.0f + erff(x * 0.70710678118654752f));
}

__device__ __forceinline__ void gload16(const void* g, void* l){
  __builtin_amdgcn_global_load_lds((const __attribute__((address_space(1))) void*)g,
                                   (__attribute__((address_space(3))) void*)l, 16, 0, 0);
}

__device__ __forceinline__ float waveReduceSum(float v){
  #pragma unroll
  for (int off = 32; off > 0; off >>= 1) v += __shfl_xor(v, off);
  return v;
}

__device__ __forceinline__ float blockReduce(float v, float* red){
  int tid = threadIdx.x;
  __syncthreads();
  red[tid] = v; __syncthreads();
  for (int s = 128; s > 0; s >>= 1){
    if (tid < s) red[tid] += red[tid + s];
    __syncthreads();
  }
  return red[0];
}

// ------ mask LUT build (enc_prep merged in; grid (9, NLUT/256)) -------------
__global__ __launch_bounds__(256) void mask_lut_build(const float* __restrict__ encW,
                                                      const float* __restrict__ encB,
                                                      const float* __restrict__ g,
                                                      const float* __restrict__ be,
                                                      float* __restrict__ lut){
  int td = blockIdx.x;            // t*3 + dsel
  int t = td / 3, dsel = td % 3;
  float d = (float)(dsel - 1);
  __shared__ float red[256];
  __shared__ float sw0[DTSq], sw1[DTSq], sbc[DTSq], sg[DTSq], sbe[DTSq];
  __shared__ float sS[6];
  int tid = threadIdx.x;
  const float* W0 = encW + t * 2 * DTSq;
  const float* W1 = W0 + DTSq;
  const float* Bv = encB + t * DTSq;
  float w0 = (tid < DTSq) ? W0[tid] : 0.f;
  float w1 = (tid < DTSq) ? W1[tid] : 0.f;
  float bv = (tid < DTSq) ? Bv[tid] : 0.f;
  const float invD = 1.0f / (float)DTSq;
  float m0 = blockReduce(w0, red) * invD;
  float m1 = blockReduce(w1, red) * invD;
  float mb = blockReduce(bv, red) * invD;
  float c0 = (tid < DTSq) ? (w0 - m0) : 0.f;
  float c1 = (tid < DTSq) ? (w1 - m1) : 0.f;
  float cb = (tid < DTSq) ? (bv - mb) : 0.f;
  if (tid < DTSq){
    sw0[tid] = c0; sw1[tid] = c1; sbc[tid] = cb;
    sg[tid] = g[t * DTSq + tid]; sbe[tid] = be[t * DTSq + tid];
  }
  float pa = blockReduce(c0 * c0, red) * invD;
  float pb = blockReduce(c1 * c1, red) * invD;
  float pc = blockReduce(c0 * c1, red) * invD;
  float pd = blockReduce(c0 * cb, red) * invD;
  float pe = blockReduce(c1 * cb, red) * invD;
  float pf = blockReduce(cb * cb, red) * invD;
  if (tid == 0){ sS[0]=pa; sS[1]=pb; sS[2]=pc; sS[3]=pd; sS[4]=pe; sS[5]=pf; }
  __syncthreads();
  float A = sS[0], Bs = sS[1], Cs = sS[2], Ds = sS[3], Es = sS[4], Fs = sS[5];
  int e = blockIdx.y * 256 + tid;
  float tscale = (t == 0) ? 1.f : ((t == 1) ? 0.1f : 0.01f);
  float m = (MAGMAXf / (float)(NLUT - 1)) * (float)e * tscale;
  float var = fabsf(d) * A + m * m * Bs + Fs + 2.f * (d * m * Cs + d * Ds + m * Es);
  float rs = rsqrtf(var + 1e-5f);
  float sum = 0.f;
  for (int c = 0; c < DTSq; ++c){
    float ee = fmaf(m, sw1[c], fmaf(d, sw0[c], sbc[c]));
    float n = fmaf(ee * rs, sg[c], sbe[c]);
    sum += n * 0.5f * (1.0f + erff(n * 0.70710678118654752f));
  }
  lut[td * NLUT + e] = sum * (1.0f / (float)DTSq);
}

// ---------------- mask fill via LUT interpolation (bf16 out) -----------------
__global__ __launch_bounds__(256) void mask_fill(const float* __restrict__ ts,
                                                 const float* __restrict__ lut,
                                                 __bf16* __restrict__ maskbuf){
  int bi = blockIdx.x;            // b*S + i
  int b = bi >> 9, i = bi & 511;
  float tsi = ts[bi];
  for (int j0 = 0; j0 < Sq; j0 += 256){
    int j = j0 + threadIdx.x;
    float dt = tsi - ts[(b << 9) + j];
    int dsel = (dt > 0.f) ? 2 : ((dt < 0.f) ? 0 : 1);
    float mag = log1pf(fabsf(dt) * (1.0f / 3600.0f));
    float u = mag * ((float)(NLUT - 1) / MAGMAXf);
    int i0 = (int)u; if (i0 > NLUT - 2) i0 = NLUT - 2;
    float f = u - (float)i0;
    #pragma unroll
    for (int t = 0; t < Tq; ++t){
      const float* lp = lut + (t * 3 + dsel) * NLUT + i0;
      float v = lp[0] + f * (lp[1] - lp[0]);
      maskbuf[(((size_t)(t * Bq + b) * Sq + i) * Sq) + j] = (__bf16)v;
    }
  }
}

// ---------------- merged weight transpose-convert ---------------------------
struct CvtEnt { const float* W; __bf16* WT; int ldw, ldt, ntn, start; };
struct CvtArgs { CvtEnt e[12]; };

__global__ __launch_bounds__(256) void cvt_wT_all(CvtArgs a){
  int bid = blockIdx.x;
  int i = 0;
  #pragma unroll
  for (int k = 1; k < 12; ++k) if (bid >= a.e[k].start) i = k;
  const float* W = a.e[i].W;
  __bf16* WT = a.e[i].WT;
  int ldw = a.e[i].ldw, ldt = a.e[i].ldt;
  int local = bid - a.e[i].start;
  int tn = local % a.e[i].ntn, tk = local / a.e[i].ntn;
  int n0 = tn * 64, k0 = tk * 64;
  __shared__ float T[64][65];
  int tid = threadIdx.x;
  #pragma unroll
  for (int q = 0; q < 16; ++q){
    int lin = q * 256 + tid;
    int r = lin >> 6, c = lin & 63;
    T[r][c] = W[(size_t)(k0 + r) * ldw + n0 + c];
  }
  __syncthreads();
  #pragma unroll
  for (int q = 0; q < 16; ++q){
    int lin = q * 256 + tid;
    int n = lin >> 6, k = lin & 63;
    WT[(size_t)(n0 + n) * ldt + k0 + k] = (__bf16)T[k][n];
  }
}

// ---------------- elementwise f32 -> bf16 ------------------------------------
__global__ __launch_bounds__(256) void cvt_bf(const float* __restrict__ in,
                                              __bf16* __restrict__ out, int n){
  int idx = (blockIdx.x * 256 + threadIdx.x) * 4;
  if (idx < n){
    float4 v = *(const float4*)&in[idx];
    bf16x4 r; r[0]=(__bf16)v.x; r[1]=(__bf16)v.y; r[2]=(__bf16)v.z; r[3]=(__bf16)v.w;
    *(bf16x4*)&out[idx] = r;
  }
}

// ---------------- pipelined bf16 MFMA GEMM: C = act(A @ BT^T + bias) ---------
template<int BM, int BN>
__global__ __launch_bounds__(256) void gemm_pipe(
    const __bf16* __restrict__ A, int lda, size_t sAz,
    const __bf16* __restrict__ BT, int ldb, size_t sBz,
    const float* __restrict__ bias, int sBiasz,
    float* __restrict__ C32, __bf16* __restrict__ C16, int ldc, size_t sCz,
    int K, int act)
{
  constexpr int MF = BM / 32;
  constexpr int NF = BN / 32;
  constexpr int LOADS = MF + NF;
  constexpr int ABYTES = BM * 128;
  constexpr int BBYTES = BN * 128;
  __shared__ __bf16 lds[(2 * (ABYTES + BBYTES)) / 2];
  int tid = threadIdx.x;

  // XCD-chunked block swizzle (nwg divisible by 8 for all our grids)
  int gx = gridDim.x, nwg = gx * gridDim.y;
  int lin = blockIdx.x + gx * blockIdx.y;
  int q8 = nwg >> 3;
  int swz = (lin & 7) * q8 + (lin >> 3);
  int bx = swz % gx, by = swz / gx;

  int z = blockIdx.z;
  A  += (size_t)z * sAz;
  BT += (size_t)z * sBz;
  const float* bz = bias ? bias + (size_t)z * sBiasz : nullptr;
  size_t cbase = (size_t)z * sCz;
  int brow = by * BM, bcol = bx * BN;

  int lane = tid & 63, w = tid >> 6;
  int wr = (w >> 1) * (BM / 2), wc = (w & 1) * (BN / 2);
  int lr = lane & 15, lg = lane >> 4;

  f32x4 acc[MF][NF];
  #pragma unroll
  for (int m = 0; m < MF; ++m)
    #pragma unroll
    for (int n = 0; n < NF; ++n) acc[m][n] = (f32x4){0.f, 0.f, 0.f, 0.f};

  char* lbase = (char*)lds;

  auto stage = [&](int buf, int ko){
    char* ab = lbase + buf * (ABYTES + BBYTES);
    #pragma unroll
    for (int qq = 0; qq < MF; ++qq){
      int byte = (qq * 256 + tid) * 16;
      int row = byte >> 7, col8 = byte & 127;
      int src = col8 ^ ((row & 7) << 4);
      gload16(&A[(size_t)(brow + row) * lda + ko + (src >> 1)], ab + byte);
    }
    char* bb = ab + ABYTES;
    #pragma unroll
    for (int qq = 0; qq < NF; ++qq){
      int byte = (qq * 256 + tid) * 16;
      int row = byte >> 7, col8 = byte & 127;
      int src = col8 ^ ((row & 7) << 4);
      gload16(&BT[(size_t)(bcol + row) * ldb + ko + (src >> 1)], bb + byte);
    }
  };

  stage(0, 0);
  int nk = K >> 6;
  for (int kt = 0; kt < nk; ++kt){
    int cur = kt & 1;
    if (kt + 1 < nk){
      stage(cur ^ 1, (kt + 1) << 6);
      if constexpr (LOADS == 3)      asm volatile("s_waitcnt vmcnt(3)" ::: "memory");
      else if constexpr (LOADS == 4) asm volatile("s_waitcnt vmcnt(4)" ::: "memory");
      else                           asm volatile("s_waitcnt vmcnt(6)" ::: "memory");
    } else {
      asm volatile("s_waitcnt vmcnt(0)" ::: "memory");
    }
    __builtin_amdgcn_s_barrier();
    __builtin_amdgcn_sched_barrier(0);
    char* ab = lbase + cur * (ABYTES + BBYTES);
    char* bb = ab + ABYTES;
    #pragma unroll
    for (int s = 0; s < 2; ++s){
      bf16x8 af[MF], bfr[NF];
      #pragma unroll
      for (int m = 0; m < MF; ++m){
        int row = wr + m * 16 + lr;
        int col8 = (s * 64 + lg * 16) ^ ((row & 7) << 4);
        af[m] = *(const bf16x8*)(ab + row * 128 + col8);
      }
      #pragma unroll
      for (int n = 0; n < NF; ++n){
        int row = wc + n * 16 + lr;
        int col8 = (s * 64 + lg * 16) ^ ((row & 7) << 4);
        bfr[n] = *(const bf16x8*)(bb + row * 128 + col8);
      }
      #pragma unroll
      for (int m = 0; m < MF; ++m)
        #pragma unroll
        for (int n = 0; n < NF; ++n)
          acc[m][n] = __builtin_amdgcn_mfma_f32_16x16x32_bf16(af[m], bfr[n], acc[m][n], 0, 0, 0);
    }
    asm volatile("" ::: "memory");
    __builtin_amdgcn_s_barrier();
  }

  #pragma unroll
  for (int m = 0; m < MF; ++m){
    #pragma unroll
    for (int n = 0; n < NF; ++n){
      int col = bcol + wc + n * 16 + lr;
      float bv = bz ? bz[col] : 0.f;
      #pragma unroll
      for (int j = 0; j < 4; ++j){
        int row = brow + wr + m * 16 + lg * 4 + j;
        float v = acc[m][n][j] + bv;
        if (act) v = gelu_f(v);
        size_t idx = cbase + (size_t)row * ldc + col;
        if (C32) C32[idx] = v;
        if (C16) C16[idx] = (__bf16)v;
      }
    }
  }
}

// ---------------- flash attention v3: K/V/mask all via global_load_lds -------
// grid: x=io tiles (8), y=bh (32), z=t. 4 waves, 16 Q-rows each.
// Ps aliased onto the current mask buffer (mask consumed before P-store).
template<bool HM>
__global__ __launch_bounds__(256) void flash_attn(
    const __bf16* __restrict__ qkv, size_t sQz,   // [2048][1536]
    const __bf16* __restrict__ vt,  size_t sVz,   // [32][64][512]
    const __bf16* __restrict__ mask, size_t sMz,  // [4][512][512] bf16
    __bf16* __restrict__ ctx, size_t sCz)         // [2048][512]
{
  int t = blockIdx.z;
  qkv += (size_t)t * sQz;
  vt  += (size_t)t * sVz;
  ctx += (size_t)t * sCz;
  const __bf16* mk = HM ? mask + (size_t)t * sMz : nullptr;

  // XCD-chunked swizzle: each XCD gets 4 bh x all 8 io (K/V L2 reuse)
  int lin = blockIdx.x + (blockIdx.y << 3);
  int swz = (lin & 7) * 32 + (lin >> 3);
  int io = (swz & 7) * 64;
  int bh = swz >> 3;
  int b = bh >> 3, h = bh & 7;

  constexpr int TB = 8192;                        // bytes per 64x64 bf16 tile
  constexpr int BUFB = HM ? 3 * TB : 2 * TB;
  __shared__ char lds[2 * BUFB + (HM ? 0 : TB)];
  char* lb = lds;
  int tid = threadIdx.x, lane = tid & 63, w = tid >> 6;
  int lr = lane & 15, lg = lane >> 4;

  // Q fragments in registers (loop-invariant)
  const __bf16* qrow = &qkv[(size_t)(b * Sq + io + w * 16 + lr) * 1536 + h * 64];
  bf16x8 q0 = *(const bf16x8*)&qrow[lg * 8];
  bf16x8 q1 = *(const bf16x8*)&qrow[32 + lg * 8];

  auto stage = [&](int buf, int jo){
    char* kb = lb + buf * BUFB;
    #pragma unroll
    for (int qq = 0; qq < 2; ++qq){
      int byte = (qq * 256 + tid) * 16;
      int row = byte >> 7;
      int src = (byte & 127) ^ ((row & 7) << 4);
      gload16(&qkv[(size_t)(b * Sq + jo + row) * 1536 + 512 + h * 64 + (src >> 1)], kb + byte);
    }
    char* vb = kb + TB;
    #pragma unroll
    for (int qq = 0; qq < 2; ++qq){
      int byte = (qq * 256 + tid) * 16;
      int row = byte >> 7;
      int src = (byte & 127) ^ ((row & 7) << 4);
      gload16(&vt[((size_t)bh * 64 + row) * Sq + jo + (src >> 1)], vb + byte);
    }
    if constexpr (HM){
      char* mb = vb + TB;
      #pragma unroll
      for (int qq = 0; qq < 2; ++qq){
        int byte = (qq * 256 + tid) * 16;
        int row = byte >> 7;
        int src = (byte & 127) ^ ((row & 7) << 4);
        gload16(&mk[(size_t)(b * Sq + io + row) * Sq + jo + (src >> 1)], mb + byte);
      }
    }
  };

  f32x4 o[4];
  #pragma unroll
  for (int n = 0; n < 4; ++n) o[n] = (f32x4){0.f, 0.f, 0.f, 0.f};
  float mrow[4] = {-1e30f, -1e30f, -1e30f, -1e30f};
  float lrow[4] = {0.f, 0.f, 0.f, 0.f};

  stage(0, 0);
  #pragma unroll
  for (int kt = 0; kt < 8; ++kt){
    int cur = kt & 1;

    if (kt + 1 < 8){
      stage(cur ^ 1, (kt + 1) << 6);
      if constexpr (HM) asm volatile("s_waitcnt vmcnt(6)" ::: "memory");
      else              asm volatile("s_waitcnt vmcnt(4)" ::: "memory");
    } else {
      asm volatile("s_waitcnt vmcnt(0)" ::: "memory");
    }
    __builtin_amdgcn_s_barrier();
    __builtin_amdgcn_sched_barrier(0);

    char* kb = lb + cur * BUFB;
    char* vb = kb + TB;
    char* mb = HM ? vb + TB : lb + 2 * BUFB;   // mask source AND Ps region

    // QK^T
    f32x4 s4[4];
    #pragma unroll
    for (int n = 0; n < 4; ++n) s4[n] = (f32x4){0.f, 0.f, 0.f, 0.f};
    __builtin_amdgcn_s_setprio(1);
    #pragma unroll
    for (int s = 0; s < 2; ++s){
      bf16x8 aq = s ? q1 : q0;
      #pragma unroll
      for (int n = 0; n < 4; ++n){
        int row = n * 16 + lr;
        int colb = (s * 64 + lg * 16) ^ ((row & 7) << 4);
        bf16x8 bk = *(const bf16x8*)(kb + row * 128 + colb);
        s4[n] = __builtin_amdgcn_mfma_f32_16x16x32_bf16(aq, bk, s4[n], 0, 0, 0);
      }
    }
    __builtin_amdgcn_s_setprio(0);

    // scale + mask (mask from LDS; each wave reads only its own 16-row slice)
    float sv[4][4];
    #pragma unroll
    for (int n = 0; n < 4; ++n){
      #pragma unroll
      for (int reg = 0; reg < 4; ++reg){
        float v = s4[n][reg] * 0.125f;
        if constexpr (HM){
          int row = w * 16 + lg * 4 + reg;
          int off = ((n * 16 + lr) * 2) ^ ((row & 7) << 4);
          v += (float)*(const __bf16*)(mb + row * 128 + off);
        }
        sv[n][reg] = v;
      }
    }

    // online softmax with defer-max (THR=8)
    #pragma unroll
    for (int reg = 0; reg < 4; ++reg){
      float pmax = fmaxf(fmaxf(sv[0][reg], sv[1][reg]), fmaxf(sv[2][reg], sv[3][reg]));
      #pragma unroll
      for (int off = 1; off < 16; off <<= 1) pmax = fmaxf(pmax, __shfl_xor(pmax, off));
      if (pmax > mrow[reg] + 8.0f){
        float corr = __expf(mrow[reg] - pmax);
        mrow[reg] = pmax;
        lrow[reg] *= corr;
        #pragma unroll
        for (int n = 0; n < 4; ++n) o[n][reg] *= corr;
      }
      float rs = 0.f;
      #pragma unroll
      for (int n = 0; n < 4; ++n){
        float p = __expf(sv[n][reg] - mrow[reg]);
        sv[n][reg] = p;
        rs += p;
      }
      #pragma unroll
      for (int off = 1; off < 16; off <<= 1) rs += __shfl_xor(rs, off);
      lrow[reg] += rs;
    }

    // P -> Ps region (aliases cur mask buf for HM; per-wave 16-row slice)
    #pragma unroll
    for (int n = 0; n < 4; ++n)
      #pragma unroll
      for (int reg = 0; reg < 4; ++reg){
        int row = w * 16 + lg * 4 + reg;
        int off = ((n * 16 + lr) * 2) ^ ((row & 7) << 4);
        *(__bf16*)(mb + row * 128 + off) = (__bf16)sv[n][reg];
      }
    __builtin_amdgcn_s_setprio(1);
    #pragma unroll
    for (int s = 0; s < 2; ++s){
      int arow = w * 16 + lr;
      int acol = (s * 64 + lg * 16) ^ ((arow & 7) << 4);
      bf16x8 ap = *(const bf16x8*)(mb + arow * 128 + acol);
      #pragma unroll
      for (int n = 0; n < 4; ++n){
        int row = n * 16 + lr;
        int colb = (s * 64 + lg * 16) ^ ((row & 7) << 4);
        bf16x8 bv = *(const bf16x8*)(vb + row * 128 + colb);
        o[n] = __builtin_amdgcn_mfma_f32_16x16x32_bf16(ap, bv, o[n], 0, 0, 0);
      }
    }
    __builtin_amdgcn_s_setprio(0);

    asm volatile("" ::: "memory");
    __builtin_amdgcn_s_barrier();                 // protect buf reuse by next stage()
  }

  // normalize + write ctx
  #pragma unroll
  for (int reg = 0; reg < 4; ++reg){
    float inv = 1.0f / lrow[reg];
    int row = b * Sq + io + w * 16 + lg * 4 + reg;
    #pragma unroll
    for (int n = 0; n < 4; ++n)
      ctx[(size_t)row * Hq + h * 64 + n * 16 + lr] = (__bf16)(o[n][reg] * inv);
  }
}

// ---------------- row LayerNorm (+residual), dual-dtype out ------------------
__global__ __launch_bounds__(256) void ln_rows(const float* __restrict__ in,
                                               const float* __restrict__ res,
                                               const float* __restrict__ g,
                                               const float* __restrict__ bb,
                                               float* __restrict__ out32,
                                               __bf16* __restrict__ out16,
                                               int do_gelu){
  int row = blockIdx.x * 4 + (threadIdx.x >> 6);
  int lane = threadIdx.x & 63;
  const float* ir = in + (size_t)row * Hq;
  const float* rr = res ? res + (size_t)row * Hq : nullptr;
  float x[8]; float s = 0.f, sq = 0.f;
  #pragma unroll
  for (int k = 0; k < 8; ++k){
    int c = lane + 64 * k;
    float v = ir[c];
    if (rr) v += rr[c];
    x[k] = v; s += v; sq += v * v;
  }
  s = waveReduceSum(s); sq = waveReduceSum(sq);
  float mean = s * (1.0f / Hq);
  float var = fmaxf(sq * (1.0f / Hq) - mean * mean, 0.f);
  float rstd = rsqrtf(var + 1e-5f);
  #pragma unroll
  for (int k = 0; k < 8; ++k){
    int c = lane + 64 * k;
    float y = (x[k] - mean) * rstd * g[c] + bb[c];
    if (do_gelu) y = gelu_f(y);
    if (out32) out32[(size_t)row * Hq + c] = y;
    if (out16) out16[(size_t)row * Hq + c] = (__bf16)y;
  }
}

// ------- fused: LN + gelu + mixer2 + softmax over T + weighted combine -------
__global__ __launch_bounds__(256) void ln_mixer_weighted(const float* __restrict__ in,
                                                         const float* __restrict__ g,
                                                         const float* __restrict__ bb,
                                                         const float* __restrict__ W2,
                                                         const float* __restrict__ b2,
                                                         const __bf16* __restrict__ comb,
                                                         float* __restrict__ out32,
                                                         __bf16* __restrict__ out16){
  int row = blockIdx.x * 4 + (threadIdx.x >> 6);
  int lane = threadIdx.x & 63;
  const float* ir = in + (size_t)row * Hq;
  float x[8]; float s = 0.f, sq = 0.f;
  #pragma unroll
  for (int k = 0; k < 8; ++k){
    int c = lane + 64 * k;
    float v = ir[c];
    x[k] = v; s += v; sq += v * v;
  }
  s = waveReduceSum(s); sq = waveReduceSum(sq);
  float mean = s * (1.0f / Hq);
  float var = fmaxf(sq * (1.0f / Hq) - mean * mean, 0.f);
  float rstd = rsqrtf(var + 1e-5f);
  float a0 = 0.f, a1 = 0.f, a2 = 0.f;
  #pragma unroll
  for (int k = 0; k < 8; ++k){
    int c = lane + 64 * k;
    float y = gelu_f((x[k] - mean) * rstd * g[c] + bb[c]);
    const float* wv = W2 + c * 3;
    a0 = fmaf(y, wv[0], a0); a1 = fmaf(y, wv[1], a1); a2 = fmaf(y, wv[2], a2);
  }
  a0 = waveReduceSum(a0) + b2[0];
  a1 = waveReduceSum(a1) + b2[1];
  a2 = waveReduceSum(a2) + b2[2];
  float mx = fmaxf(a0, fmaxf(a1, a2));
  float e0 = __expf(a0 - mx), e1 = __expf(a1 - mx), e2 = __expf(a2 - mx);
  float inv = 1.0f / (e0 + e1 + e2);
  float m0 = e0 * inv, m1 = e1 * inv, m2 = e2 * inv;
  const __bf16* cr = comb + (size_t)row * 1536;
  #pragma unroll
  for (int k = 0; k < 8; ++k){
    int c = lane + 64 * k;
    float v = m0 * (float)cr[c] + m1 * (float)cr[512 + c] + m2 * (float)cr[1024 + c];
    out32[(size_t)row * Hq + c] = v;
    out16[(size_t)row * Hq + c] = (__bf16)v;
  }
}

// ---------------- V transpose per head (z-batched over t) --------------------
__global__ __launch_bounds__(256) void transpose_v(const __bf16* __restrict__ qkv, size_t sQz,
                                                   __bf16* __restrict__ vt, size_t sVz){
  int t = blockIdx.z;
  qkv += (size_t)t * sQz;
  vt  += (size_t)t * sVz;
  int bh = blockIdx.y, b = bh >> 3, h = bh & 7;
  int so = blockIdx.x * 64;
  __shared__ __bf16 T[64][72];
  int tid = threadIdx.x;
  #pragma unroll
  for (int q = 0; q < 16; ++q){
    int lin = q * 256 + tid;
    int r = lin >> 6, c = lin & 63;
    T[r][c] = qkv[(size_t)(b * Sq + so + r) * 1536 + 1024 + h * 64 + c];
  }
  __syncthreads();
  #pragma unroll
  for (int q = 0; q < 16; ++q){
    int lin = q * 256 + tid;
    int d = lin >> 6, s = lin & 63;
    vt[((size_t)bh * 64 + d) * Sq + so + s] = T[s][d];
  }
}

extern "C" void kernel_launch(void* const* d_in, const int* in_sizes, int n_in,
                              void* d_out, int out_size, void* d_ws, size_t ws_size,
                              hipStream_t stream){
  const float* x         = (const float*)d_in[0];
  const float* ts        = (const float*)d_in[1];
  const float* enc_W     = (const float*)d_in[2];
  const float* enc_b     = (const float*)d_in[3];
  const float* enc_ln_g  = (const float*)d_in[4];
  const float* enc_ln_b  = (const float*)d_in[5];
  const float* qkv_W     = (const float*)d_in[6];
  const float* qkv_b     = (const float*)d_in[7];
  const float* aout_W    = (const float*)d_in[8];
  const float* aout_b    = (const float*)d_in[9];
  const float* mx_W1     = (const float*)d_in[10];
  const float* mx_b1     = (const float*)d_in[11];
  const float* mx_ln_g   = (const float*)d_in[12];
  const float* mx_ln_b   = (const float*)d_in[13];
  const float* mx_W2     = (const float*)d_in[14];
  const float* mx_b2     = (const float*)d_in[15];
  const float* el_qkv_W  = (const float*)d_in[16];
  const float* el_qkv_b  = (const float*)d_in[17];
  const float* el_out_W  = (const float*)d_in[18];
  const float* el_out_b  = (const float*)d_in[19];
  const float* el_ln1_g  = (const float*)d_in[20];
  const float* el_ln1_b  = (const float*)d_in[21];
  const float* el_ff_W1  = (const float*)d_in[22];
  const float* el_ff_b1  = (const float*)d_in[23];
  const float* el_ff_W2  = (const float*)d_in[24];
  const float* el_ff_b2  = (const float*)d_in[25];
  const float* el_ln2_g  = (const float*)d_in[26];
  const float* el_ln2_b  = (const float*)d_in[27];
  const float* op_W      = (const float*)d_in[28];
  const float* op_b      = (const float*)d_in[29];
  const float* op_ln_g   = (const float*)d_in[30];
  const float* op_ln_b   = (const float*)d_in[31];

  float* ws = (float*)d_ws;
  size_t o = 0;
  __bf16* MASKBb = (__bf16*)(ws + o); o += 1572864;           // [3][4][512][512]
  __bf16* XB     = (__bf16*)(ws + o); o += 524288;            // [2048][512]
  __bf16* qkvT   = (__bf16*)(ws + o); o += 1179648;           // [3][1536][512]
  __bf16* aoutT  = (__bf16*)(ws + o); o += 393216;            // [3][512][512]
  __bf16* mx1T   = (__bf16*)(ws + o); o += 393216;            // [512][1536]
  __bf16* elqkvT = (__bf16*)(ws + o); o += 393216;            // [1536][512]
  __bf16* eloutT = (__bf16*)(ws + o); o += 131072;            // [512][512]
  __bf16* ff1T   = (__bf16*)(ws + o); o += 524288;            // [2048][512]
  __bf16* ff2T   = (__bf16*)(ws + o); o += 524288;            // [512][2048]
  __bf16* opT    = (__bf16*)(ws + o); o += 131072;            // [512][512]
  __bf16* QKVb   = (__bf16*)(ws + o); o += 4718592;           // [3][2048][1536]
  __bf16* VTb    = (__bf16*)(ws + o); o += 1572864;           // [3][32][64][512]
  __bf16* FFBb   = (__bf16*)(ws + o); o += 2097152;           // [2048][2048]
  __bf16* CTXb   = (__bf16*)(ws + o); o += 1572864;           // [3][2048][512]
  __bf16* COMBb  = (__bf16*)(ws + o); o += 1572864;           // [2048][1536]
  float*  MBUF   = ws + o;            o += 1048576;           // mixer1 out, also OPO
  float*  WEI    = ws + o;            o += 1048576;
  __bf16* WEIb   = (__bf16*)(ws + o); o += 524288;
  float*  SA     = ws + o;            o += 1048576;
  float*  H1     = ws + o;            o += 1048576;
  __bf16* H1b    = (__bf16*)(ws + o); o += 524288;
  float*  H2     = ws + o;            o += 1048576;
  __bf16* H2b    = (__bf16*)(ws + o); o += 524288;
  float*  LUTB   = ws + o;            o += 9 * NLUT;
  float*  OPO    = MBUF;

  // 0. dtype conversions (merged)
  cvt_bf<<<1024, 256, 0, stream>>>(x, XB, BSq * Hq);
  {
    CvtArgs ca;
    for (int t = 0; t < 3; ++t)
      ca.e[t] = {qkv_W + (size_t)t * 512 * 1536, qkvT + (size_t)t * 1536 * 512, 1536, 512, 24, 192 * t};
    for (int t = 0; t < 3; ++t)
      ca.e[3 + t] = {aout_W + (size_t)t * 512 * 512, aoutT + (size_t)t * 512 * 512, 512, 512, 8, 576 + 64 * t};
    ca.e[6]  = {mx_W1,    mx1T,   512,  1536, 8,  768};
    ca.e[7]  = {el_qkv_W, elqkvT, 1536, 512,  24, 960};
    ca.e[8]  = {el_out_W, eloutT, 512,  512,  8,  1152};
    ca.e[9]  = {el_ff_W1, ff1T,   2048, 512,  32, 1216};
    ca.e[10] = {el_ff_W2, ff2T,   512,  2048, 8,  1472};
    ca.e[11] = {op_W,     opT,    512,  512,  8,  1728};
    cvt_wT_all<<<1792, 256, 0, stream>>>(ca);
  }

  // 1. temporal masks
  mask_lut_build<<<dim3(9, NLUT / 256), 256, 0, stream>>>(enc_W, enc_b, enc_ln_g, enc_ln_b, LUTB);
  mask_fill<<<BSq, 256, 0, stream>>>(ts, LUTB, MASKBb);

  // 2. per-timescale masked attention (flash, t-batched)
  gemm_pipe<128,64><<<dim3(24, 16, 3), 256, 0, stream>>>(XB, 512, 0, qkvT, 512, (size_t)1536 * 512,
      qkv_b, 1536, nullptr, QKVb, 1536, (size_t)2048 * 1536, 512, 0);
  transpose_v<<<dim3(8, 32, 3), 256, 0, stream>>>(QKVb, (size_t)2048 * 1536, VTb, (size_t)32 * 64 * 512);
  flash_attn<true><<<dim3(8, 32, 3), 256, 0, stream>>>(QKVb, (size_t)2048 * 1536,
      VTb, (size_t)32 * 64 * 512, MASKBb, (size_t)4 * 512 * 512, CTXb, (size_t)2048 * 512);
  gemm_pipe<64,32><<<dim3(16, 32, 3), 256, 0, stream>>>(CTXb, 512, (size_t)2048 * 512, aoutT, 512, (size_t)512 * 512,
      aout_b, 512, nullptr, COMBb, 1536, 512, 512, 0);

  // 3. time mixer (fused LN+gelu+mixer2+softmax+weighted)
  gemm_pipe<64,32><<<dim3(16, 32, 1), 256, 0, stream>>>(COMBb, 1536, 0, mx1T, 1536, 0,
      mx_b1, 0, MBUF, nullptr, 512, 0, 1536, 0);
  ln_mixer_weighted<<<512, 256, 0, stream>>>(MBUF, mx_ln_g, mx_ln_b, mx_W2, mx_b2, COMBb, WEI, WEIb);

  // 4. transformer encoder layer (post-norm)
  gemm_pipe<128,64><<<dim3(24, 16, 1), 256, 0, stream>>>(WEIb, 512, 0, elqkvT, 512, 0,
      el_qkv_b, 0, nullptr, QKVb, 1536, 0, 512, 0);
  transpose_v<<<dim3(8, 32, 1), 256, 0, stream>>>(QKVb, 0, VTb, 0);
  flash_attn<false><<<dim3(8, 32, 1), 256, 0, stream>>>(QKVb, 0, VTb, 0, nullptr, 0, CTXb, 0);
  gemm_pipe<64,32><<<dim3(16, 32, 1), 256, 0, stream>>>(CTXb, 512, 0, eloutT, 512, 0,
      el_out_b, 0, SA, nullptr, 512, 0, 512, 0);
  ln_rows<<<512, 256, 0, stream>>>(WEI, SA, el_ln1_g, el_ln1_b, H1, H1b, 0);
  gemm_pipe<128,64><<<dim3(32, 16, 1), 256, 0, stream>>>(H1b, 512, 0, ff1T, 512, 0,
      el_ff_b1, 0, nullptr, FFBb, 2048, 0, 512, 1);
  gemm_pipe<64,32><<<dim3(16, 32, 1), 256, 0, stream>>>(FFBb, 2048, 0, ff2T, 2048, 0,
      el_ff_b2, 0, SA, nullptr, 512, 0, 2048, 0);
  ln_rows<<<512, 256, 0, stream>>>(H1, SA, el_ln2_g, el_ln2_b, H2, H2b, 0);

  // 5. output projection + final LN
  gemm_pipe<64,32><<<dim3(16, 32, 1), 256, 0, stream>>>(H2b, 512, 0, opT, 512, 0,
      op_b, 0, OPO, nullptr, 512, 0, 512, 0);
  ln_rows<<<512, 256, 0, stream>>>(OPO, nullptr, op_ln_g, op_ln_b, (float*)d_out, nullptr, 0);
}